// Round 1
// baseline (4550.803 us; speedup 1.0000x reference)
//
#include <hip/hip_runtime.h>
#include <math.h>

#define NS 1024
#define T0 32
#define DF 158
#define DG 63
#define DM 256
#define XROW (DF + DG)  // 221

// ---------------- positional encoding table (32 x 256) ----------------
__global__ void k_pe(float* __restrict__ pe) {
  int t = blockIdx.x, d = threadIdx.x;
  int i2 = d & ~1;
  float div = expf((float)i2 * (-logf(10000.0f) / (float)DM));
  float ang = (float)t * div;
  pe[t * DM + d] = (d & 1) ? cosf(ang) : sinf(ang);
}

// ---------------- gate: g = 158 * softmax((gate_in @ gate_W + b)/5) ----------------
__global__ void k_gate(const float* __restrict__ x, const float* __restrict__ gW,
                       const float* __restrict__ gb, float* __restrict__ g) {
  int n = blockIdx.x, tid = threadIdx.x;
  __shared__ float gin[DG];
  __shared__ float red[256];
  if (tid < DG) gin[tid] = x[(size_t)n * T0 * XROW + 31 * XROW + DF + tid];
  __syncthreads();
  float myv = 0.f;
  if (tid < DF) {
    float acc = gb[tid];
    for (int j = 0; j < DG; j++) acc = fmaf(gin[j], gW[j * DF + tid], acc);
    myv = acc * (1.0f / 5.0f);
  }
  red[tid] = (tid < DF) ? myv : -1e30f;
  __syncthreads();
  for (int s = 128; s > 0; s >>= 1) { if (tid < s) red[tid] = fmaxf(red[tid], red[tid + s]); __syncthreads(); }
  float mx = red[0];
  __syncthreads();
  float e = (tid < DF) ? expf(myv - mx) : 0.f;
  red[tid] = e;
  __syncthreads();
  for (int s = 128; s > 0; s >>= 1) { if (tid < s) red[tid] += red[tid + s]; __syncthreads(); }
  float sum = red[0];
  if (tid < DF) g[(size_t)n * DF + tid] = (float)DF * e / sum;
}

// ---------------- generic fp32 GEMM: C = act(A@B + bias + pe + res) ----------------
// A: M x K row-major with leading dim lda. B: K x N row-major. C: M x N.
template <bool GATE, bool PE, bool BIAS, bool RELU, bool RES>
__global__ __launch_bounds__(256) void k_gemm(
    const float* __restrict__ A, int lda, const float* __restrict__ B,
    const float* __restrict__ bias, const float* __restrict__ pe,
    const float* __restrict__ gate, const float* __restrict__ res,
    float* __restrict__ C, int M, int N, int K) {
  __shared__ float As[16][65];
  __shared__ float Bs[16][64];
  int tid = threadIdx.x;
  int tx = tid & 15, ty = tid >> 4;
  int row0 = blockIdx.x * 64, col0 = blockIdx.y * 64;
  float acc[4][4] = {};
  for (int k0 = 0; k0 < K; k0 += 16) {
#pragma unroll
    for (int i = 0; i < 4; i++) {
      int idx = tid + i * 256;
      int m = idx >> 4, kk = idx & 15;
      int gk = k0 + kk;
      float val = 0.f;
      if (gk < K) {
        int grow = row0 + m;
        val = A[(size_t)grow * lda + gk];
        if (GATE) val *= gate[(size_t)(grow >> 5) * DF + gk];
      }
      As[kk][m] = val;
    }
#pragma unroll
    for (int i = 0; i < 4; i++) {
      int idx = tid + i * 256;
      int kk = idx >> 6, nn = idx & 63;
      int gk = k0 + kk;
      Bs[kk][nn] = (gk < K) ? B[(size_t)gk * N + col0 + nn] : 0.f;
    }
    __syncthreads();
#pragma unroll
    for (int kk = 0; kk < 16; kk++) {
      float a[4], b[4];
#pragma unroll
      for (int i = 0; i < 4; i++) a[i] = As[kk][ty * 4 + i];
#pragma unroll
      for (int j = 0; j < 4; j++) b[j] = Bs[kk][tx * 4 + j];
#pragma unroll
      for (int i = 0; i < 4; i++)
#pragma unroll
        for (int j = 0; j < 4; j++) acc[i][j] = fmaf(a[i], b[j], acc[i][j]);
    }
    __syncthreads();
  }
#pragma unroll
  for (int i = 0; i < 4; i++) {
    int row = row0 + ty * 4 + i;
#pragma unroll
    for (int j = 0; j < 4; j++) {
      int col = col0 + tx * 4 + j;
      float v = acc[i][j];
      if (BIAS) v += bias[col];
      if (PE) v += pe[(row & (T0 - 1)) * DM + col];
      if (RES) v += res[(size_t)row * N + col];
      if (RELU) v = fmaxf(v, 0.f);
      C[(size_t)row * N + col] = v;
    }
  }
}

// ---------------- LayerNorm over last dim 256; optional residual input ----------------
template <bool RES_IN>
__global__ __launch_bounds__(256) void k_ln(const float* __restrict__ a, const float* __restrict__ b,
                                            const float* __restrict__ g, const float* __restrict__ be,
                                            float* __restrict__ out) {
  int row = blockIdx.x, tid = threadIdx.x;
  size_t base = (size_t)row * DM;
  float v = a[base + tid];
  if (RES_IN) v += b[base + tid];
  __shared__ float red[256];
  red[tid] = v;
  __syncthreads();
  for (int s = 128; s > 0; s >>= 1) { if (tid < s) red[tid] += red[tid + s]; __syncthreads(); }
  float mean = red[0] * (1.0f / DM);
  __syncthreads();
  float d = v - mean;
  red[tid] = d * d;
  __syncthreads();
  for (int s = 128; s > 0; s >>= 1) { if (tid < s) red[tid] += red[tid + s]; __syncthreads(); }
  float var = red[0] * (1.0f / DM);
  out[base + tid] = d * rsqrtf(var + 1e-5f) * g[tid] + be[tid];
}

// ---------------- mean-pool over time groups ----------------
__global__ void k_poolmean(const float* __restrict__ h, float* __restrict__ out, int Tout, int P) {
  int idx = blockIdx.x * 256 + threadIdx.x;
  int d = idx & 255;
  int tmp = idx >> 8;
  int to = tmp % Tout;
  int n = tmp / Tout;
  int Tin = Tout * P;
  float s = 0.f;
  for (int p = 0; p < P; p++) s += h[((size_t)(n * Tin + to * P + p)) * DM + d];
  out[idx] = s / (float)P;
}

// ---------------- time attention (per stock, nhead=4, dh=64) ----------------
template <int T>
__global__ __launch_bounds__(256) void k_tattn(const float* __restrict__ q, const float* __restrict__ k,
                                               const float* __restrict__ v, float* __restrict__ o) {
  int b = blockIdx.x;
  int n = b >> 2, h = b & 3;
  int tid = threadIdx.x;
  __shared__ float qs[T][65], ks[T][65], vs[T][65], sc[T][T + 1];
  for (int idx = tid; idx < T * 64; idx += 256) {
    int t = idx >> 6, d = idx & 63;
    size_t gi = ((size_t)(n * T + t)) * DM + h * 64 + d;
    qs[t][d] = q[gi];
    ks[t][d] = k[gi];
    vs[t][d] = v[gi];
  }
  __syncthreads();
  for (int idx = tid; idx < T * T; idx += 256) {
    int i = idx / T, j = idx % T;
    float s = 0.f;
#pragma unroll
    for (int d = 0; d < 64; d++) s = fmaf(qs[i][d], ks[j][d], s);
    sc[i][j] = s * 0.125f;  // / sqrt(256/4)
  }
  __syncthreads();
  if (tid < T) {
    float mx = -1e30f;
    for (int j = 0; j < T; j++) mx = fmaxf(mx, sc[tid][j]);
    float sum = 0.f;
    for (int j = 0; j < T; j++) { float e = expf(sc[tid][j] - mx); sc[tid][j] = e; sum += e; }
    float inv = 1.0f / sum;
    for (int j = 0; j < T; j++) sc[tid][j] *= inv;
  }
  __syncthreads();
  for (int idx = tid; idx < T * 64; idx += 256) {
    int i = idx >> 6, d = idx & 63;
    float s = 0.f;
#pragma unroll
    for (int j = 0; j < T; j++) s = fmaf(sc[i][j], vs[j][d], s);
    o[((size_t)(n * T + i)) * DM + h * 64 + d] = s;
  }
}

// ---------------- stock attention (over_stocks, nhead=2, dh=128), flash-style ----------------
// grid: (T*2) * 16 blocks; each block: (t,h) + 64-query tile, loops 1024 keys in 32-key tiles.
// thread (r = tid>>2, g = tid&3) owns query row r and d-columns {g + 4*dd} (interleave: bank-conflict-free).
__global__ __launch_bounds__(256) void k_sattn(const float* __restrict__ q, const float* __restrict__ k,
                                               const float* __restrict__ v, float* __restrict__ o, int T) {
  int bid = blockIdx.x;
  int qb = bid & 15;
  int th = bid >> 4;
  int t = th >> 1, h = th & 1;
  int tid = threadIdx.x;
  int r = tid >> 2, g = tid & 3;
  const float invtemp = 0.08838834764831845f;  // 1/sqrt(256/2)
  __shared__ float Ks[32][128], Vs[32][128];
  float Q[32], O[32];
  size_t qbase = ((size_t)((qb * 64 + r) * T + t)) * DM + h * 128;
#pragma unroll
  for (int dd = 0; dd < 32; dd++) { Q[dd] = q[qbase + g + 4 * dd]; O[dd] = 0.f; }
  float m = -1e30f, l = 0.f;
  for (int kb = 0; kb < NS; kb += 32) {
    __syncthreads();
    for (int idx = tid; idx < 32 * 128; idx += 256) {
      int j = idx >> 7, d = idx & 127;
      size_t gi = ((size_t)((kb + j) * T + t)) * DM + h * 128 + d;
      Ks[j][d] = k[gi];
      Vs[j][d] = v[gi];
    }
    __syncthreads();
    float s[32];
#pragma unroll
    for (int j = 0; j < 32; j++) {
      float p = 0.f;
#pragma unroll
      for (int dd = 0; dd < 32; dd++) p = fmaf(Q[dd], Ks[j][g + 4 * dd], p);
      s[j] = p;
    }
#pragma unroll
    for (int j = 0; j < 32; j++) {
      s[j] += __shfl_xor(s[j], 1);
      s[j] += __shfl_xor(s[j], 2);
      s[j] *= invtemp;
    }
    float mn = m;
#pragma unroll
    for (int j = 0; j < 32; j++) mn = fmaxf(mn, s[j]);
    float scale = expf(m - mn);
    l *= scale;
#pragma unroll
    for (int dd = 0; dd < 32; dd++) O[dd] *= scale;
    float ps = 0.f;
    for (int j = 0; j < 32; j++) {
      float p = expf(s[j] - mn);
      ps += p;
#pragma unroll
      for (int dd = 0; dd < 32; dd++) O[dd] = fmaf(p, Vs[j][g + 4 * dd], O[dd]);
    }
    l += ps;
    m = mn;
  }
  float inv = 1.0f / l;
#pragma unroll
  for (int dd = 0; dd < 32; dd++) o[qbase + g + 4 * dd] = O[dd] * inv;
}

// ---------------- temporal pooling: lam = softmax_t(hh[n,t]·hh[n,-1]); pooled = sum_t lam*z ----------------
__global__ __launch_bounds__(256) void k_tpool(const float* __restrict__ hh, const float* __restrict__ z,
                                               float* __restrict__ pooled, int T, int off) {
  int n = blockIdx.x, d = threadIdx.x;
  __shared__ float red[256];
  __shared__ float lam[T0];
  __shared__ float lame[T0];
  float last = hh[((size_t)(n * T + T - 1)) * DM + d];
  for (int t = 0; t < T; t++) {
    red[d] = hh[((size_t)(n * T + t)) * DM + d] * last;
    __syncthreads();
    for (int s = 128; s > 0; s >>= 1) { if (d < s) red[d] += red[d + s]; __syncthreads(); }
    if (d == 0) lam[t] = red[0];
    __syncthreads();
  }
  float mx = -1e30f;
  for (int t = 0; t < T; t++) mx = fmaxf(mx, lam[t]);
  if (d < T) lame[d] = expf(lam[d] - mx);
  __syncthreads();
  float sum = 0.f;
  for (int t = 0; t < T; t++) sum += lame[t];
  float acc = 0.f;
  for (int t = 0; t < T; t++) acc += lame[t] * z[((size_t)(n * T + t)) * DM + d];
  pooled[(size_t)n * (3 * DM) + off + d] = acc / sum;
}

// ---------------- final: out = relu(LN(fused)) @ dec_W + dec_b ----------------
__global__ __launch_bounds__(256) void k_final(const float* __restrict__ f, const float* __restrict__ g,
                                               const float* __restrict__ b, const float* __restrict__ dw,
                                               const float* __restrict__ db, float* __restrict__ out) {
  int n = blockIdx.x, d = threadIdx.x;
  float v = f[(size_t)n * DM + d];
  __shared__ float red[256];
  red[d] = v;
  __syncthreads();
  for (int s = 128; s > 0; s >>= 1) { if (d < s) red[d] += red[d + s]; __syncthreads(); }
  float mean = red[0] * (1.0f / DM);
  __syncthreads();
  float dv = v - mean;
  red[d] = dv * dv;
  __syncthreads();
  for (int s = 128; s > 0; s >>= 1) { if (d < s) red[d] += red[d + s]; __syncthreads(); }
  float var = red[0] * (1.0f / DM);
  __syncthreads();
  float y = dv * rsqrtf(var + 1e-5f) * g[d] + b[d];
  y = fmaxf(y, 0.f);
  red[d] = y * dw[d];
  __syncthreads();
  for (int s = 128; s > 0; s >>= 1) { if (d < s) red[d] += red[d + s]; __syncthreads(); }
  if (d == 0) out[n] = red[0] + db[0];
}

extern "C" void kernel_launch(void* const* d_in, const int* in_sizes, int n_in,
                              void* d_out, int out_size, void* d_ws, size_t ws_size,
                              hipStream_t stream) {
  const float* x = (const float*)d_in[0];
  const float* gate_W = (const float*)d_in[1];
  const float* gate_b = (const float*)d_in[2];
  const float* feat_W = (const float*)d_in[3];
  const float* feat_b = (const float*)d_in[4];
  const float* ds_mid_W = (const float*)d_in[5];
  const float* ds_mid_b = (const float*)d_in[6];
  const float* ds_small_W = (const float*)d_in[7];
  const float* ds_small_b = (const float*)d_in[8];
  const float* tn1g = (const float*)d_in[9];
  const float* tn1b = (const float*)d_in[10];
  const float* tWq = (const float*)d_in[11];
  const float* tWk = (const float*)d_in[12];
  const float* tWv = (const float*)d_in[13];
  const float* tn2g = (const float*)d_in[14];
  const float* tn2b = (const float*)d_in[15];
  const float* tW1 = (const float*)d_in[16];
  const float* tb1 = (const float*)d_in[17];
  const float* tW2 = (const float*)d_in[18];
  const float* tb2 = (const float*)d_in[19];
  const float* sn1g = (const float*)d_in[20];
  const float* sn1b = (const float*)d_in[21];
  const float* sWq = (const float*)d_in[22];
  const float* sWk = (const float*)d_in[23];
  const float* sWv = (const float*)d_in[24];
  const float* sn2g = (const float*)d_in[25];
  const float* sn2b = (const float*)d_in[26];
  const float* sW1 = (const float*)d_in[27];
  const float* sb1 = (const float*)d_in[28];
  const float* sW2 = (const float*)d_in[29];
  const float* sb2 = (const float*)d_in[30];
  const float* temp_W = (const float*)d_in[31];
  const float* fus_W = (const float*)d_in[32];
  const float* fus_b = (const float*)d_in[33];
  const float* fus_g = (const float*)d_in[34];
  const float* fus_bb = (const float*)d_in[35];
  const float* dec_W = (const float*)d_in[36];
  const float* dec_b = (const float*)d_in[37];

  float* ws = (float*)d_ws;
  float* pe = ws;                         // 8192
  float* g = pe + 8192;                   // 161792
  float* h0 = g + 161792;                 // 8388608  (also aliases bO)
  float* h1 = h0 + 8388608;               // 4194304
  float* h2 = h1 + 4194304;               // 2097152
  float* bXN = h2 + 2097152;              // 8388608
  float* bQ = bXN + 8388608;              // 8388608
  float* bK = bQ + 8388608;               // 8388608
  float* bV = bK + 8388608;               // 8388608
  float* pooled = bV + 8388608;           // 786432
  float* fused = pooled + 786432;         // 262144
  float* bO = h0;  // alias: h0 is dead by the time attn output is produced

  k_pe<<<T0, DM, 0, stream>>>(pe);
  k_gate<<<NS, 256, 0, stream>>>(x, gate_W, gate_b, g);

  // h0 = (src * gate) @ feat_W + feat_b + pe
  k_gemm<true, true, true, false, false><<<dim3(32768 / 64, 4), 256, 0, stream>>>(
      x, XROW, feat_W, feat_b, pe, g, nullptr, h0, 32768, DM, DF);

  // h1 = pool2(h0) @ ds_mid_W + b ; h2 = pool4(h0) @ ds_small_W + b
  k_poolmean<<<NS * 16, 256, 0, stream>>>(h0, bXN, 16, 2);
  k_gemm<false, false, true, false, false><<<dim3(16384 / 64, 4), 256, 0, stream>>>(
      bXN, DM, ds_mid_W, ds_mid_b, nullptr, nullptr, nullptr, h1, 16384, DM, DM);
  k_poolmean<<<NS * 8, 256, 0, stream>>>(h0, bXN, 8, 4);
  k_gemm<false, false, true, false, false><<<dim3(8192 / 64, 4), 256, 0, stream>>>(
      bXN, DM, ds_small_W, ds_small_b, nullptr, nullptr, nullptr, h2, 8192, DM, DM);

  const float* hs[3] = {h0, h1, h2};
  const int Ts[3] = {32, 16, 8};
  for (int s = 0; s < 3; s++) {
    int T = Ts[s];
    int M = NS * T;
    dim3 gg(M / 64, 4);
    const float* h = hs[s];
    // ---- block 1: time attention (nhead=4) ----
    k_ln<false><<<M, 256, 0, stream>>>(h, nullptr, tn1g, tn1b, bXN);
    k_gemm<false, false, false, false, false><<<gg, 256, 0, stream>>>(bXN, DM, tWq, nullptr, nullptr, nullptr, nullptr, bQ, M, DM, DM);
    k_gemm<false, false, false, false, false><<<gg, 256, 0, stream>>>(bXN, DM, tWk, nullptr, nullptr, nullptr, nullptr, bK, M, DM, DM);
    k_gemm<false, false, false, false, false><<<gg, 256, 0, stream>>>(bXN, DM, tWv, nullptr, nullptr, nullptr, nullptr, bV, M, DM, DM);
    if (T == 32) k_tattn<32><<<NS * 4, 256, 0, stream>>>(bQ, bK, bV, bO);
    else if (T == 16) k_tattn<16><<<NS * 4, 256, 0, stream>>>(bQ, bK, bV, bO);
    else k_tattn<8><<<NS * 4, 256, 0, stream>>>(bQ, bK, bV, bO);
    k_ln<true><<<M, 256, 0, stream>>>(bXN, bO, tn2g, tn2b, bQ);  // xt
    k_gemm<false, false, true, true, false><<<gg, 256, 0, stream>>>(bQ, DM, tW1, tb1, nullptr, nullptr, nullptr, bK, M, DM, DM);
    k_gemm<false, false, true, false, true><<<gg, 256, 0, stream>>>(bK, DM, tW2, tb2, nullptr, nullptr, bQ, bV, M, DM, DM);  // z
    // ---- block 2: stock attention (nhead=2) ----
    k_ln<false><<<M, 256, 0, stream>>>(bV, nullptr, sn1g, sn1b, bXN);  // xn2
    k_gemm<false, false, false, false, false><<<gg, 256, 0, stream>>>(bXN, DM, sWq, nullptr, nullptr, nullptr, nullptr, bQ, M, DM, DM);
    k_gemm<false, false, false, false, false><<<gg, 256, 0, stream>>>(bXN, DM, sWk, nullptr, nullptr, nullptr, nullptr, bK, M, DM, DM);
    k_gemm<false, false, false, false, false><<<gg, 256, 0, stream>>>(bXN, DM, sWv, nullptr, nullptr, nullptr, nullptr, bO, M, DM, DM);
    k_sattn<<<T * 2 * 16, 256, 0, stream>>>(bQ, bK, bO, bV, T);  // o2 -> bV (z dead)
    k_ln<true><<<M, 256, 0, stream>>>(bXN, bV, sn2g, sn2b, bQ);  // xt2
    k_gemm<false, false, true, true, false><<<gg, 256, 0, stream>>>(bQ, DM, sW1, sb1, nullptr, nullptr, nullptr, bK, M, DM, DM);
    k_gemm<false, false, true, false, true><<<gg, 256, 0, stream>>>(bK, DM, sW2, sb2, nullptr, nullptr, bQ, bXN, M, DM, DM);  // z2
    k_gemm<false, false, false, false, false><<<gg, 256, 0, stream>>>(bXN, DM, temp_W, nullptr, nullptr, nullptr, nullptr, bK, M, DM, DM);  // hh
    k_tpool<<<NS, 256, 0, stream>>>(bK, bXN, pooled, T, s * DM);
  }

  // fused = pooled @ fus_W + fus_b ; out = relu(LN(fused)) @ dec_W + dec_b
  k_gemm<false, false, true, false, false><<<dim3(1024 / 64, 4), 256, 0, stream>>>(
      pooled, 3 * DM, fus_W, fus_b, nullptr, nullptr, nullptr, fused, 1024, DM, 3 * DM);
  k_final<<<NS, 256, 0, stream>>>(fused, fus_g, fus_bb, dec_W, dec_b, (float*)d_out);
}

// Round 2
// 2602.460 us; speedup vs baseline: 1.7487x; 1.7487x over previous
//
#include <hip/hip_runtime.h>
#include <math.h>

#define NS 1024
#define T0 32
#define DF 158
#define DG 63
#define DM 256
#define XROW (DF + DG)  // 221

typedef __attribute__((ext_vector_type(8))) short bf16x8_t;
typedef __attribute__((ext_vector_type(4))) float f32x4_t;

union frag_u {
  bf16x8_t f;
  unsigned short us[8];
  unsigned int u32[4];
};

__device__ inline unsigned short f2bf(float x) {
  unsigned int u = __float_as_uint(x);
  unsigned int r = u + 0x7fffu + ((u >> 16) & 1u);
  return (unsigned short)(r >> 16);
}
__device__ inline unsigned int pkbf(float lo, float hi) {
  return (unsigned int)f2bf(lo) | ((unsigned int)f2bf(hi) << 16);
}

// ---------------- positional encoding table (32 x 256) ----------------
__global__ void k_pe(float* __restrict__ pe) {
  int t = blockIdx.x, d = threadIdx.x;
  int i2 = d & ~1;
  float div = expf((float)i2 * (-logf(10000.0f) / (float)DM));
  float ang = (float)t * div;
  pe[t * DM + d] = (d & 1) ? cosf(ang) : sinf(ang);
}

// ---------------- gate ----------------
__global__ void k_gate(const float* __restrict__ x, const float* __restrict__ gW,
                       const float* __restrict__ gb, float* __restrict__ g) {
  int n = blockIdx.x, tid = threadIdx.x;
  __shared__ float gin[DG];
  __shared__ float red[256];
  if (tid < DG) gin[tid] = x[(size_t)n * T0 * XROW + 31 * XROW + DF + tid];
  __syncthreads();
  float myv = 0.f;
  if (tid < DF) {
    float acc = gb[tid];
    for (int j = 0; j < DG; j++) acc = fmaf(gin[j], gW[j * DF + tid], acc);
    myv = acc * (1.0f / 5.0f);
  }
  red[tid] = (tid < DF) ? myv : -1e30f;
  __syncthreads();
  for (int s = 128; s > 0; s >>= 1) { if (tid < s) red[tid] = fmaxf(red[tid], red[tid + s]); __syncthreads(); }
  float mx = red[0];
  __syncthreads();
  float e = (tid < DF) ? expf(myv - mx) : 0.f;
  red[tid] = e;
  __syncthreads();
  for (int s = 128; s > 0; s >>= 1) { if (tid < s) red[tid] += red[tid + s]; __syncthreads(); }
  float sum = red[0];
  if (tid < DF) g[(size_t)n * DF + tid] = (float)DF * e / sum;
}

// ---------------- generic fp32 GEMM ----------------
template <bool GATE, bool PE, bool BIAS, bool RELU, bool RES>
__global__ __launch_bounds__(256) void k_gemm(
    const float* __restrict__ A, int lda, const float* __restrict__ B,
    const float* __restrict__ bias, const float* __restrict__ pe,
    const float* __restrict__ gate, const float* __restrict__ res,
    float* __restrict__ C, int M, int N, int K) {
  __shared__ float As[16][65];
  __shared__ float Bs[16][64];
  int tid = threadIdx.x;
  int tx = tid & 15, ty = tid >> 4;
  int row0 = blockIdx.x * 64, col0 = blockIdx.y * 64;
  float acc[4][4] = {};
  for (int k0 = 0; k0 < K; k0 += 16) {
#pragma unroll
    for (int i = 0; i < 4; i++) {
      int idx = tid + i * 256;
      int m = idx >> 4, kk = idx & 15;
      int gk = k0 + kk;
      float val = 0.f;
      if (gk < K) {
        int grow = row0 + m;
        val = A[(size_t)grow * lda + gk];
        if (GATE) val *= gate[(size_t)(grow >> 5) * DF + gk];
      }
      As[kk][m] = val;
    }
#pragma unroll
    for (int i = 0; i < 4; i++) {
      int idx = tid + i * 256;
      int kk = idx >> 6, nn = idx & 63;
      int gk = k0 + kk;
      Bs[kk][nn] = (gk < K) ? B[(size_t)gk * N + col0 + nn] : 0.f;
    }
    __syncthreads();
#pragma unroll
    for (int kk = 0; kk < 16; kk++) {
      float a[4], b[4];
#pragma unroll
      for (int i = 0; i < 4; i++) a[i] = As[kk][ty * 4 + i];
#pragma unroll
      for (int j = 0; j < 4; j++) b[j] = Bs[kk][tx * 4 + j];
#pragma unroll
      for (int i = 0; i < 4; i++)
#pragma unroll
        for (int j = 0; j < 4; j++) acc[i][j] = fmaf(a[i], b[j], acc[i][j]);
    }
    __syncthreads();
  }
#pragma unroll
  for (int i = 0; i < 4; i++) {
    int row = row0 + ty * 4 + i;
#pragma unroll
    for (int j = 0; j < 4; j++) {
      int col = col0 + tx * 4 + j;
      float v = acc[i][j];
      if (BIAS) v += bias[col];
      if (PE) v += pe[(row & (T0 - 1)) * DM + col];
      if (RES) v += res[(size_t)row * N + col];
      if (RELU) v = fmaxf(v, 0.f);
      C[(size_t)row * N + col] = v;
    }
  }
}

// ---------------- LayerNorm ----------------
template <bool RES_IN>
__global__ __launch_bounds__(256) void k_ln(const float* __restrict__ a, const float* __restrict__ b,
                                            const float* __restrict__ g, const float* __restrict__ be,
                                            float* __restrict__ out) {
  int row = blockIdx.x, tid = threadIdx.x;
  size_t base = (size_t)row * DM;
  float v = a[base + tid];
  if (RES_IN) v += b[base + tid];
  __shared__ float red[256];
  red[tid] = v;
  __syncthreads();
  for (int s = 128; s > 0; s >>= 1) { if (tid < s) red[tid] += red[tid + s]; __syncthreads(); }
  float mean = red[0] * (1.0f / DM);
  __syncthreads();
  float d = v - mean;
  red[tid] = d * d;
  __syncthreads();
  for (int s = 128; s > 0; s >>= 1) { if (tid < s) red[tid] += red[tid + s]; __syncthreads(); }
  float var = red[0] * (1.0f / DM);
  out[base + tid] = d * rsqrtf(var + 1e-5f) * g[tid] + be[tid];
}

// ---------------- mean-pool over time groups ----------------
__global__ void k_poolmean(const float* __restrict__ h, float* __restrict__ out, int Tout, int P) {
  int idx = blockIdx.x * 256 + threadIdx.x;
  int d = idx & 255;
  int tmp = idx >> 8;
  int to = tmp % Tout;
  int n = tmp / Tout;
  int Tin = Tout * P;
  float s = 0.f;
  for (int p = 0; p < P; p++) s += h[((size_t)(n * Tin + to * P + p)) * DM + d];
  out[idx] = s / (float)P;
}

// ---------------- time attention (per stock, nhead=4, dh=64) ----------------
template <int T>
__global__ __launch_bounds__(256) void k_tattn(const float* __restrict__ q, const float* __restrict__ k,
                                               const float* __restrict__ v, float* __restrict__ o) {
  int b = blockIdx.x;
  int n = b >> 2, h = b & 3;
  int tid = threadIdx.x;
  __shared__ float qs[T][65], ks[T][65], vs[T][65], sc[T][T + 1];
  for (int idx = tid; idx < T * 64; idx += 256) {
    int t = idx >> 6, d = idx & 63;
    size_t gi = ((size_t)(n * T + t)) * DM + h * 64 + d;
    qs[t][d] = q[gi];
    ks[t][d] = k[gi];
    vs[t][d] = v[gi];
  }
  __syncthreads();
  for (int idx = tid; idx < T * T; idx += 256) {
    int i = idx / T, j = idx % T;
    float s = 0.f;
#pragma unroll
    for (int d = 0; d < 64; d++) s = fmaf(qs[i][d], ks[j][d], s);
    sc[i][j] = s * 0.125f;
  }
  __syncthreads();
  if (tid < T) {
    float mx = -1e30f;
    for (int j = 0; j < T; j++) mx = fmaxf(mx, sc[tid][j]);
    float sum = 0.f;
    for (int j = 0; j < T; j++) { float e = expf(sc[tid][j] - mx); sc[tid][j] = e; sum += e; }
    float inv = 1.0f / sum;
    for (int j = 0; j < T; j++) sc[tid][j] *= inv;
  }
  __syncthreads();
  for (int idx = tid; idx < T * 64; idx += 256) {
    int i = idx >> 6, d = idx & 63;
    float s = 0.f;
#pragma unroll
    for (int j = 0; j < T; j++) s = fmaf(sc[i][j], vs[j][d], s);
    o[((size_t)(n * T + i)) * DM + h * 64 + d] = s;
  }
}

// ---------------- stock attention, bf16 MFMA flash ----------------
// Block: one (t,h), 64-query tile (4 waves x 16 queries). KV tile = 64 keys.
// Swapped QK^T: S^T tile = mfma(A=K[16x32], B=Q^T[32x16]) -> lane holds q=lane&15,
// keys sub*16 + 4*(lane>>4) + reg. Softmax reduce: 16 regs local + shfl_xor 16/32.
// P redistributed through 2KB/wave LDS into A-frag layout for O = P@V.
__global__ __launch_bounds__(256) void k_sattn(const float* __restrict__ q, const float* __restrict__ k,
                                               const float* __restrict__ v, float* __restrict__ o, int T) {
  __shared__ __align__(16) unsigned char smem[40960];
  unsigned char* Ks = smem;            // 64 x 128 bf16, XOR-swizzled rows (16KB)
  unsigned char* Vt = smem + 16384;    // 128 x 64 bf16 (V transposed), swizzled (16KB)
  unsigned char* Ps = smem + 32768;    // 4 waves x 2KB

  const int NTH = T * 2;
  int bid = blockIdx.x;
  // XCD-aware swizzle: keep all 16 query-blocks of one (t,h) on one XCD.
  int xcd = bid & 7, slot = bid >> 3;
  int th = xcd * (NTH >> 3) + (slot >> 4);
  int qb = slot & 15;
  int t = th >> 1, h = th & 1;

  int tid = threadIdx.x;
  int lane = tid & 63;
  int wid = tid >> 6;
  int qi = lane & 15;
  int g = lane >> 4;
  const float invtemp = 0.08838834764831845f;  // 1/sqrt(128)

  const size_t rs = (size_t)T * 256;
  const float* qp = q + (size_t)t * 256 + h * 128;
  const float* kp = k + (size_t)t * 256 + h * 128;
  const float* vp = v + (size_t)t * 256 + h * 128;
  float* op = o + (size_t)t * 256 + h * 128;

  int q0 = qb * 64 + wid * 16;

  // ---- Q fragments (B-operand): lane holds Q[q0+qi][kst*32 + 8g + e], e=0..7
  bf16x8_t Qf[4];
  {
    const float* src = qp + (size_t)(q0 + qi) * rs + g * 8;
#pragma unroll
    for (int kst = 0; kst < 4; kst++) {
      f32x4_t a = *(const f32x4_t*)(src + kst * 32);
      f32x4_t b = *(const f32x4_t*)(src + kst * 32 + 4);
      frag_u f;
#pragma unroll
      for (int i = 0; i < 4; i++) {
        f.us[i] = f2bf(a[i] * invtemp);
        f.us[4 + i] = f2bf(b[i] * invtemp);
      }
      Qf[kst] = f.f;
    }
  }

  f32x4_t Oacc[8];
#pragma unroll
  for (int i = 0; i < 8; i++) Oacc[i] = (f32x4_t){0.f, 0.f, 0.f, 0.f};
  float mrun = -3.0e38f, lrun = 0.f;
  const int pbase = wid * 2048;

  for (int kb = 0; kb < NS; kb += 64) {
    __syncthreads();
    // ---- stage K tile: rows=keys, 128 dims bf16, row-swizzled
#pragma unroll
    for (int i = 0; i < 4; i++) {
      int cid = tid + i * 256;
      int row = cid >> 4, ch = cid & 15;
      const float* sp = kp + (size_t)(kb + row) * rs + ch * 8;
      f32x4_t a = *(const f32x4_t*)sp;
      f32x4_t b = *(const f32x4_t*)(sp + 4);
      frag_u f;
#pragma unroll
      for (int j = 0; j < 4; j++) {
        f.us[j] = f2bf(a[j]);
        f.us[4 + j] = f2bf(b[j]);
      }
      *(bf16x8_t*)(Ks + row * 256 + ((ch * 16) ^ ((row & 7) << 4))) = f.f;
    }
    // ---- stage V tile transposed: Vt[d][key], key-pairs packed as u32
    {
      int kpair = tid & 31, dg = tid >> 5;
      int d0 = dg * 16;
      const float* s0 = vp + (size_t)(kb + 2 * kpair) * rs + d0;
      const float* s1 = s0 + rs;
      float r0[16], r1[16];
#pragma unroll
      for (int i = 0; i < 4; i++) {
        *(f32x4_t*)&r0[i * 4] = *(const f32x4_t*)(s0 + i * 4);
        *(f32x4_t*)&r1[i * 4] = *(const f32x4_t*)(s1 + i * 4);
      }
#pragma unroll
      for (int i = 0; i < 16; i++) {
        int d = d0 + i;
        *(unsigned int*)(Vt + d * 128 + ((kpair * 4) ^ ((d & 7) << 4))) = pkbf(r0[i], r1[i]);
      }
    }
    __syncthreads();

    // ---- QK^T (swapped): sacc[sub] = S^T[sub*16+keys][16 queries]
    f32x4_t sacc[4];
#pragma unroll
    for (int i = 0; i < 4; i++) sacc[i] = (f32x4_t){0.f, 0.f, 0.f, 0.f};
#pragma unroll
    for (int sub = 0; sub < 4; sub++) {
      int row = sub * 16 + qi;
      int swz = (row & 7) << 4;
      const unsigned char* kr = Ks + row * 256;
#pragma unroll
      for (int kst = 0; kst < 4; kst++) {
        bf16x8_t Af = *(const bf16x8_t*)(kr + ((g * 16 + kst * 64) ^ swz));
        sacc[sub] = __builtin_amdgcn_mfma_f32_16x16x32_bf16(Af, Qf[kst], sacc[sub], 0, 0, 0);
      }
    }

    // ---- online softmax (lane owns 16 keys of query qi)
    float mx = -3.0e38f;
#pragma unroll
    for (int sub = 0; sub < 4; sub++)
#pragma unroll
      for (int r = 0; r < 4; r++) mx = fmaxf(mx, sacc[sub][r]);
    mx = fmaxf(mx, __shfl_xor(mx, 16));
    mx = fmaxf(mx, __shfl_xor(mx, 32));
    float mnew = fmaxf(mrun, mx);
    float fac = __expf(mrun - mnew);
    float p[4][4];
    float ls = 0.f;
#pragma unroll
    for (int sub = 0; sub < 4; sub++)
#pragma unroll
      for (int r = 0; r < 4; r++) {
        float e = __expf(sacc[sub][r] - mnew);
        p[sub][r] = e;
        ls += e;
      }
    ls += __shfl_xor(ls, 16);
    ls += __shfl_xor(ls, 32);
    lrun = lrun * fac + ls;
    mrun = mnew;
    // rescale O (O-acc rows are q' = 4g + reg -> fetch factor per reg)
    float fr[4];
#pragma unroll
    for (int r = 0; r < 4; r++) fr[r] = __shfl(fac, (g << 2) | r);
#pragma unroll
    for (int dsub = 0; dsub < 8; dsub++)
#pragma unroll
      for (int r = 0; r < 4; r++) Oacc[dsub][r] *= fr[r];

    // ---- redistribute P into A-frag layout: [kst][g][q][e] bf16, e = key&7
    // source: key = 16*sub + 4*g' + r  ->  kst=key>>5, gdst=(key>>3)&3, e=key&7
#pragma unroll
    for (int s = 0; s < 4; s++) {
      int kst = s >> 1;
      int gdst = (2 * s + (g >> 1)) & 3;
      int rowbyte = pbase + (kst * 4 + gdst) * 256 + qi * 16 + (g & 1) * 8;
      *(unsigned int*)(Ps + rowbyte) = pkbf(p[s][0], p[s][1]);
      *(unsigned int*)(Ps + rowbyte + 4) = pkbf(p[s][2], p[s][3]);
    }

    // ---- O += P @ V
#pragma unroll
    for (int kst = 0; kst < 2; kst++) {
      bf16x8_t Pa = *(const bf16x8_t*)(Ps + pbase + (kst * 4 + g) * 256 + qi * 16);
#pragma unroll
      for (int dsub = 0; dsub < 8; dsub++) {
        int row = dsub * 16 + qi;
        bf16x8_t Vb = *(const bf16x8_t*)(Vt + row * 128 + ((g * 16 + kst * 64) ^ ((row & 7) << 4)));
        Oacc[dsub] = __builtin_amdgcn_mfma_f32_16x16x32_bf16(Pa, Vb, Oacc[dsub], 0, 0, 0);
      }
    }
  }

  // ---- epilogue: O /= l, write out. O rows are q' = 4g + r, cols d = dsub*16 + qi.
  float rin[4];
#pragma unroll
  for (int r = 0; r < 4; r++) rin[r] = 1.0f / __shfl(lrun, (g << 2) | r);
#pragma unroll
  for (int dsub = 0; dsub < 8; dsub++)
#pragma unroll
    for (int r = 0; r < 4; r++) {
      size_t row = (size_t)(q0 + 4 * g + r);
      op[row * rs + dsub * 16 + qi] = Oacc[dsub][r] * rin[r];
    }
}

// ---------------- temporal pooling ----------------
__global__ __launch_bounds__(256) void k_tpool(const float* __restrict__ hh, const float* __restrict__ z,
                                               float* __restrict__ pooled, int T, int off) {
  int n = blockIdx.x, d = threadIdx.x;
  __shared__ float red[256];
  __shared__ float lam[T0];
  __shared__ float lame[T0];
  float last = hh[((size_t)(n * T + T - 1)) * DM + d];
  for (int t = 0; t < T; t++) {
    red[d] = hh[((size_t)(n * T + t)) * DM + d] * last;
    __syncthreads();
    for (int s = 128; s > 0; s >>= 1) { if (d < s) red[d] += red[d + s]; __syncthreads(); }
    if (d == 0) lam[t] = red[0];
    __syncthreads();
  }
  float mx = -1e30f;
  for (int t = 0; t < T; t++) mx = fmaxf(mx, lam[t]);
  if (d < T) lame[d] = expf(lam[d] - mx);
  __syncthreads();
  float sum = 0.f;
  for (int t = 0; t < T; t++) sum += lame[t];
  float acc = 0.f;
  for (int t = 0; t < T; t++) acc += lame[t] * z[((size_t)(n * T + t)) * DM + d];
  pooled[(size_t)n * (3 * DM) + off + d] = acc / sum;
}

// ---------------- final ----------------
__global__ __launch_bounds__(256) void k_final(const float* __restrict__ f, const float* __restrict__ g,
                                               const float* __restrict__ b, const float* __restrict__ dw,
                                               const float* __restrict__ db, float* __restrict__ out) {
  int n = blockIdx.x, d = threadIdx.x;
  float v = f[(size_t)n * DM + d];
  __shared__ float red[256];
  red[d] = v;
  __syncthreads();
  for (int s = 128; s > 0; s >>= 1) { if (d < s) red[d] += red[d + s]; __syncthreads(); }
  float mean = red[0] * (1.0f / DM);
  __syncthreads();
  float dv = v - mean;
  red[d] = dv * dv;
  __syncthreads();
  for (int s = 128; s > 0; s >>= 1) { if (d < s) red[d] += red[d + s]; __syncthreads(); }
  float var = red[0] * (1.0f / DM);
  __syncthreads();
  float y = dv * rsqrtf(var + 1e-5f) * g[d] + b[d];
  y = fmaxf(y, 0.f);
  red[d] = y * dw[d];
  __syncthreads();
  for (int s = 128; s > 0; s >>= 1) { if (d < s) red[d] += red[d + s]; __syncthreads(); }
  if (d == 0) out[n] = red[0] + db[0];
}

extern "C" void kernel_launch(void* const* d_in, const int* in_sizes, int n_in,
                              void* d_out, int out_size, void* d_ws, size_t ws_size,
                              hipStream_t stream) {
  const float* x = (const float*)d_in[0];
  const float* gate_W = (const float*)d_in[1];
  const float* gate_b = (const float*)d_in[2];
  const float* feat_W = (const float*)d_in[3];
  const float* feat_b = (const float*)d_in[4];
  const float* ds_mid_W = (const float*)d_in[5];
  const float* ds_mid_b = (const float*)d_in[6];
  const float* ds_small_W = (const float*)d_in[7];
  const float* ds_small_b = (const float*)d_in[8];
  const float* tn1g = (const float*)d_in[9];
  const float* tn1b = (const float*)d_in[10];
  const float* tWq = (const float*)d_in[11];
  const float* tWk = (const float*)d_in[12];
  const float* tWv = (const float*)d_in[13];
  const float* tn2g = (const float*)d_in[14];
  const float* tn2b = (const float*)d_in[15];
  const float* tW1 = (const float*)d_in[16];
  const float* tb1 = (const float*)d_in[17];
  const float* tW2 = (const float*)d_in[18];
  const float* tb2 = (const float*)d_in[19];
  const float* sn1g = (const float*)d_in[20];
  const float* sn1b = (const float*)d_in[21];
  const float* sWq = (const float*)d_in[22];
  const float* sWk = (const float*)d_in[23];
  const float* sWv = (const float*)d_in[24];
  const float* sn2g = (const float*)d_in[25];
  const float* sn2b = (const float*)d_in[26];
  const float* sW1 = (const float*)d_in[27];
  const float* sb1 = (const float*)d_in[28];
  const float* sW2 = (const float*)d_in[29];
  const float* sb2 = (const float*)d_in[30];
  const float* temp_W = (const float*)d_in[31];
  const float* fus_W = (const float*)d_in[32];
  const float* fus_b = (const float*)d_in[33];
  const float* fus_g = (const float*)d_in[34];
  const float* fus_bb = (const float*)d_in[35];
  const float* dec_W = (const float*)d_in[36];
  const float* dec_b = (const float*)d_in[37];

  float* ws = (float*)d_ws;
  float* pe = ws;
  float* g = pe + 8192;
  float* h0 = g + 161792;
  float* h1 = h0 + 8388608;
  float* h2 = h1 + 4194304;
  float* bXN = h2 + 2097152;
  float* bQ = bXN + 8388608;
  float* bK = bQ + 8388608;
  float* bV = bK + 8388608;
  float* pooled = bV + 8388608;
  float* fused = pooled + 786432;
  float* bO = h0;  // alias: h0 dead once attn output is produced

  k_pe<<<T0, DM, 0, stream>>>(pe);
  k_gate<<<NS, 256, 0, stream>>>(x, gate_W, gate_b, g);

  k_gemm<true, true, true, false, false><<<dim3(32768 / 64, 4), 256, 0, stream>>>(
      x, XROW, feat_W, feat_b, pe, g, nullptr, h0, 32768, DM, DF);

  k_poolmean<<<NS * 16, 256, 0, stream>>>(h0, bXN, 16, 2);
  k_gemm<false, false, true, false, false><<<dim3(16384 / 64, 4), 256, 0, stream>>>(
      bXN, DM, ds_mid_W, ds_mid_b, nullptr, nullptr, nullptr, h1, 16384, DM, DM);
  k_poolmean<<<NS * 8, 256, 0, stream>>>(h0, bXN, 8, 4);
  k_gemm<false, false, true, false, false><<<dim3(8192 / 64, 4), 256, 0, stream>>>(
      bXN, DM, ds_small_W, ds_small_b, nullptr, nullptr, nullptr, h2, 8192, DM, DM);

  const float* hs[3] = {h0, h1, h2};
  const int Ts[3] = {32, 16, 8};
  for (int s = 0; s < 3; s++) {
    int T = Ts[s];
    int M = NS * T;
    dim3 gg(M / 64, 4);
    const float* h = hs[s];
    // ---- block 1: time attention ----
    k_ln<false><<<M, 256, 0, stream>>>(h, nullptr, tn1g, tn1b, bXN);
    k_gemm<false, false, false, false, false><<<gg, 256, 0, stream>>>(bXN, DM, tWq, nullptr, nullptr, nullptr, nullptr, bQ, M, DM, DM);
    k_gemm<false, false, false, false, false><<<gg, 256, 0, stream>>>(bXN, DM, tWk, nullptr, nullptr, nullptr, nullptr, bK, M, DM, DM);
    k_gemm<false, false, false, false, false><<<gg, 256, 0, stream>>>(bXN, DM, tWv, nullptr, nullptr, nullptr, nullptr, bV, M, DM, DM);
    if (T == 32) k_tattn<32><<<NS * 4, 256, 0, stream>>>(bQ, bK, bV, bO);
    else if (T == 16) k_tattn<16><<<NS * 4, 256, 0, stream>>>(bQ, bK, bV, bO);
    else k_tattn<8><<<NS * 4, 256, 0, stream>>>(bQ, bK, bV, bO);
    k_ln<true><<<M, 256, 0, stream>>>(bXN, bO, tn2g, tn2b, bQ);
    k_gemm<false, false, true, true, false><<<gg, 256, 0, stream>>>(bQ, DM, tW1, tb1, nullptr, nullptr, nullptr, bK, M, DM, DM);
    k_gemm<false, false, true, false, true><<<gg, 256, 0, stream>>>(bK, DM, tW2, tb2, nullptr, nullptr, bQ, bV, M, DM, DM);
    // ---- block 2: stock attention (MFMA) ----
    k_ln<false><<<M, 256, 0, stream>>>(bV, nullptr, sn1g, sn1b, bXN);
    k_gemm<false, false, false, false, false><<<gg, 256, 0, stream>>>(bXN, DM, sWq, nullptr, nullptr, nullptr, nullptr, bQ, M, DM, DM);
    k_gemm<false, false, false, false, false><<<gg, 256, 0, stream>>>(bXN, DM, sWk, nullptr, nullptr, nullptr, nullptr, bK, M, DM, DM);
    k_gemm<false, false, false, false, false><<<gg, 256, 0, stream>>>(bXN, DM, sWv, nullptr, nullptr, nullptr, nullptr, bO, M, DM, DM);
    k_sattn<<<T * 2 * 16, 256, 0, stream>>>(bQ, bK, bO, bV, T);
    k_ln<true><<<M, 256, 0, stream>>>(bXN, bV, sn2g, sn2b, bQ);
    k_gemm<false, false, true, true, false><<<gg, 256, 0, stream>>>(bQ, DM, sW1, sb1, nullptr, nullptr, nullptr, bK, M, DM, DM);
    k_gemm<false, false, true, false, true><<<gg, 256, 0, stream>>>(bK, DM, sW2, sb2, nullptr, nullptr, bQ, bXN, M, DM, DM);
    k_gemm<false, false, false, false, false><<<gg, 256, 0, stream>>>(bXN, DM, temp_W, nullptr, nullptr, nullptr, nullptr, bK, M, DM, DM);
    k_tpool<<<NS, 256, 0, stream>>>(bK, bXN, pooled, T, s * DM);
  }

  k_gemm<false, false, true, false, false><<<dim3(1024 / 64, 4), 256, 0, stream>>>(
      pooled, 3 * DM, fus_W, fus_b, nullptr, nullptr, nullptr, fused, 1024, DM, 3 * DM);
  k_final<<<NS, 256, 0, stream>>>(fused, fus_g, fus_bb, dec_W, dec_b, (float*)d_out);
}

// Round 3
// 936.159 us; speedup vs baseline: 4.8611x; 2.7799x over previous
//
#include <hip/hip_runtime.h>
#include <math.h>

#define NS 1024
#define T0 32
#define DF 158
#define DG 63
#define DM 256
#define XROW (DF + DG)  // 221

typedef unsigned short u16;
typedef __attribute__((ext_vector_type(8))) short bf16x8_t;
typedef __attribute__((ext_vector_type(4))) float f32x4_t;

union frag_u {
  bf16x8_t f;
  unsigned short us[8];
  unsigned int u32[4];
};

__device__ inline unsigned short f2bf(float x) {
  unsigned int u = __float_as_uint(x);
  unsigned int r = u + 0x7fffu + ((u >> 16) & 1u);
  return (unsigned short)(r >> 16);
}
__device__ inline unsigned int pkbf(float lo, float hi) {
  return (unsigned int)f2bf(lo) | ((unsigned int)f2bf(hi) << 16);
}
__device__ inline float bf2f(u16 u) {
  return __uint_as_float(((unsigned int)u) << 16);
}

// ---------------- positional encoding table (32 x 256) ----------------
__global__ void k_pe(float* __restrict__ pe) {
  int t = blockIdx.x, d = threadIdx.x;
  int i2 = d & ~1;
  float div = expf((float)i2 * (-logf(10000.0f) / (float)DM));
  float ang = (float)t * div;
  pe[t * DM + d] = (d & 1) ? cosf(ang) : sinf(ang);
}

// ---------------- gate ----------------
__global__ void k_gate(const float* __restrict__ x, const float* __restrict__ gW,
                       const float* __restrict__ gb, float* __restrict__ g) {
  int n = blockIdx.x, tid = threadIdx.x;
  __shared__ float gin[DG];
  __shared__ float red[256];
  if (tid < DG) gin[tid] = x[(size_t)n * T0 * XROW + 31 * XROW + DF + tid];
  __syncthreads();
  float myv = 0.f;
  if (tid < DF) {
    float acc = gb[tid];
    for (int j = 0; j < DG; j++) acc = fmaf(gin[j], gW[j * DF + tid], acc);
    myv = acc * (1.0f / 5.0f);
  }
  red[tid] = (tid < DF) ? myv : -1e30f;
  __syncthreads();
  for (int s = 128; s > 0; s >>= 1) { if (tid < s) red[tid] = fmaxf(red[tid], red[tid + s]); __syncthreads(); }
  float mx = red[0];
  __syncthreads();
  float e = (tid < DF) ? expf(myv - mx) : 0.f;
  red[tid] = e;
  __syncthreads();
  for (int s = 128; s > 0; s >>= 1) { if (tid < s) red[tid] += red[tid + s]; __syncthreads(); }
  float sum = red[0];
  if (tid < DF) g[(size_t)n * DF + tid] = (float)DF * e / sum;
}

// ---------------- weight prep: W[K][256] fp32 -> Wt[256][256] bf16 (transposed, zero-pad K) ----------------
struct WPrep { const float* s[14]; };
__global__ __launch_bounds__(256) void k_wprep(WPrep w, u16* __restrict__ dst) {
  int mat = blockIdx.x >> 4, nb = blockIdx.x & 15;
  int tid = threadIdx.x;
  int n = nb * 16 + (tid >> 4);
  int kc = (tid & 15) * 16;
  const float* src = w.s[mat];
  int K = (mat == 0) ? DF : 256;
  frag_u f0, f1;
#pragma unroll
  for (int j = 0; j < 8; j++) {
    int k0 = kc + j, k1 = kc + 8 + j;
    f0.us[j] = (k0 < K) ? f2bf(src[(size_t)k0 * 256 + n]) : (u16)0;
    f1.us[j] = (k1 < K) ? f2bf(src[(size_t)k1 * 256 + n]) : (u16)0;
  }
  u16* d = dst + (size_t)mat * 65536 + (size_t)n * 256 + kc;
  *(bf16x8_t*)d = f0.f;
  *(bf16x8_t*)(d + 8) = f1.f;
}

// ---------------- bf16 MFMA GEMM: C = act(A@Bt^T + bias + res), A[M][256] bf16, Bt[256n][256k] bf16 ----------------
// Block 128x128, 4 waves (2x2 of 64x64). blockIdx.z selects matrix (QKV fusion).
template <bool BIAS, bool RELU, bool RES, bool OUTBF>
__global__ __launch_bounds__(256) void k_bgemm(
    const u16* __restrict__ A,
    const u16* __restrict__ B0, const u16* __restrict__ B1, const u16* __restrict__ B2,
    const float* __restrict__ bias, const u16* __restrict__ res,
    void* __restrict__ C0, void* __restrict__ C1, void* __restrict__ C2) {
  __shared__ __align__(16) unsigned char sm[32768];
  unsigned char* As = sm;
  unsigned char* Bs = sm + 16384;
  const u16* Bt = blockIdx.z == 0 ? B0 : (blockIdx.z == 1 ? B1 : B2);
  void* Cv = blockIdx.z == 0 ? C0 : (blockIdx.z == 1 ? C1 : C2);
  int m0 = blockIdx.x * 128, n0w = blockIdx.y * 128;
  int tid = threadIdx.x, lane = tid & 63, wid = tid >> 6;
  int qi = lane & 15, g = lane >> 4;
  int wr = wid >> 1, wc = wid & 1;
  f32x4_t acc[4][4];
#pragma unroll
  for (int i = 0; i < 4; i++)
#pragma unroll
    for (int j = 0; j < 4; j++) acc[i][j] = (f32x4_t){0.f, 0.f, 0.f, 0.f};
  for (int kt = 0; kt < 4; kt++) {
    if (kt) __syncthreads();
#pragma unroll
    for (int i = 0; i < 4; i++) {
      int cid = tid + i * 256;
      int row = cid >> 3, c = cid & 7;
      int swz = (c * 16) ^ ((row & 7) << 4);
      bf16x8_t va = *(const bf16x8_t*)(A + (size_t)(m0 + row) * 256 + kt * 64 + c * 8);
      *(bf16x8_t*)(As + row * 128 + swz) = va;
      bf16x8_t vb = *(const bf16x8_t*)(Bt + (size_t)(n0w + row) * 256 + kt * 64 + c * 8);
      *(bf16x8_t*)(Bs + row * 128 + swz) = vb;
    }
    __syncthreads();
    bf16x8_t Af[2][4], Bf[2][4];
#pragma unroll
    for (int mi = 0; mi < 4; mi++) {
      int row = wr * 64 + mi * 16 + qi;
      int swz = (row & 7) << 4;
      const unsigned char* ap = As + row * 128;
      Af[0][mi] = *(const bf16x8_t*)(ap + ((g * 16) ^ swz));
      Af[1][mi] = *(const bf16x8_t*)(ap + ((64 + g * 16) ^ swz));
    }
#pragma unroll
    for (int ni = 0; ni < 4; ni++) {
      int row = wc * 64 + ni * 16 + qi;
      int swz = (row & 7) << 4;
      const unsigned char* bp = Bs + row * 128;
      Bf[0][ni] = *(const bf16x8_t*)(bp + ((g * 16) ^ swz));
      Bf[1][ni] = *(const bf16x8_t*)(bp + ((64 + g * 16) ^ swz));
    }
#pragma unroll
    for (int ks = 0; ks < 2; ks++)
#pragma unroll
      for (int mi = 0; mi < 4; mi++)
#pragma unroll
        for (int ni = 0; ni < 4; ni++)
          acc[mi][ni] = __builtin_amdgcn_mfma_f32_16x16x32_bf16(Af[ks][mi], Bf[ks][ni], acc[mi][ni], 0, 0, 0);
  }
#pragma unroll
  for (int mi = 0; mi < 4; mi++) {
#pragma unroll
    for (int ni = 0; ni < 4; ni++) {
#pragma unroll
      for (int r = 0; r < 4; r++) {
        int row = m0 + wr * 64 + mi * 16 + 4 * g + r;
        int col = n0w + wc * 64 + ni * 16 + qi;
        float vv = acc[mi][ni][r];
        if (BIAS) vv += bias[col];
        if (RES) vv += bf2f(res[(size_t)row * 256 + col]);
        if (RELU) vv = fmaxf(vv, 0.f);
        if (OUTBF) ((u16*)Cv)[(size_t)row * 256 + col] = f2bf(vv);
        else ((float*)Cv)[(size_t)row * 256 + col] = vv;
      }
    }
  }
}

// ---------------- feat GEMM: h = (x*gate)@feat_W + bias + pe, fp32 out ----------------
__global__ __launch_bounds__(256) void k_fgemm(
    const float* __restrict__ x, const float* __restrict__ gate,
    const u16* __restrict__ Bt, const float* __restrict__ bias,
    const float* __restrict__ pe, float* __restrict__ C) {
  __shared__ __align__(16) unsigned char sm[32768];
  unsigned char* As = sm;
  unsigned char* Bs = sm + 16384;
  int m0 = blockIdx.x * 128, n0w = blockIdx.y * 128;
  int tid = threadIdx.x, lane = tid & 63, wid = tid >> 6;
  int qi = lane & 15, g = lane >> 4;
  int wr = wid >> 1, wc = wid & 1;
  f32x4_t acc[4][4];
#pragma unroll
  for (int i = 0; i < 4; i++)
#pragma unroll
    for (int j = 0; j < 4; j++) acc[i][j] = (f32x4_t){0.f, 0.f, 0.f, 0.f};
  for (int kt = 0; kt < 3; kt++) {
    if (kt) __syncthreads();
#pragma unroll
    for (int i = 0; i < 4; i++) {
      int cid = tid + i * 256;
      int row = cid >> 3, c = cid & 7;
      int swz = (c * 16) ^ ((row & 7) << 4);
      int gk0 = kt * 64 + c * 8;
      const float* xr = x + (size_t)(m0 + row) * XROW;
      const float* gr = gate + (size_t)((m0 + row) >> 5) * DF;
      frag_u f;
#pragma unroll
      for (int j = 0; j < 8; j++) {
        int gk = gk0 + j;
        f.us[j] = (gk < DF) ? f2bf(xr[gk] * gr[gk]) : (u16)0;
      }
      *(bf16x8_t*)(As + row * 128 + swz) = f.f;
      bf16x8_t vb = *(const bf16x8_t*)(Bt + (size_t)(n0w + row) * 256 + kt * 64 + c * 8);
      *(bf16x8_t*)(Bs + row * 128 + swz) = vb;
    }
    __syncthreads();
    bf16x8_t Af[2][4], Bf[2][4];
#pragma unroll
    for (int mi = 0; mi < 4; mi++) {
      int row = wr * 64 + mi * 16 + qi;
      int swz = (row & 7) << 4;
      const unsigned char* ap = As + row * 128;
      Af[0][mi] = *(const bf16x8_t*)(ap + ((g * 16) ^ swz));
      Af[1][mi] = *(const bf16x8_t*)(ap + ((64 + g * 16) ^ swz));
    }
#pragma unroll
    for (int ni = 0; ni < 4; ni++) {
      int row = wc * 64 + ni * 16 + qi;
      int swz = (row & 7) << 4;
      const unsigned char* bp = Bs + row * 128;
      Bf[0][ni] = *(const bf16x8_t*)(bp + ((g * 16) ^ swz));
      Bf[1][ni] = *(const bf16x8_t*)(bp + ((64 + g * 16) ^ swz));
    }
#pragma unroll
    for (int ks = 0; ks < 2; ks++)
#pragma unroll
      for (int mi = 0; mi < 4; mi++)
#pragma unroll
        for (int ni = 0; ni < 4; ni++)
          acc[mi][ni] = __builtin_amdgcn_mfma_f32_16x16x32_bf16(Af[ks][mi], Bf[ks][ni], acc[mi][ni], 0, 0, 0);
  }
#pragma unroll
  for (int mi = 0; mi < 4; mi++) {
#pragma unroll
    for (int ni = 0; ni < 4; ni++) {
#pragma unroll
      for (int r = 0; r < 4; r++) {
        int row = m0 + wr * 64 + mi * 16 + 4 * g + r;
        int col = n0w + wc * 64 + ni * 16 + qi;
        float vv = acc[mi][ni][r] + bias[col] + pe[(row & (T0 - 1)) * DM + col];
        C[(size_t)row * 256 + col] = vv;
      }
    }
  }
}

// ---------------- fp32 GEMM (fus only) ----------------
template <bool GATE, bool PE, bool BIAS, bool RELU, bool RES>
__global__ __launch_bounds__(256) void k_gemm(
    const float* __restrict__ A, int lda, const float* __restrict__ B,
    const float* __restrict__ bias, const float* __restrict__ pe,
    const float* __restrict__ gate, const float* __restrict__ res,
    float* __restrict__ C, int M, int N, int K) {
  __shared__ float As[16][65];
  __shared__ float Bs[16][64];
  int tid = threadIdx.x;
  int tx = tid & 15, ty = tid >> 4;
  int row0 = blockIdx.x * 64, col0 = blockIdx.y * 64;
  float acc[4][4] = {};
  for (int k0 = 0; k0 < K; k0 += 16) {
#pragma unroll
    for (int i = 0; i < 4; i++) {
      int idx = tid + i * 256;
      int m = idx >> 4, kk = idx & 15;
      int gk = k0 + kk;
      float val = 0.f;
      if (gk < K) {
        int grow = row0 + m;
        val = A[(size_t)grow * lda + gk];
        if (GATE) val *= gate[(size_t)(grow >> 5) * DF + gk];
      }
      As[kk][m] = val;
    }
#pragma unroll
    for (int i = 0; i < 4; i++) {
      int idx = tid + i * 256;
      int kk = idx >> 6, nn = idx & 63;
      int gk = k0 + kk;
      Bs[kk][nn] = (gk < K) ? B[(size_t)gk * N + col0 + nn] : 0.f;
    }
    __syncthreads();
#pragma unroll
    for (int kk = 0; kk < 16; kk++) {
      float a[4], b[4];
#pragma unroll
      for (int i = 0; i < 4; i++) a[i] = As[kk][ty * 4 + i];
#pragma unroll
      for (int j = 0; j < 4; j++) b[j] = Bs[kk][tx * 4 + j];
#pragma unroll
      for (int i = 0; i < 4; i++)
#pragma unroll
        for (int j = 0; j < 4; j++) acc[i][j] = fmaf(a[i], b[j], acc[i][j]);
    }
    __syncthreads();
  }
#pragma unroll
  for (int i = 0; i < 4; i++) {
    int row = row0 + ty * 4 + i;
#pragma unroll
    for (int j = 0; j < 4; j++) {
      int col = col0 + tx * 4 + j;
      float v = acc[i][j];
      if (BIAS) v += bias[col];
      if (PE) v += pe[(row & (T0 - 1)) * DM + col];
      if (RES) v += res[(size_t)row * N + col];
      if (RELU) v = fmaxf(v, 0.f);
      C[(size_t)row * N + col] = v;
    }
  }
}

// ---------------- LayerNorm: out bf16; a fp32 or bf16; optional fp32 residual ----------------
template <bool RES, bool ABF>
__global__ __launch_bounds__(256) void k_ln(const void* __restrict__ a, const float* __restrict__ b,
                                            const float* __restrict__ g, const float* __restrict__ be,
                                            u16* __restrict__ out) {
  int row = blockIdx.x, tid = threadIdx.x;
  size_t base = (size_t)row * DM + tid;
  float v = ABF ? bf2f(((const u16*)a)[base]) : ((const float*)a)[base];
  if (RES) v += b[base];
  __shared__ float red[256];
  red[tid] = v;
  __syncthreads();
  for (int s = 128; s > 0; s >>= 1) { if (tid < s) red[tid] += red[tid + s]; __syncthreads(); }
  float mean = red[0] * (1.0f / DM);
  __syncthreads();
  float d = v - mean;
  red[tid] = d * d;
  __syncthreads();
  for (int s = 128; s > 0; s >>= 1) { if (tid < s) red[tid] += red[tid + s]; __syncthreads(); }
  float var = red[0] * (1.0f / DM);
  out[base] = f2bf(d * rsqrtf(var + 1e-5f) * g[tid] + be[tid]);
}

// ---------------- mean-pool over time groups (bf16 out) ----------------
__global__ void k_poolmean(const float* __restrict__ h, u16* __restrict__ out, int Tout, int P) {
  int idx = blockIdx.x * 256 + threadIdx.x;
  int d = idx & 255;
  int tmp = idx >> 8;
  int to = tmp % Tout;
  int n = tmp / Tout;
  int Tin = Tout * P;
  float s = 0.f;
  for (int p = 0; p < P; p++) s += h[((size_t)(n * Tin + to * P + p)) * DM + d];
  out[idx] = f2bf(s / (float)P);
}

// ---------------- time attention (bf16 in, fp32 out) ----------------
template <int T>
__global__ __launch_bounds__(256) void k_tattn(const u16* __restrict__ q, const u16* __restrict__ k,
                                               const u16* __restrict__ v, float* __restrict__ o) {
  int b = blockIdx.x;
  int n = b >> 2, h = b & 3;
  int tid = threadIdx.x;
  __shared__ float qs[T][65], ks[T][65], vs[T][65], sc[T][T + 1];
  for (int idx = tid; idx < T * 64; idx += 256) {
    int t = idx >> 6, d = idx & 63;
    size_t gi = ((size_t)(n * T + t)) * DM + h * 64 + d;
    qs[t][d] = bf2f(q[gi]);
    ks[t][d] = bf2f(k[gi]);
    vs[t][d] = bf2f(v[gi]);
  }
  __syncthreads();
  for (int idx = tid; idx < T * T; idx += 256) {
    int i = idx / T, j = idx % T;
    float s = 0.f;
#pragma unroll
    for (int d = 0; d < 64; d++) s = fmaf(qs[i][d], ks[j][d], s);
    sc[i][j] = s * 0.125f;
  }
  __syncthreads();
  if (tid < T) {
    float mx = -1e30f;
    for (int j = 0; j < T; j++) mx = fmaxf(mx, sc[tid][j]);
    float sum = 0.f;
    for (int j = 0; j < T; j++) { float e = expf(sc[tid][j] - mx); sc[tid][j] = e; sum += e; }
    float inv = 1.0f / sum;
    for (int j = 0; j < T; j++) sc[tid][j] *= inv;
  }
  __syncthreads();
  for (int idx = tid; idx < T * 64; idx += 256) {
    int i = idx >> 6, d = idx & 63;
    float s = 0.f;
#pragma unroll
    for (int j = 0; j < T; j++) s = fmaf(sc[i][j], vs[j][d], s);
    o[((size_t)(n * T + i)) * DM + h * 64 + d] = s;
  }
}

// ---------------- stock attention, bf16 MFMA flash (bf16 in, fp32 out) ----------------
__global__ __launch_bounds__(256) void k_sattn(const u16* __restrict__ q, const u16* __restrict__ k,
                                               const u16* __restrict__ v, float* __restrict__ o, int T) {
  __shared__ __align__(16) unsigned char smem[40960];
  unsigned char* Ks = smem;
  unsigned char* Vt = smem + 16384;
  unsigned char* Ps = smem + 32768;

  const int NTH = T * 2;
  int bid = blockIdx.x;
  int xcd = bid & 7, slot = bid >> 3;
  int th = xcd * (NTH >> 3) + (slot >> 4);
  int qb = slot & 15;
  int t = th >> 1, h = th & 1;

  int tid = threadIdx.x;
  int lane = tid & 63;
  int wid = tid >> 6;
  int qi = lane & 15;
  int g = lane >> 4;
  const float invtemp = 0.08838834764831845f;

  const size_t rs = (size_t)T * 256;
  const u16* qp = q + (size_t)t * 256 + h * 128;
  const u16* kp = k + (size_t)t * 256 + h * 128;
  const u16* vp = v + (size_t)t * 256 + h * 128;
  float* op = o + (size_t)t * 256 + h * 128;

  int q0 = qb * 64 + wid * 16;

  bf16x8_t Qf[4];
  {
    const u16* src = qp + (size_t)(q0 + qi) * rs + g * 8;
#pragma unroll
    for (int kst = 0; kst < 4; kst++) Qf[kst] = *(const bf16x8_t*)(src + kst * 32);
  }

  f32x4_t Oacc[8];
#pragma unroll
  for (int i = 0; i < 8; i++) Oacc[i] = (f32x4_t){0.f, 0.f, 0.f, 0.f};
  float mrun = -3.0e38f, lrun = 0.f;
  const int pbase = wid * 2048;

  for (int kb = 0; kb < NS; kb += 64) {
    __syncthreads();
    // stage K tile (bf16 copy, swizzled)
#pragma unroll
    for (int i = 0; i < 4; i++) {
      int cid = tid + i * 256;
      int row = cid >> 4, ch = cid & 15;
      bf16x8_t kv = *(const bf16x8_t*)(kp + (size_t)(kb + row) * rs + ch * 8);
      *(bf16x8_t*)(Ks + row * 256 + ((ch * 16) ^ ((row & 7) << 4))) = kv;
    }
    // stage V transposed: Vt[d][key-pair u32]
    {
      int kpair = tid & 31, dg = tid >> 5;
      int d0 = dg * 16;
      const u16* s0 = vp + (size_t)(kb + 2 * kpair) * rs + d0;
      const u16* s1 = s0 + rs;
      frag_u a0, a1, b0, b1;
      a0.f = *(const bf16x8_t*)s0;
      a1.f = *(const bf16x8_t*)(s0 + 8);
      b0.f = *(const bf16x8_t*)s1;
      b1.f = *(const bf16x8_t*)(s1 + 8);
#pragma unroll
      for (int i = 0; i < 8; i++) {
        int d = d0 + i;
        *(unsigned int*)(Vt + d * 128 + ((kpair * 4) ^ ((d & 7) << 4))) =
            (unsigned int)a0.us[i] | ((unsigned int)b0.us[i] << 16);
      }
#pragma unroll
      for (int i = 0; i < 8; i++) {
        int d = d0 + 8 + i;
        *(unsigned int*)(Vt + d * 128 + ((kpair * 4) ^ ((d & 7) << 4))) =
            (unsigned int)a1.us[i] | ((unsigned int)b1.us[i] << 16);
      }
    }
    __syncthreads();

    f32x4_t sacc[4];
#pragma unroll
    for (int i = 0; i < 4; i++) sacc[i] = (f32x4_t){0.f, 0.f, 0.f, 0.f};
#pragma unroll
    for (int sub = 0; sub < 4; sub++) {
      int row = sub * 16 + qi;
      int swz = (row & 7) << 4;
      const unsigned char* kr = Ks + row * 256;
#pragma unroll
      for (int kst = 0; kst < 4; kst++) {
        bf16x8_t Af = *(const bf16x8_t*)(kr + ((g * 16 + kst * 64) ^ swz));
        sacc[sub] = __builtin_amdgcn_mfma_f32_16x16x32_bf16(Af, Qf[kst], sacc[sub], 0, 0, 0);
      }
    }

    float sv[4][4];
    float mx = -3.0e38f;
#pragma unroll
    for (int sub = 0; sub < 4; sub++)
#pragma unroll
      for (int r = 0; r < 4; r++) {
        sv[sub][r] = sacc[sub][r] * invtemp;
        mx = fmaxf(mx, sv[sub][r]);
      }
    mx = fmaxf(mx, __shfl_xor(mx, 16));
    mx = fmaxf(mx, __shfl_xor(mx, 32));
    float mnew = fmaxf(mrun, mx);
    float fac = __expf(mrun - mnew);
    float p[4][4];
    float ls = 0.f;
#pragma unroll
    for (int sub = 0; sub < 4; sub++)
#pragma unroll
      for (int r = 0; r < 4; r++) {
        float e = __expf(sv[sub][r] - mnew);
        p[sub][r] = e;
        ls += e;
      }
    ls += __shfl_xor(ls, 16);
    ls += __shfl_xor(ls, 32);
    lrun = lrun * fac + ls;
    mrun = mnew;
    float fr[4];
#pragma unroll
    for (int r = 0; r < 4; r++) fr[r] = __shfl(fac, (g << 2) | r);
#pragma unroll
    for (int dsub = 0; dsub < 8; dsub++)
#pragma unroll
      for (int r = 0; r < 4; r++) Oacc[dsub][r] *= fr[r];

#pragma unroll
    for (int s = 0; s < 4; s++) {
      int kst = s >> 1;
      int gdst = (2 * s + (g >> 1)) & 3;
      int rowbyte = pbase + (kst * 4 + gdst) * 256 + qi * 16 + (g & 1) * 8;
      *(unsigned int*)(Ps + rowbyte) = pkbf(p[s][0], p[s][1]);
      *(unsigned int*)(Ps + rowbyte + 4) = pkbf(p[s][2], p[s][3]);
    }

#pragma unroll
    for (int kst = 0; kst < 2; kst++) {
      bf16x8_t Pa = *(const bf16x8_t*)(Ps + pbase + (kst * 4 + g) * 256 + qi * 16);
#pragma unroll
      for (int dsub = 0; dsub < 8; dsub++) {
        int row = dsub * 16 + qi;
        bf16x8_t Vb = *(const bf16x8_t*)(Vt + row * 128 + ((g * 16 + kst * 64) ^ ((row & 7) << 4)));
        Oacc[dsub] = __builtin_amdgcn_mfma_f32_16x16x32_bf16(Pa, Vb, Oacc[dsub], 0, 0, 0);
      }
    }
  }

  float rin[4];
#pragma unroll
  for (int r = 0; r < 4; r++) rin[r] = 1.0f / __shfl(lrun, (g << 2) | r);
#pragma unroll
  for (int dsub = 0; dsub < 8; dsub++)
#pragma unroll
    for (int r = 0; r < 4; r++) {
      size_t row = (size_t)(q0 + 4 * g + r);
      op[row * rs + dsub * 16 + qi] = Oacc[dsub][r] * rin[r];
    }
}

// ---------------- temporal pooling (hh fp32, z bf16) ----------------
__global__ __launch_bounds__(256) void k_tpool(const float* __restrict__ hh, const u16* __restrict__ z,
                                               float* __restrict__ pooled, int T, int off) {
  int n = blockIdx.x, d = threadIdx.x;
  __shared__ float red[256];
  __shared__ float lam[T0];
  __shared__ float lame[T0];
  float last = hh[((size_t)(n * T + T - 1)) * DM + d];
  for (int t = 0; t < T; t++) {
    red[d] = hh[((size_t)(n * T + t)) * DM + d] * last;
    __syncthreads();
    for (int s = 128; s > 0; s >>= 1) { if (d < s) red[d] += red[d + s]; __syncthreads(); }
    if (d == 0) lam[t] = red[0];
    __syncthreads();
  }
  float mx = -1e30f;
  for (int t = 0; t < T; t++) mx = fmaxf(mx, lam[t]);
  if (d < T) lame[d] = expf(lam[d] - mx);
  __syncthreads();
  float sum = 0.f;
  for (int t = 0; t < T; t++) sum += lame[t];
  float acc = 0.f;
  for (int t = 0; t < T; t++) acc += lame[t] * bf2f(z[((size_t)(n * T + t)) * DM + d]);
  pooled[(size_t)n * (3 * DM) + off + d] = acc / sum;
}

// ---------------- final ----------------
__global__ __launch_bounds__(256) void k_final(const float* __restrict__ f, const float* __restrict__ g,
                                               const float* __restrict__ b, const float* __restrict__ dw,
                                               const float* __restrict__ db, float* __restrict__ out) {
  int n = blockIdx.x, d = threadIdx.x;
  float v = f[(size_t)n * DM + d];
  __shared__ float red[256];
  red[d] = v;
  __syncthreads();
  for (int s = 128; s > 0; s >>= 1) { if (d < s) red[d] += red[d + s]; __syncthreads(); }
  float mean = red[0] * (1.0f / DM);
  __syncthreads();
  float dv = v - mean;
  red[d] = dv * dv;
  __syncthreads();
  for (int s = 128; s > 0; s >>= 1) { if (d < s) red[d] += red[d + s]; __syncthreads(); }
  float var = red[0] * (1.0f / DM);
  __syncthreads();
  float y = dv * rsqrtf(var + 1e-5f) * g[d] + b[d];
  y = fmaxf(y, 0.f);
  red[d] = y * dw[d];
  __syncthreads();
  for (int s = 128; s > 0; s >>= 1) { if (d < s) red[d] += red[d + s]; __syncthreads(); }
  if (d == 0) out[n] = red[0] + db[0];
}

extern "C" void kernel_launch(void* const* d_in, const int* in_sizes, int n_in,
                              void* d_out, int out_size, void* d_ws, size_t ws_size,
                              hipStream_t stream) {
  const float* x = (const float*)d_in[0];
  const float* gate_W = (const float*)d_in[1];
  const float* gate_b = (const float*)d_in[2];
  const float* feat_W = (const float*)d_in[3];
  const float* feat_b = (const float*)d_in[4];
  const float* ds_mid_W = (const float*)d_in[5];
  const float* ds_mid_b = (const float*)d_in[6];
  const float* ds_small_W = (const float*)d_in[7];
  const float* ds_small_b = (const float*)d_in[8];
  const float* tn1g = (const float*)d_in[9];
  const float* tn1b = (const float*)d_in[10];
  const float* tWq = (const float*)d_in[11];
  const float* tWk = (const float*)d_in[12];
  const float* tWv = (const float*)d_in[13];
  const float* tn2g = (const float*)d_in[14];
  const float* tn2b = (const float*)d_in[15];
  const float* tW1 = (const float*)d_in[16];
  const float* tb1 = (const float*)d_in[17];
  const float* tW2 = (const float*)d_in[18];
  const float* tb2 = (const float*)d_in[19];
  const float* sn1g = (const float*)d_in[20];
  const float* sn1b = (const float*)d_in[21];
  const float* sWq = (const float*)d_in[22];
  const float* sWk = (const float*)d_in[23];
  const float* sWv = (const float*)d_in[24];
  const float* sn2g = (const float*)d_in[25];
  const float* sn2b = (const float*)d_in[26];
  const float* sW1 = (const float*)d_in[27];
  const float* sb1 = (const float*)d_in[28];
  const float* sW2 = (const float*)d_in[29];
  const float* sb2 = (const float*)d_in[30];
  const float* temp_W = (const float*)d_in[31];
  const float* fus_W = (const float*)d_in[32];
  const float* fus_b = (const float*)d_in[33];
  const float* fus_g = (const float*)d_in[34];
  const float* fus_bb = (const float*)d_in[35];
  const float* dec_W = (const float*)d_in[36];
  const float* dec_b = (const float*)d_in[37];

  float* ws = (float*)d_ws;
  size_t o = 0;
  float* pe = ws + o; o += 8192;
  float* g = ws + o; o += 161792;
  u16* wt = (u16*)(ws + o); o += 458752;   // 14 x 256x256 bf16
  float* h0 = ws + o; o += 8388608;
  float* h1 = ws + o; o += 4194304;
  float* h2 = ws + o; o += 2097152;
  u16* bXNu = (u16*)(ws + o); o += 4194304;
  u16* bXTu = (u16*)(ws + o); o += 4194304;
  u16* bZu = (u16*)(ws + o); o += 4194304;
  u16* bQu = (u16*)(ws + o); o += 4194304;
  u16* bKu = (u16*)(ws + o); o += 4194304;
  u16* bVu = (u16*)(ws + o); o += 4194304;
  float* pooled = ws + o; o += 786432;
  float* fused = ws + o; o += 262144;
  float* bO = h0;   // attn outputs (fp32), h0 dead by then
  float* hh = h0;   // temp-gemm output, bO dead by then

  u16* wFeat = wt;
  u16* wDSm = wt + 1 * 65536;
  u16* wDSs = wt + 2 * 65536;
  u16* wTQ = wt + 3 * 65536;
  u16* wTK = wt + 4 * 65536;
  u16* wTV = wt + 5 * 65536;
  u16* wT1 = wt + 6 * 65536;
  u16* wT2 = wt + 7 * 65536;
  u16* wSQ = wt + 8 * 65536;
  u16* wSK = wt + 9 * 65536;
  u16* wSV = wt + 10 * 65536;
  u16* wS1 = wt + 11 * 65536;
  u16* wS2 = wt + 12 * 65536;
  u16* wTW = wt + 13 * 65536;

  k_pe<<<T0, DM, 0, stream>>>(pe);
  k_gate<<<NS, 256, 0, stream>>>(x, gate_W, gate_b, g);
  WPrep wp;
  wp.s[0] = feat_W; wp.s[1] = ds_mid_W; wp.s[2] = ds_small_W;
  wp.s[3] = tWq; wp.s[4] = tWk; wp.s[5] = tWv; wp.s[6] = tW1; wp.s[7] = tW2;
  wp.s[8] = sWq; wp.s[9] = sWk; wp.s[10] = sWv; wp.s[11] = sW1; wp.s[12] = sW2;
  wp.s[13] = temp_W;
  k_wprep<<<224, 256, 0, stream>>>(wp, wt);

  k_fgemm<<<dim3(256, 2), 256, 0, stream>>>(x, g, wFeat, feat_b, pe, h0);

  k_poolmean<<<NS * 16, 256, 0, stream>>>(h0, bXNu, 16, 2);
  k_bgemm<true, false, false, false><<<dim3(128, 2, 1), 256, 0, stream>>>(
      bXNu, wDSm, wDSm, wDSm, ds_mid_b, nullptr, h1, h1, h1);
  k_poolmean<<<NS * 8, 256, 0, stream>>>(h0, bXNu, 8, 4);
  k_bgemm<true, false, false, false><<<dim3(64, 2, 1), 256, 0, stream>>>(
      bXNu, wDSs, wDSs, wDSs, ds_small_b, nullptr, h2, h2, h2);

  const float* hs[3] = {h0, h1, h2};
  const int Ts[3] = {32, 16, 8};
  for (int s = 0; s < 3; s++) {
    int T = Ts[s];
    int M = NS * T;
    dim3 g1(M / 128, 2, 1), g3(M / 128, 2, 3);
    const float* h = hs[s];
    // ---- time attention block ----
    k_ln<false, false><<<M, 256, 0, stream>>>(h, nullptr, tn1g, tn1b, bXNu);
    k_bgemm<false, false, false, true><<<g3, 256, 0, stream>>>(
        bXNu, wTQ, wTK, wTV, nullptr, nullptr, bQu, bKu, bVu);
    if (T == 32) k_tattn<32><<<NS * 4, 256, 0, stream>>>(bQu, bKu, bVu, bO);
    else if (T == 16) k_tattn<16><<<NS * 4, 256, 0, stream>>>(bQu, bKu, bVu, bO);
    else k_tattn<8><<<NS * 4, 256, 0, stream>>>(bQu, bKu, bVu, bO);
    k_ln<true, true><<<M, 256, 0, stream>>>(bXNu, bO, tn2g, tn2b, bXTu);
    k_bgemm<true, true, false, true><<<g1, 256, 0, stream>>>(
        bXTu, wT1, wT1, wT1, tb1, nullptr, bXNu, bXNu, bXNu);
    k_bgemm<true, false, true, true><<<g1, 256, 0, stream>>>(
        bXNu, wT2, wT2, wT2, tb2, bXTu, bZu, bZu, bZu);
    // ---- stock attention block ----
    k_ln<false, true><<<M, 256, 0, stream>>>(bZu, nullptr, sn1g, sn1b, bXTu);
    k_bgemm<false, false, false, true><<<g3, 256, 0, stream>>>(
        bXTu, wSQ, wSK, wSV, nullptr, nullptr, bQu, bKu, bVu);
    k_sattn<<<T * 2 * 16, 256, 0, stream>>>(bQu, bKu, bVu, bO, T);
    k_ln<true, true><<<M, 256, 0, stream>>>(bXTu, bO, sn2g, sn2b, bZu);
    k_bgemm<true, true, false, true><<<g1, 256, 0, stream>>>(
        bZu, wS1, wS1, wS1, sb1, nullptr, bXNu, bXNu, bXNu);
    k_bgemm<true, false, true, true><<<g1, 256, 0, stream>>>(
        bXNu, wS2, wS2, wS2, sb2, bZu, bQu, bQu, bQu);  // z2 -> bQu
    k_bgemm<false, false, false, false><<<g1, 256, 0, stream>>>(
        bQu, wTW, wTW, wTW, nullptr, nullptr, hh, hh, hh);
    k_tpool<<<NS, 256, 0, stream>>>(hh, bQu, pooled, T, s * DM);
  }

  k_gemm<false, false, true, false, false><<<dim3(1024 / 64, 4), 256, 0, stream>>>(
      pooled, 3 * DM, fus_W, fus_b, nullptr, nullptr, nullptr, fused, 1024, DM, 3 * DM);
  k_final<<<NS, 256, 0, stream>>>(fused, fus_g, fus_bb, dec_W, dec_b, (float*)d_out);
}

// Round 4
// 811.479 us; speedup vs baseline: 5.6080x; 1.1536x over previous
//
#include <hip/hip_runtime.h>
#include <math.h>

#define NS 1024
#define T0 32
#define DF 158
#define DG 63
#define DM 256
#define XROW (DF + DG)  // 221

typedef unsigned short u16;
typedef __attribute__((ext_vector_type(8))) short bf16x8_t;
typedef __attribute__((ext_vector_type(4))) float f32x4_t;

union frag_u {
  bf16x8_t f;
  unsigned short us[8];
  unsigned int u32[4];
};

__device__ inline unsigned short f2bf(float x) {
  unsigned int u = __float_as_uint(x);
  unsigned int r = u + 0x7fffu + ((u >> 16) & 1u);
  return (unsigned short)(r >> 16);
}
__device__ inline unsigned int pkbf(float lo, float hi) {
  return (unsigned int)f2bf(lo) | ((unsigned int)f2bf(hi) << 16);
}
__device__ inline float bf2f(u16 u) {
  return __uint_as_float(((unsigned int)u) << 16);
}

// ---------------- positional encoding table (32 x 256) ----------------
__global__ void k_pe(float* __restrict__ pe) {
  int t = blockIdx.x, d = threadIdx.x;
  int i2 = d & ~1;
  float div = expf((float)i2 * (-logf(10000.0f) / (float)DM));
  float ang = (float)t * div;
  pe[t * DM + d] = (d & 1) ? cosf(ang) : sinf(ang);
}

// ---------------- gate ----------------
__global__ void k_gate(const float* __restrict__ x, const float* __restrict__ gW,
                       const float* __restrict__ gb, float* __restrict__ g) {
  int n = blockIdx.x, tid = threadIdx.x;
  __shared__ float gin[DG];
  __shared__ float red[256];
  if (tid < DG) gin[tid] = x[(size_t)n * T0 * XROW + 31 * XROW + DF + tid];
  __syncthreads();
  float myv = 0.f;
  if (tid < DF) {
    float acc = gb[tid];
    for (int j = 0; j < DG; j++) acc = fmaf(gin[j], gW[j * DF + tid], acc);
    myv = acc * (1.0f / 5.0f);
  }
  red[tid] = (tid < DF) ? myv : -1e30f;
  __syncthreads();
  for (int s = 128; s > 0; s >>= 1) { if (tid < s) red[tid] = fmaxf(red[tid], red[tid + s]); __syncthreads(); }
  float mx = red[0];
  __syncthreads();
  float e = (tid < DF) ? expf(myv - mx) : 0.f;
  red[tid] = e;
  __syncthreads();
  for (int s = 128; s > 0; s >>= 1) { if (tid < s) red[tid] += red[tid + s]; __syncthreads(); }
  float sum = red[0];
  if (tid < DF) g[(size_t)n * DF + tid] = (float)DF * e / sum;
}

// ---------------- weight prep: W[K][256] fp32 -> Wt[256][256] bf16 (transposed, zero-pad K) ----------------
struct WPrep { const float* s[14]; };
__global__ __launch_bounds__(256) void k_wprep(WPrep w, u16* __restrict__ dst) {
  int mat = blockIdx.x >> 4, nb = blockIdx.x & 15;
  int tid = threadIdx.x;
  int n = nb * 16 + (tid >> 4);
  int kc = (tid & 15) * 16;
  const float* src = w.s[mat];
  int K = (mat == 0) ? DF : 256;
  frag_u f0, f1;
#pragma unroll
  for (int j = 0; j < 8; j++) {
    int k0 = kc + j, k1 = kc + 8 + j;
    f0.us[j] = (k0 < K) ? f2bf(src[(size_t)k0 * 256 + n]) : (u16)0;
    f1.us[j] = (k1 < K) ? f2bf(src[(size_t)k1 * 256 + n]) : (u16)0;
  }
  u16* d = dst + (size_t)mat * 65536 + (size_t)n * 256 + kc;
  *(bf16x8_t*)d = f0.f;
  *(bf16x8_t*)(d + 8) = f1.f;
}

// ---------------- fus_W transpose: [768][256] fp32 -> [256][768] bf16 ----------------
__global__ __launch_bounds__(256) void k_wtrans(const float* __restrict__ W, u16* __restrict__ Wt) {
  __shared__ u16 Ts[64][65];
  int k0 = blockIdx.x * 64, n0 = blockIdx.y * 64;
  int tid = threadIdx.x;
#pragma unroll
  for (int i = 0; i < 16; i++) {
    int e = tid + i * 256;
    int r = e >> 6, c = e & 63;
    Ts[r][c] = f2bf(W[(size_t)(k0 + r) * 256 + n0 + c]);
  }
  __syncthreads();
#pragma unroll
  for (int i = 0; i < 16; i++) {
    int e = tid + i * 256;
    int r = e >> 6, c = e & 63;
    Wt[(size_t)(n0 + r) * 768 + k0 + c] = Ts[c][r];
  }
}

// ---------------- bf16 MFMA GEMM: C = act(A@Bt^T + bias + res), A[M][256] bf16, Bt[256n][256k] bf16 ----------------
// Block 128x128, 4 waves (2x2 of 64x64). blockIdx.z selects matrix (QKV fusion).
// grid = (2, M/128, z): x fastest so the 2 blocks sharing an A-panel are dispatch-adjacent.
template <bool BIAS, bool RELU, bool RES, bool OUTBF>
__global__ __launch_bounds__(256) void k_bgemm(
    const u16* __restrict__ A,
    const u16* __restrict__ B0, const u16* __restrict__ B1, const u16* __restrict__ B2,
    const float* __restrict__ bias, const u16* __restrict__ res,
    void* __restrict__ C0, void* __restrict__ C1, void* __restrict__ C2) {
  __shared__ __align__(16) unsigned char sm[32768];
  unsigned char* As = sm;
  unsigned char* Bs = sm + 16384;
  const u16* Bt = blockIdx.z == 0 ? B0 : (blockIdx.z == 1 ? B1 : B2);
  void* Cv = blockIdx.z == 0 ? C0 : (blockIdx.z == 1 ? C1 : C2);
  int m0 = blockIdx.y * 128, n0w = blockIdx.x * 128;
  int tid = threadIdx.x, lane = tid & 63, wid = tid >> 6;
  int qi = lane & 15, g = lane >> 4;
  int wr = wid >> 1, wc = wid & 1;
  f32x4_t acc[4][4];
#pragma unroll
  for (int i = 0; i < 4; i++)
#pragma unroll
    for (int j = 0; j < 4; j++) acc[i][j] = (f32x4_t){0.f, 0.f, 0.f, 0.f};
  for (int kt = 0; kt < 4; kt++) {
    if (kt) __syncthreads();
#pragma unroll
    for (int i = 0; i < 4; i++) {
      int cid = tid + i * 256;
      int row = cid >> 3, c = cid & 7;
      int swz = (c * 16) ^ ((row & 7) << 4);
      bf16x8_t va = *(const bf16x8_t*)(A + (size_t)(m0 + row) * 256 + kt * 64 + c * 8);
      *(bf16x8_t*)(As + row * 128 + swz) = va;
      bf16x8_t vb = *(const bf16x8_t*)(Bt + (size_t)(n0w + row) * 256 + kt * 64 + c * 8);
      *(bf16x8_t*)(Bs + row * 128 + swz) = vb;
    }
    __syncthreads();
    bf16x8_t Af[2][4], Bf[2][4];
#pragma unroll
    for (int mi = 0; mi < 4; mi++) {
      int row = wr * 64 + mi * 16 + qi;
      int swz = (row & 7) << 4;
      const unsigned char* ap = As + row * 128;
      Af[0][mi] = *(const bf16x8_t*)(ap + ((g * 16) ^ swz));
      Af[1][mi] = *(const bf16x8_t*)(ap + ((64 + g * 16) ^ swz));
    }
#pragma unroll
    for (int ni = 0; ni < 4; ni++) {
      int row = wc * 64 + ni * 16 + qi;
      int swz = (row & 7) << 4;
      const unsigned char* bp = Bs + row * 128;
      Bf[0][ni] = *(const bf16x8_t*)(bp + ((g * 16) ^ swz));
      Bf[1][ni] = *(const bf16x8_t*)(bp + ((64 + g * 16) ^ swz));
    }
#pragma unroll
    for (int ks = 0; ks < 2; ks++)
#pragma unroll
      for (int mi = 0; mi < 4; mi++)
#pragma unroll
        for (int ni = 0; ni < 4; ni++)
          acc[mi][ni] = __builtin_amdgcn_mfma_f32_16x16x32_bf16(Af[ks][mi], Bf[ks][ni], acc[mi][ni], 0, 0, 0);
  }
#pragma unroll
  for (int mi = 0; mi < 4; mi++) {
#pragma unroll
    for (int ni = 0; ni < 4; ni++) {
#pragma unroll
      for (int r = 0; r < 4; r++) {
        int row = m0 + wr * 64 + mi * 16 + 4 * g + r;
        int col = n0w + wc * 64 + ni * 16 + qi;
        float vv = acc[mi][ni][r];
        if (BIAS) vv += bias[col];
        if (RES) vv += bf2f(res[(size_t)row * 256 + col]);
        if (RELU) vv = fmaxf(vv, 0.f);
        if (OUTBF) ((u16*)Cv)[(size_t)row * 256 + col] = f2bf(vv);
        else ((float*)Cv)[(size_t)row * 256 + col] = vv;
      }
    }
  }
}

// ---------------- feat GEMM: h = (x*gate)@feat_W + bias + pe, fp32 out ----------------
__global__ __launch_bounds__(256) void k_fgemm(
    const float* __restrict__ x, const float* __restrict__ gate,
    const u16* __restrict__ Bt, const float* __restrict__ bias,
    const float* __restrict__ pe, float* __restrict__ C) {
  __shared__ __align__(16) unsigned char sm[32768];
  unsigned char* As = sm;
  unsigned char* Bs = sm + 16384;
  int m0 = blockIdx.y * 128, n0w = blockIdx.x * 128;
  int tid = threadIdx.x, lane = tid & 63, wid = tid >> 6;
  int qi = lane & 15, g = lane >> 4;
  int wr = wid >> 1, wc = wid & 1;
  f32x4_t acc[4][4];
#pragma unroll
  for (int i = 0; i < 4; i++)
#pragma unroll
    for (int j = 0; j < 4; j++) acc[i][j] = (f32x4_t){0.f, 0.f, 0.f, 0.f};
  for (int kt = 0; kt < 3; kt++) {
    if (kt) __syncthreads();
#pragma unroll
    for (int i = 0; i < 4; i++) {
      int cid = tid + i * 256;
      int row = cid >> 3, c = cid & 7;
      int swz = (c * 16) ^ ((row & 7) << 4);
      int gk0 = kt * 64 + c * 8;
      const float* xr = x + (size_t)(m0 + row) * XROW;
      const float* gr = gate + (size_t)((m0 + row) >> 5) * DF;
      frag_u f;
#pragma unroll
      for (int j = 0; j < 8; j++) {
        int gk = gk0 + j;
        f.us[j] = (gk < DF) ? f2bf(xr[gk] * gr[gk]) : (u16)0;
      }
      *(bf16x8_t*)(As + row * 128 + swz) = f.f;
      bf16x8_t vb = *(const bf16x8_t*)(Bt + (size_t)(n0w + row) * 256 + kt * 64 + c * 8);
      *(bf16x8_t*)(Bs + row * 128 + swz) = vb;
    }
    __syncthreads();
    bf16x8_t Af[2][4], Bf[2][4];
#pragma unroll
    for (int mi = 0; mi < 4; mi++) {
      int row = wr * 64 + mi * 16 + qi;
      int swz = (row & 7) << 4;
      const unsigned char* ap = As + row * 128;
      Af[0][mi] = *(const bf16x8_t*)(ap + ((g * 16) ^ swz));
      Af[1][mi] = *(const bf16x8_t*)(ap + ((64 + g * 16) ^ swz));
    }
#pragma unroll
    for (int ni = 0; ni < 4; ni++) {
      int row = wc * 64 + ni * 16 + qi;
      int swz = (row & 7) << 4;
      const unsigned char* bp = Bs + row * 128;
      Bf[0][ni] = *(const bf16x8_t*)(bp + ((g * 16) ^ swz));
      Bf[1][ni] = *(const bf16x8_t*)(bp + ((64 + g * 16) ^ swz));
    }
#pragma unroll
    for (int ks = 0; ks < 2; ks++)
#pragma unroll
      for (int mi = 0; mi < 4; mi++)
#pragma unroll
        for (int ni = 0; ni < 4; ni++)
          acc[mi][ni] = __builtin_amdgcn_mfma_f32_16x16x32_bf16(Af[ks][mi], Bf[ks][ni], acc[mi][ni], 0, 0, 0);
  }
#pragma unroll
  for (int mi = 0; mi < 4; mi++) {
#pragma unroll
    for (int ni = 0; ni < 4; ni++) {
#pragma unroll
      for (int r = 0; r < 4; r++) {
        int row = m0 + wr * 64 + mi * 16 + 4 * g + r;
        int col = n0w + wc * 64 + ni * 16 + qi;
        float vv = acc[mi][ni][r] + bias[col] + pe[(row & (T0 - 1)) * DM + col];
        C[(size_t)row * 256 + col] = vv;
      }
    }
  }
}

// ---------------- fus GEMM: fused = pooled @ fus_W + fus_b; A[1024][768] bf16, Wt[256][768] bf16 ----------------
// grid (4 n-tiles, 16 m-tiles), 64x64 tile, wave = 16 rows x 64 cols.
__global__ __launch_bounds__(256) void k_fus(const u16* __restrict__ A, const u16* __restrict__ Bt,
                                             const float* __restrict__ bias, float* __restrict__ C) {
  __shared__ __align__(16) unsigned char sm[16384];
  unsigned char* As = sm;
  unsigned char* Bs = sm + 8192;
  int n0 = blockIdx.x * 64, m0 = blockIdx.y * 64;
  int tid = threadIdx.x, lane = tid & 63, wid = tid >> 6;
  int qi = lane & 15, g = lane >> 4;
  f32x4_t acc[4];
#pragma unroll
  for (int i = 0; i < 4; i++) acc[i] = (f32x4_t){0.f, 0.f, 0.f, 0.f};
  for (int kt = 0; kt < 12; kt++) {
    if (kt) __syncthreads();
#pragma unroll
    for (int i = 0; i < 2; i++) {
      int cid = tid + i * 256;
      int row = cid >> 3, c = cid & 7;
      int swz = (c * 16) ^ ((row & 7) << 4);
      *(bf16x8_t*)(As + row * 128 + swz) = *(const bf16x8_t*)(A + (size_t)(m0 + row) * 768 + kt * 64 + c * 8);
      *(bf16x8_t*)(Bs + row * 128 + swz) = *(const bf16x8_t*)(Bt + (size_t)(n0 + row) * 768 + kt * 64 + c * 8);
    }
    __syncthreads();
    int arow = wid * 16 + qi;
    int asw = (arow & 7) << 4;
    bf16x8_t Af[2];
    Af[0] = *(const bf16x8_t*)(As + arow * 128 + ((g * 16) ^ asw));
    Af[1] = *(const bf16x8_t*)(As + arow * 128 + ((64 + g * 16) ^ asw));
#pragma unroll
    for (int ni = 0; ni < 4; ni++) {
      int brow = ni * 16 + qi;
      int bsw = (brow & 7) << 4;
      bf16x8_t B0 = *(const bf16x8_t*)(Bs + brow * 128 + ((g * 16) ^ bsw));
      bf16x8_t B1 = *(const bf16x8_t*)(Bs + brow * 128 + ((64 + g * 16) ^ bsw));
      acc[ni] = __builtin_amdgcn_mfma_f32_16x16x32_bf16(Af[0], B0, acc[ni], 0, 0, 0);
      acc[ni] = __builtin_amdgcn_mfma_f32_16x16x32_bf16(Af[1], B1, acc[ni], 0, 0, 0);
    }
  }
#pragma unroll
  for (int ni = 0; ni < 4; ni++)
#pragma unroll
    for (int r = 0; r < 4; r++) {
      int row = m0 + wid * 16 + 4 * g + r;
      int col = n0 + ni * 16 + qi;
      C[(size_t)row * 256 + col] = acc[ni][r] + bias[col];
    }
}

// ---------------- LayerNorm: out bf16; a fp32 or bf16; optional fp32 residual ----------------
template <bool RES, bool ABF>
__global__ __launch_bounds__(256) void k_ln(const void* __restrict__ a, const float* __restrict__ b,
                                            const float* __restrict__ g, const float* __restrict__ be,
                                            u16* __restrict__ out) {
  int row = blockIdx.x, tid = threadIdx.x;
  size_t base = (size_t)row * DM + tid;
  float v = ABF ? bf2f(((const u16*)a)[base]) : ((const float*)a)[base];
  if (RES) v += b[base];
  __shared__ float red[256];
  red[tid] = v;
  __syncthreads();
  for (int s = 128; s > 0; s >>= 1) { if (tid < s) red[tid] += red[tid + s]; __syncthreads(); }
  float mean = red[0] * (1.0f / DM);
  __syncthreads();
  float d = v - mean;
  red[tid] = d * d;
  __syncthreads();
  for (int s = 128; s > 0; s >>= 1) { if (tid < s) red[tid] += red[tid + s]; __syncthreads(); }
  float var = red[0] * (1.0f / DM);
  out[base] = f2bf(d * rsqrtf(var + 1e-5f) * g[tid] + be[tid]);
}

// ---------------- mean-pool over time groups (bf16 out) ----------------
__global__ void k_poolmean(const float* __restrict__ h, u16* __restrict__ out, int Tout, int P) {
  int idx = blockIdx.x * 256 + threadIdx.x;
  int d = idx & 255;
  int tmp = idx >> 8;
  int to = tmp % Tout;
  int n = tmp / Tout;
  int Tin = Tout * P;
  float s = 0.f;
  for (int p = 0; p < P; p++) s += h[((size_t)(n * Tin + to * P + p)) * DM + d];
  out[idx] = f2bf(s / (float)P);
}

// ---------------- time attention via MFMA (bf16 in, fp32 out) ----------------
// Block = stock n; 4 waves = 4 heads; no inter-wave LDS sharing.
// Swapped S^T = mfma(A=K, B=Q^T); softmax lane-local + shfl_xor(16/32); P/l -> LDS -> A-frag for PV.
template <int T>
__global__ __launch_bounds__(256) void k_tattn(const u16* __restrict__ q, const u16* __restrict__ k,
                                               const u16* __restrict__ v, float* __restrict__ o) {
  constexpr int TR = (T < 16) ? 16 : T;          // K/Q rows staged (A/B frags read 16 rows)
  constexpr int PROWS = (T == 32) ? 32 : 16;
  constexpr int QKB = TR * 128;                  // bytes per Q or K array
  constexpr int HS = 2 * QKB + 64 * 80 + PROWS * 80;
  __shared__ __align__(16) unsigned char smem[4 * HS];
  int n = blockIdx.x;
  int tid = threadIdx.x, lane = tid & 63, h = tid >> 6;
  int qi = lane & 15, g = lane >> 4;
  unsigned char* Qs = smem + h * HS;
  unsigned char* Ks = Qs + QKB;
  unsigned char* Vt = Ks + QKB;
  unsigned char* Pl = Vt + 64 * 80;

  const u16* qh = q + (size_t)n * T * 256 + h * 64;
  const u16* kh = k + (size_t)n * T * 256 + h * 64;
  const u16* vh = v + (size_t)n * T * 256 + h * 64;
  const bf16x8_t zero8 = {0, 0, 0, 0, 0, 0, 0, 0};

  // stage Q, K (zero rows >= T)
  for (int idx = lane; idx < TR * 8; idx += 64) {
    int row = idx >> 3, c = idx & 7;
    bf16x8_t vq = zero8, vk = zero8;
    if (row < T) {
      vq = *(const bf16x8_t*)(qh + (size_t)row * 256 + c * 8);
      vk = *(const bf16x8_t*)(kh + (size_t)row * 256 + c * 8);
    }
    int off = row * 128 + ((c * 16) ^ ((row & 7) << 4));
    *(bf16x8_t*)(Qs + off) = vq;
    *(bf16x8_t*)(Ks + off) = vk;
  }
  // stage V transposed: Vt[d][key], key pairs packed u32; rows >= T zeroed
  {
    int kp = lane & 15, dg = lane >> 4;
    int d0 = dg * 16;
    frag_u a0, a1, b0, b1;
    a0.f = a1.f = b0.f = b1.f = zero8;
    if (2 * kp < T) {
      a0.f = *(const bf16x8_t*)(vh + (size_t)(2 * kp) * 256 + d0);
      a1.f = *(const bf16x8_t*)(vh + (size_t)(2 * kp) * 256 + d0 + 8);
    }
    if (2 * kp + 1 < T) {
      b0.f = *(const bf16x8_t*)(vh + (size_t)(2 * kp + 1) * 256 + d0);
      b1.f = *(const bf16x8_t*)(vh + (size_t)(2 * kp + 1) * 256 + d0 + 8);
    }
#pragma unroll
    for (int i = 0; i < 8; i++)
      *(unsigned int*)(Vt + (d0 + i) * 80 + kp * 4) = (unsigned int)a0.us[i] | ((unsigned int)b0.us[i] << 16);
#pragma unroll
    for (int i = 0; i < 8; i++)
      *(unsigned int*)(Vt + (d0 + 8 + i) * 80 + kp * 4) = (unsigned int)a1.us[i] | ((unsigned int)b1.us[i] << 16);
  }
  // zero P key-slots 16..31 when T < 32 (avoid poisoned-LDS NaN * 0)
  if (T < 32) *(unsigned long long*)(Pl + qi * 80 + 32 + g * 8) = 0ULL;
  __syncthreads();

  constexpr int NQT = (T == 32) ? 2 : 1;
  constexpr int NSUB = (T == 32) ? 2 : 1;
  const float scale = 0.125f;  // 1/sqrt(256/4)

  bf16x8_t Qb[NQT][2];
#pragma unroll
  for (int qt = 0; qt < NQT; qt++) {
    int row = qt * 16 + qi;
    int sw = (row & 7) << 4;
#pragma unroll
    for (int kst = 0; kst < 2; kst++)
      Qb[qt][kst] = *(const bf16x8_t*)(Qs + row * 128 + ((kst * 64 + g * 16) ^ sw));
  }
  f32x4_t sacc[NQT][NSUB];
#pragma unroll
  for (int qt = 0; qt < NQT; qt++)
#pragma unroll
    for (int sub = 0; sub < NSUB; sub++) sacc[qt][sub] = (f32x4_t){0.f, 0.f, 0.f, 0.f};
#pragma unroll
  for (int sub = 0; sub < NSUB; sub++) {
    int row = sub * 16 + qi;
    int sw = (row & 7) << 4;
    bf16x8_t Ka[2];
#pragma unroll
    for (int kst = 0; kst < 2; kst++)
      Ka[kst] = *(const bf16x8_t*)(Ks + row * 128 + ((kst * 64 + g * 16) ^ sw));
#pragma unroll
    for (int qt = 0; qt < NQT; qt++)
#pragma unroll
      for (int kst = 0; kst < 2; kst++)
        sacc[qt][sub] = __builtin_amdgcn_mfma_f32_16x16x32_bf16(Ka[kst], Qb[qt][kst], sacc[qt][sub], 0, 0, 0);
  }
  // softmax per query column + write P/l to LDS
#pragma unroll
  for (int qt = 0; qt < NQT; qt++) {
    float sv[NSUB][4];
    float mx = -3.0e38f;
#pragma unroll
    for (int sub = 0; sub < NSUB; sub++)
#pragma unroll
      for (int r = 0; r < 4; r++) {
        int key = sub * 16 + 4 * g + r;
        float s = sacc[qt][sub][r] * scale;
        if (key >= T) s = -3.0e38f;
        sv[sub][r] = s;
        mx = fmaxf(mx, s);
      }
    mx = fmaxf(mx, __shfl_xor(mx, 16));
    mx = fmaxf(mx, __shfl_xor(mx, 32));
    float p[NSUB][4];
    float l = 0.f;
#pragma unroll
    for (int sub = 0; sub < NSUB; sub++)
#pragma unroll
      for (int r = 0; r < 4; r++) {
        float e = __expf(sv[sub][r] - mx);
        p[sub][r] = e;
        l += e;
      }
    l += __shfl_xor(l, 16);
    l += __shfl_xor(l, 32);
    float linv = 1.0f / l;
#pragma unroll
    for (int sub = 0; sub < NSUB; sub++) {
      unsigned char* addr = Pl + (qt * 16 + qi) * 80 + sub * 32 + g * 8;
      *(unsigned int*)addr = pkbf(p[sub][0] * linv, p[sub][1] * linv);
      *(unsigned int*)(addr + 4) = pkbf(p[sub][2] * linv, p[sub][3] * linv);
    }
  }
  // PV
  f32x4_t oacc[NQT][4];
#pragma unroll
  for (int qt = 0; qt < NQT; qt++)
#pragma unroll
    for (int ni = 0; ni < 4; ni++) oacc[qt][ni] = (f32x4_t){0.f, 0.f, 0.f, 0.f};
  bf16x8_t Pa[NQT];
#pragma unroll
  for (int qt = 0; qt < NQT; qt++)
    Pa[qt] = *(const bf16x8_t*)(Pl + (qt * 16 + qi) * 80 + g * 16);
#pragma unroll
  for (int ni = 0; ni < 4; ni++) {
    bf16x8_t Vb = *(const bf16x8_t*)(Vt + (ni * 16 + qi) * 80 + g * 16);
#pragma unroll
    for (int qt = 0; qt < NQT; qt++)
      oacc[qt][ni] = __builtin_amdgcn_mfma_f32_16x16x32_bf16(Pa[qt], Vb, oacc[qt][ni], 0, 0, 0);
  }
#pragma unroll
  for (int qt = 0; qt < NQT; qt++)
#pragma unroll
    for (int ni = 0; ni < 4; ni++)
#pragma unroll
      for (int r = 0; r < 4; r++) {
        int qq = qt * 16 + 4 * g + r;
        if (qq < T) o[((size_t)(n * T + qq)) * 256 + h * 64 + ni * 16 + qi] = oacc[qt][ni][r];
      }
}

// ---------------- stock attention, bf16 MFMA flash (bf16 in, fp32 out) ----------------
__global__ __launch_bounds__(256) void k_sattn(const u16* __restrict__ q, const u16* __restrict__ k,
                                               const u16* __restrict__ v, float* __restrict__ o, int T) {
  __shared__ __align__(16) unsigned char smem[40960];
  unsigned char* Ks = smem;
  unsigned char* Vt = smem + 16384;
  unsigned char* Ps = smem + 32768;

  const int NTH = T * 2;
  int bid = blockIdx.x;
  int xcd = bid & 7, slot = bid >> 3;
  int th = xcd * (NTH >> 3) + (slot >> 4);
  int qb = slot & 15;
  int t = th >> 1, h = th & 1;

  int tid = threadIdx.x;
  int lane = tid & 63;
  int wid = tid >> 6;
  int qi = lane & 15;
  int g = lane >> 4;
  const float invtemp = 0.08838834764831845f;

  const size_t rs = (size_t)T * 256;
  const u16* qp = q + (size_t)t * 256 + h * 128;
  const u16* kp = k + (size_t)t * 256 + h * 128;
  const u16* vp = v + (size_t)t * 256 + h * 128;
  float* op = o + (size_t)t * 256 + h * 128;

  int q0 = qb * 64 + wid * 16;

  bf16x8_t Qf[4];
  {
    const u16* src = qp + (size_t)(q0 + qi) * rs + g * 8;
#pragma unroll
    for (int kst = 0; kst < 4; kst++) Qf[kst] = *(const bf16x8_t*)(src + kst * 32);
  }

  f32x4_t Oacc[8];
#pragma unroll
  for (int i = 0; i < 8; i++) Oacc[i] = (f32x4_t){0.f, 0.f, 0.f, 0.f};
  float mrun = -3.0e38f, lrun = 0.f;
  const int pbase = wid * 2048;

  for (int kb = 0; kb < NS; kb += 64) {
    __syncthreads();
#pragma unroll
    for (int i = 0; i < 4; i++) {
      int cid = tid + i * 256;
      int row = cid >> 4, ch = cid & 15;
      bf16x8_t kv = *(const bf16x8_t*)(kp + (size_t)(kb + row) * rs + ch * 8);
      *(bf16x8_t*)(Ks + row * 256 + ((ch * 16) ^ ((row & 7) << 4))) = kv;
    }
    {
      int kpair = tid & 31, dg = tid >> 5;
      int d0 = dg * 16;
      const u16* s0 = vp + (size_t)(kb + 2 * kpair) * rs + d0;
      const u16* s1 = s0 + rs;
      frag_u a0, a1, b0, b1;
      a0.f = *(const bf16x8_t*)s0;
      a1.f = *(const bf16x8_t*)(s0 + 8);
      b0.f = *(const bf16x8_t*)s1;
      b1.f = *(const bf16x8_t*)(s1 + 8);
#pragma unroll
      for (int i = 0; i < 8; i++) {
        int d = d0 + i;
        *(unsigned int*)(Vt + d * 128 + ((kpair * 4) ^ ((d & 7) << 4))) =
            (unsigned int)a0.us[i] | ((unsigned int)b0.us[i] << 16);
      }
#pragma unroll
      for (int i = 0; i < 8; i++) {
        int d = d0 + 8 + i;
        *(unsigned int*)(Vt + d * 128 + ((kpair * 4) ^ ((d & 7) << 4))) =
            (unsigned int)a1.us[i] | ((unsigned int)b1.us[i] << 16);
      }
    }
    __syncthreads();

    f32x4_t sacc[4];
#pragma unroll
    for (int i = 0; i < 4; i++) sacc[i] = (f32x4_t){0.f, 0.f, 0.f, 0.f};
#pragma unroll
    for (int sub = 0; sub < 4; sub++) {
      int row = sub * 16 + qi;
      int swz = (row & 7) << 4;
      const unsigned char* kr = Ks + row * 256;
#pragma unroll
      for (int kst = 0; kst < 4; kst++) {
        bf16x8_t Af = *(const bf16x8_t*)(kr + ((g * 16 + kst * 64) ^ swz));
        sacc[sub] = __builtin_amdgcn_mfma_f32_16x16x32_bf16(Af, Qf[kst], sacc[sub], 0, 0, 0);
      }
    }

    float sv[4][4];
    float mx = -3.0e38f;
#pragma unroll
    for (int sub = 0; sub < 4; sub++)
#pragma unroll
      for (int r = 0; r < 4; r++) {
        sv[sub][r] = sacc[sub][r] * invtemp;
        mx = fmaxf(mx, sv[sub][r]);
      }
    mx = fmaxf(mx, __shfl_xor(mx, 16));
    mx = fmaxf(mx, __shfl_xor(mx, 32));
    float mnew = fmaxf(mrun, mx);
    float fac = __expf(mrun - mnew);
    float p[4][4];
    float ls = 0.f;
#pragma unroll
    for (int sub = 0; sub < 4; sub++)
#pragma unroll
      for (int r = 0; r < 4; r++) {
        float e = __expf(sv[sub][r] - mnew);
        p[sub][r] = e;
        ls += e;
      }
    ls += __shfl_xor(ls, 16);
    ls += __shfl_xor(ls, 32);
    lrun = lrun * fac + ls;
    mrun = mnew;
    float fr[4];
#pragma unroll
    for (int r = 0; r < 4; r++) fr[r] = __shfl(fac, (g << 2) | r);
#pragma unroll
    for (int dsub = 0; dsub < 8; dsub++)
#pragma unroll
      for (int r = 0; r < 4; r++) Oacc[dsub][r] *= fr[r];

#pragma unroll
    for (int s = 0; s < 4; s++) {
      int kst = s >> 1;
      int gdst = (2 * s + (g >> 1)) & 3;
      int rowbyte = pbase + (kst * 4 + gdst) * 256 + qi * 16 + (g & 1) * 8;
      *(unsigned int*)(Ps + rowbyte) = pkbf(p[s][0], p[s][1]);
      *(unsigned int*)(Ps + rowbyte + 4) = pkbf(p[s][2], p[s][3]);
    }

#pragma unroll
    for (int kst = 0; kst < 2; kst++) {
      bf16x8_t Pa = *(const bf16x8_t*)(Ps + pbase + (kst * 4 + g) * 256 + qi * 16);
#pragma unroll
      for (int dsub = 0; dsub < 8; dsub++) {
        int row = dsub * 16 + qi;
        bf16x8_t Vb = *(const bf16x8_t*)(Vt + row * 128 + ((g * 16 + kst * 64) ^ ((row & 7) << 4)));
        Oacc[dsub] = __builtin_amdgcn_mfma_f32_16x16x32_bf16(Pa, Vb, Oacc[dsub], 0, 0, 0);
      }
    }
  }

  float rin[4];
#pragma unroll
  for (int r = 0; r < 4; r++) rin[r] = 1.0f / __shfl(lrun, (g << 2) | r);
#pragma unroll
  for (int dsub = 0; dsub < 8; dsub++)
#pragma unroll
    for (int r = 0; r < 4; r++) {
      size_t row = (size_t)(q0 + 4 * g + r);
      op[row * rs + dsub * 16 + qi] = Oacc[dsub][r] * rin[r];
    }
}

// ---------------- temporal pooling (hh fp32, z bf16) -> pooled bf16 [n][768] ----------------
__global__ __launch_bounds__(256) void k_tpool(const float* __restrict__ hh, const u16* __restrict__ z,
                                               u16* __restrict__ pooled, int T, int off) {
  int n = blockIdx.x, d = threadIdx.x;
  __shared__ float red[256];
  __shared__ float lam[T0];
  __shared__ float lame[T0];
  float last = hh[((size_t)(n * T + T - 1)) * DM + d];
  for (int t = 0; t < T; t++) {
    red[d] = hh[((size_t)(n * T + t)) * DM + d] * last;
    __syncthreads();
    for (int s = 128; s > 0; s >>= 1) { if (d < s) red[d] += red[d + s]; __syncthreads(); }
    if (d == 0) lam[t] = red[0];
    __syncthreads();
  }
  float mx = -1e30f;
  for (int t = 0; t < T; t++) mx = fmaxf(mx, lam[t]);
  if (d < T) lame[d] = expf(lam[d] - mx);
  __syncthreads();
  float sum = 0.f;
  for (int t = 0; t < T; t++) sum += lame[t];
  float acc = 0.f;
  for (int t = 0; t < T; t++) acc += lame[t] * bf2f(z[((size_t)(n * T + t)) * DM + d]);
  pooled[(size_t)n * 768 + off + d] = f2bf(acc / sum);
}

// ---------------- final ----------------
__global__ __launch_bounds__(256) void k_final(const float* __restrict__ f, const float* __restrict__ g,
                                               const float* __restrict__ b, const float* __restrict__ dw,
                                               const float* __restrict__ db, float* __restrict__ out) {
  int n = blockIdx.x, d = threadIdx.x;
  float v = f[(size_t)n * DM + d];
  __shared__ float red[256];
  red[d] = v;
  __syncthreads();
  for (int s = 128; s > 0; s >>= 1) { if (d < s) red[d] += red[d + s]; __syncthreads(); }
  float mean = red[0] * (1.0f / DM);
  __syncthreads();
  float dv = v - mean;
  red[d] = dv * dv;
  __syncthreads();
  for (int s = 128; s > 0; s >>= 1) { if (d < s) red[d] += red[d + s]; __syncthreads(); }
  float var = red[0] * (1.0f / DM);
  __syncthreads();
  float y = dv * rsqrtf(var + 1e-5f) * g[d] + b[d];
  y = fmaxf(y, 0.f);
  red[d] = y * dw[d];
  __syncthreads();
  for (int s = 128; s > 0; s >>= 1) { if (d < s) red[d] += red[d + s]; __syncthreads(); }
  if (d == 0) out[n] = red[0] + db[0];
}

extern "C" void kernel_launch(void* const* d_in, const int* in_sizes, int n_in,
                              void* d_out, int out_size, void* d_ws, size_t ws_size,
                              hipStream_t stream) {
  const float* x = (const float*)d_in[0];
  const float* gate_W = (const float*)d_in[1];
  const float* gate_b = (const float*)d_in[2];
  const float* feat_W = (const float*)d_in[3];
  const float* feat_b = (const float*)d_in[4];
  const float* ds_mid_W = (const float*)d_in[5];
  const float* ds_mid_b = (const float*)d_in[6];
  const float* ds_small_W = (const float*)d_in[7];
  const float* ds_small_b = (const float*)d_in[8];
  const float* tn1g = (const float*)d_in[9];
  const float* tn1b = (const float*)d_in[10];
  const float* tWq = (const float*)d_in[11];
  const float* tWk = (const float*)d_in[12];
  const float* tWv = (const float*)d_in[13];
  const float* tn2g = (const float*)d_in[14];
  const float* tn2b = (const float*)d_in[15];
  const float* tW1 = (const float*)d_in[16];
  const float* tb1 = (const float*)d_in[17];
  const float* tW2 = (const float*)d_in[18];
  const float* tb2 = (const float*)d_in[19];
  const float* sn1g = (const float*)d_in[20];
  const float* sn1b = (const float*)d_in[21];
  const float* sWq = (const float*)d_in[22];
  const float* sWk = (const float*)d_in[23];
  const float* sWv = (const float*)d_in[24];
  const float* sn2g = (const float*)d_in[25];
  const float* sn2b = (const float*)d_in[26];
  const float* sW1 = (const float*)d_in[27];
  const float* sb1 = (const float*)d_in[28];
  const float* sW2 = (const float*)d_in[29];
  const float* sb2 = (const float*)d_in[30];
  const float* temp_W = (const float*)d_in[31];
  const float* fus_W = (const float*)d_in[32];
  const float* fus_b = (const float*)d_in[33];
  const float* fus_g = (const float*)d_in[34];
  const float* fus_bb = (const float*)d_in[35];
  const float* dec_W = (const float*)d_in[36];
  const float* dec_b = (const float*)d_in[37];

  float* ws = (float*)d_ws;
  size_t o = 0;
  float* pe = ws + o; o += 8192;
  float* g = ws + o; o += 161792;
  u16* wt = (u16*)(ws + o); o += 458752;   // 14 x 256x256 bf16
  float* h0 = ws + o; o += 8388608;
  float* h1 = ws + o; o += 4194304;
  float* h2 = ws + o; o += 2097152;
  u16* bXNu = (u16*)(ws + o); o += 4194304;
  u16* bXTu = (u16*)(ws + o); o += 4194304;
  u16* bZu = (u16*)(ws + o); o += 4194304;
  u16* bQu = (u16*)(ws + o); o += 4194304;
  u16* bKu = (u16*)(ws + o); o += 4194304;
  u16* bVu = (u16*)(ws + o); o += 4194304;
  u16* pooledu = (u16*)(ws + o); o += 393216;  // 1024 x 768 bf16
  u16* wFus = (u16*)(ws + o); o += 98304;      // 256 x 768 bf16
  float* fused = ws + o; o += 262144;
  float* bO = h0;   // attn outputs (fp32), h0 dead by then
  float* hh = h0;   // temp-gemm output, bO dead by then

  u16* wFeat = wt;
  u16* wDSm = wt + 1 * 65536;
  u16* wDSs = wt + 2 * 65536;
  u16* wTQ = wt + 3 * 65536;
  u16* wTK = wt + 4 * 65536;
  u16* wTV = wt + 5 * 65536;
  u16* wT1 = wt + 6 * 65536;
  u16* wT2 = wt + 7 * 65536;
  u16* wSQ = wt + 8 * 65536;
  u16* wSK = wt + 9 * 65536;
  u16* wSV = wt + 10 * 65536;
  u16* wS1 = wt + 11 * 65536;
  u16* wS2 = wt + 12 * 65536;
  u16* wTW = wt + 13 * 65536;

  k_pe<<<T0, DM, 0, stream>>>(pe);
  k_gate<<<NS, 256, 0, stream>>>(x, gate_W, gate_b, g);
  WPrep wp;
  wp.s[0] = feat_W; wp.s[1] = ds_mid_W; wp.s[2] = ds_small_W;
  wp.s[3] = tWq; wp.s[4] = tWk; wp.s[5] = tWv; wp.s[6] = tW1; wp.s[7] = tW2;
  wp.s[8] = sWq; wp.s[9] = sWk; wp.s[10] = sWv; wp.s[11] = sW1; wp.s[12] = sW2;
  wp.s[13] = temp_W;
  k_wprep<<<224, 256, 0, stream>>>(wp, wt);
  k_wtrans<<<dim3(12, 4), 256, 0, stream>>>(fus_W, wFus);

  k_fgemm<<<dim3(2, 256), 256, 0, stream>>>(x, g, wFeat, feat_b, pe, h0);

  k_poolmean<<<NS * 16, 256, 0, stream>>>(h0, bXNu, 16, 2);
  k_bgemm<true, false, false, false><<<dim3(2, 128, 1), 256, 0, stream>>>(
      bXNu, wDSm, wDSm, wDSm, ds_mid_b, nullptr, h1, h1, h1);
  k_poolmean<<<NS * 8, 256, 0, stream>>>(h0, bXNu, 8, 4);
  k_bgemm<true, false, false, false><<<dim3(2, 64, 1), 256, 0, stream>>>(
      bXNu, wDSs, wDSs, wDSs, ds_small_b, nullptr, h2, h2, h2);

  const float* hs[3] = {h0, h1, h2};
  const int Ts[3] = {32, 16, 8};
  for (int s = 0; s < 3; s++) {
    int T = Ts[s];
    int M = NS * T;
    dim3 g1(2, M / 128, 1), g3(2, M / 128, 3);
    const float* h = hs[s];
    // ---- time attention block ----
    k_ln<false, false><<<M, 256, 0, stream>>>(h, nullptr, tn1g, tn1b, bXNu);
    k_bgemm<false, false, false, true><<<g3, 256, 0, stream>>>(
        bXNu, wTQ, wTK, wTV, nullptr, nullptr, bQu, bKu, bVu);
    if (T == 32) k_tattn<32><<<NS, 256, 0, stream>>>(bQu, bKu, bVu, bO);
    else if (T == 16) k_tattn<16><<<NS, 256, 0, stream>>>(bQu, bKu, bVu, bO);
    else k_tattn<8><<<NS, 256, 0, stream>>>(bQu, bKu, bVu, bO);
    k_ln<true, true><<<M, 256, 0, stream>>>(bXNu, bO, tn2g, tn2b, bXTu);
    k_bgemm<true, true, false, true><<<g1, 256, 0, stream>>>(
        bXTu, wT1, wT1, wT1, tb1, nullptr, bXNu, bXNu, bXNu);
    k_bgemm<true, false, true, true><<<g1, 256, 0, stream>>>(
        bXNu, wT2, wT2, wT2, tb2, bXTu, bZu, bZu, bZu);
    // ---- stock attention block ----
    k_ln<false, true><<<M, 256, 0, stream>>>(bZu, nullptr, sn1g, sn1b, bXTu);
    k_bgemm<false, false, false, true><<<g3, 256, 0, stream>>>(
        bXTu, wSQ, wSK, wSV, nullptr, nullptr, bQu, bKu, bVu);
    k_sattn<<<T * 2 * 16, 256, 0, stream>>>(bQu, bKu, bVu, bO, T);
    k_ln<true, true><<<M, 256, 0, stream>>>(bXTu, bO, sn2g, sn2b, bZu);
    k_bgemm<true, true, false, true><<<g1, 256, 0, stream>>>(
        bZu, wS1, wS1, wS1, sb1, nullptr, bXNu, bXNu, bXNu);
    k_bgemm<true, false, true, true><<<g1, 256, 0, stream>>>(
        bXNu, wS2, wS2, wS2, sb2, bZu, bQu, bQu, bQu);  // z2 -> bQu
    k_bgemm<false, false, false, false><<<g1, 256, 0, stream>>>(
        bQu, wTW, wTW, wTW, nullptr, nullptr, hh, hh, hh);
    k_tpool<<<NS, 256, 0, stream>>>(hh, bQu, pooledu, T, s * DM);
  }

  k_fus<<<dim3(4, 16), 256, 0, stream>>>(pooledu, wFus, fus_b, fused);
  k_final<<<NS, 256, 0, stream>>>(fused, fus_g, fus_bb, dec_W, dec_b, (float*)d_out);
}

// Round 5
// 594.717 us; speedup vs baseline: 7.6521x; 1.3645x over previous
//
#include <hip/hip_runtime.h>
#include <math.h>

#define NS 1024
#define T0 32
#define DF 158
#define DG 63
#define DM 256
#define XROW (DF + DG)  // 221
// merged-scale row bases: h0 rows [0,32768), h1 [32768,49152), h2 [49152,57344)
#define MTOT 57344
#define B1R 32768
#define B2R 49152

typedef unsigned short u16;
typedef __attribute__((ext_vector_type(8))) short bf16x8_t;
typedef __attribute__((ext_vector_type(4))) float f32x4_t;

union frag_u {
  bf16x8_t f;
  unsigned short us[8];
  unsigned int u32[4];
};

__device__ inline unsigned short f2bf(float x) {
  unsigned int u = __float_as_uint(x);
  unsigned int r = u + 0x7fffu + ((u >> 16) & 1u);
  return (unsigned short)(r >> 16);
}
__device__ inline unsigned int pkbf(float lo, float hi) {
  return (unsigned int)f2bf(lo) | ((unsigned int)f2bf(hi) << 16);
}
__device__ inline float bf2f(u16 u) {
  return __uint_as_float(((unsigned int)u) << 16);
}
// v_cvt_pk_bf16_f32: D.lo16 = bf16(a), D.hi16 = bf16(b)
__device__ inline unsigned int cvtpk(float a, float b) {
  unsigned int r;
  asm("v_cvt_pk_bf16_f32 %0, %1, %2" : "=v"(r) : "v"(a), "v"(b));
  return r;
}

// ---------------- positional encoding table (32 x 256) ----------------
__global__ void k_pe(float* __restrict__ pe) {
  int t = blockIdx.x, d = threadIdx.x;
  int i2 = d & ~1;
  float div = expf((float)i2 * (-logf(10000.0f) / (float)DM));
  float ang = (float)t * div;
  pe[t * DM + d] = (d & 1) ? cosf(ang) : sinf(ang);
}

// ---------------- gate ----------------
__global__ void k_gate(const float* __restrict__ x, const float* __restrict__ gW,
                       const float* __restrict__ gb, float* __restrict__ g) {
  int n = blockIdx.x, tid = threadIdx.x;
  __shared__ float gin[DG];
  __shared__ float red[256];
  if (tid < DG) gin[tid] = x[(size_t)n * T0 * XROW + 31 * XROW + DF + tid];
  __syncthreads();
  float myv = 0.f;
  if (tid < DF) {
    float acc = gb[tid];
    for (int j = 0; j < DG; j++) acc = fmaf(gin[j], gW[j * DF + tid], acc);
    myv = acc * (1.0f / 5.0f);
  }
  red[tid] = (tid < DF) ? myv : -1e30f;
  __syncthreads();
  for (int s = 128; s > 0; s >>= 1) { if (tid < s) red[tid] = fmaxf(red[tid], red[tid + s]); __syncthreads(); }
  float mx = red[0];
  __syncthreads();
  float e = (tid < DF) ? expf(myv - mx) : 0.f;
  red[tid] = e;
  __syncthreads();
  for (int s = 128; s > 0; s >>= 1) { if (tid < s) red[tid] += red[tid + s]; __syncthreads(); }
  float sum = red[0];
  if (tid < DF) g[(size_t)n * DF + tid] = (float)DF * e / sum;
}

// ---------------- weight prep: W[K][256] fp32 -> Wt[256][256] bf16 (transposed, zero-pad K) ----------------
struct WPrep { const float* s[14]; };
__global__ __launch_bounds__(256) void k_wprep(WPrep w, u16* __restrict__ dst) {
  int mat = blockIdx.x >> 4, nb = blockIdx.x & 15;
  int tid = threadIdx.x;
  int n = nb * 16 + (tid >> 4);
  int kc = (tid & 15) * 16;
  const float* src = w.s[mat];
  int K = (mat == 0) ? DF : 256;
  frag_u f0, f1;
#pragma unroll
  for (int j = 0; j < 8; j++) {
    int k0 = kc + j, k1 = kc + 8 + j;
    f0.us[j] = (k0 < K) ? f2bf(src[(size_t)k0 * 256 + n]) : (u16)0;
    f1.us[j] = (k1 < K) ? f2bf(src[(size_t)k1 * 256 + n]) : (u16)0;
  }
  u16* d = dst + (size_t)mat * 65536 + (size_t)n * 256 + kc;
  *(bf16x8_t*)d = f0.f;
  *(bf16x8_t*)(d + 8) = f1.f;
}

// ---------------- fus_W transpose: [768][256] fp32 -> [256][768] bf16 ----------------
__global__ __launch_bounds__(256) void k_wtrans(const float* __restrict__ W, u16* __restrict__ Wt) {
  __shared__ u16 Ts[64][65];
  int k0 = blockIdx.x * 64, n0 = blockIdx.y * 64;
  int tid = threadIdx.x;
#pragma unroll
  for (int i = 0; i < 16; i++) {
    int e = tid + i * 256;
    int r = e >> 6, c = e & 63;
    Ts[r][c] = f2bf(W[(size_t)(k0 + r) * 256 + n0 + c]);
  }
  __syncthreads();
#pragma unroll
  for (int i = 0; i < 16; i++) {
    int e = tid + i * 256;
    int r = e >> 6, c = e & 63;
    Wt[(size_t)(n0 + r) * 768 + k0 + c] = Ts[c][r];
  }
}

// ---------------- bf16 MFMA GEMM: C = act(A@Bt^T + bias + res) ----------------
template <bool BIAS, bool RELU, bool RES, bool OUTBF>
__global__ __launch_bounds__(256) void k_bgemm(
    const u16* __restrict__ A,
    const u16* __restrict__ B0, const u16* __restrict__ B1, const u16* __restrict__ B2,
    const float* __restrict__ bias, const u16* __restrict__ res,
    void* __restrict__ C0, void* __restrict__ C1, void* __restrict__ C2) {
  __shared__ __align__(16) unsigned char sm[32768];
  unsigned char* As = sm;
  unsigned char* Bs = sm + 16384;
  const u16* Bt = blockIdx.z == 0 ? B0 : (blockIdx.z == 1 ? B1 : B2);
  void* Cv = blockIdx.z == 0 ? C0 : (blockIdx.z == 1 ? C1 : C2);
  int m0 = blockIdx.y * 128, n0w = blockIdx.x * 128;
  int tid = threadIdx.x, lane = tid & 63, wid = tid >> 6;
  int qi = lane & 15, g = lane >> 4;
  int wr = wid >> 1, wc = wid & 1;
  f32x4_t acc[4][4];
#pragma unroll
  for (int i = 0; i < 4; i++)
#pragma unroll
    for (int j = 0; j < 4; j++) acc[i][j] = (f32x4_t){0.f, 0.f, 0.f, 0.f};
  for (int kt = 0; kt < 4; kt++) {
    if (kt) __syncthreads();
#pragma unroll
    for (int i = 0; i < 4; i++) {
      int cid = tid + i * 256;
      int row = cid >> 3, c = cid & 7;
      int swz = (c * 16) ^ ((row & 7) << 4);
      bf16x8_t va = *(const bf16x8_t*)(A + (size_t)(m0 + row) * 256 + kt * 64 + c * 8);
      *(bf16x8_t*)(As + row * 128 + swz) = va;
      bf16x8_t vb = *(const bf16x8_t*)(Bt + (size_t)(n0w + row) * 256 + kt * 64 + c * 8);
      *(bf16x8_t*)(Bs + row * 128 + swz) = vb;
    }
    __syncthreads();
    bf16x8_t Af[2][4], Bf[2][4];
#pragma unroll
    for (int mi = 0; mi < 4; mi++) {
      int row = wr * 64 + mi * 16 + qi;
      int swz = (row & 7) << 4;
      const unsigned char* ap = As + row * 128;
      Af[0][mi] = *(const bf16x8_t*)(ap + ((g * 16) ^ swz));
      Af[1][mi] = *(const bf16x8_t*)(ap + ((64 + g * 16) ^ swz));
    }
#pragma unroll
    for (int ni = 0; ni < 4; ni++) {
      int row = wc * 64 + ni * 16 + qi;
      int swz = (row & 7) << 4;
      const unsigned char* bp = Bs + row * 128;
      Bf[0][ni] = *(const bf16x8_t*)(bp + ((g * 16) ^ swz));
      Bf[1][ni] = *(const bf16x8_t*)(bp + ((64 + g * 16) ^ swz));
    }
#pragma unroll
    for (int ks = 0; ks < 2; ks++)
#pragma unroll
      for (int mi = 0; mi < 4; mi++)
#pragma unroll
        for (int ni = 0; ni < 4; ni++)
          acc[mi][ni] = __builtin_amdgcn_mfma_f32_16x16x32_bf16(Af[ks][mi], Bf[ks][ni], acc[mi][ni], 0, 0, 0);
  }
#pragma unroll
  for (int mi = 0; mi < 4; mi++) {
#pragma unroll
    for (int ni = 0; ni < 4; ni++) {
#pragma unroll
      for (int r = 0; r < 4; r++) {
        int row = m0 + wr * 64 + mi * 16 + 4 * g + r;
        int col = n0w + wc * 64 + ni * 16 + qi;
        float vv = acc[mi][ni][r];
        if (BIAS) vv += bias[col];
        if (RES) vv += bf2f(res[(size_t)row * 256 + col]);
        if (RELU) vv = fmaxf(vv, 0.f);
        if (OUTBF) ((u16*)Cv)[(size_t)row * 256 + col] = f2bf(vv);
        else ((float*)Cv)[(size_t)row * 256 + col] = vv;
      }
    }
  }
}

// ---------------- feat GEMM: h = (x*gate)@feat_W + bias + pe, fp32 out ----------------
__global__ __launch_bounds__(256) void k_fgemm(
    const float* __restrict__ x, const float* __restrict__ gate,
    const u16* __restrict__ Bt, const float* __restrict__ bias,
    const float* __restrict__ pe, float* __restrict__ C) {
  __shared__ __align__(16) unsigned char sm[32768];
  unsigned char* As = sm;
  unsigned char* Bs = sm + 16384;
  int m0 = blockIdx.y * 128, n0w = blockIdx.x * 128;
  int tid = threadIdx.x, lane = tid & 63, wid = tid >> 6;
  int qi = lane & 15, g = lane >> 4;
  int wr = wid >> 1, wc = wid & 1;
  f32x4_t acc[4][4];
#pragma unroll
  for (int i = 0; i < 4; i++)
#pragma unroll
    for (int j = 0; j < 4; j++) acc[i][j] = (f32x4_t){0.f, 0.f, 0.f, 0.f};
  for (int kt = 0; kt < 3; kt++) {
    if (kt) __syncthreads();
#pragma unroll
    for (int i = 0; i < 4; i++) {
      int cid = tid + i * 256;
      int row = cid >> 3, c = cid & 7;
      int swz = (c * 16) ^ ((row & 7) << 4);
      int gk0 = kt * 64 + c * 8;
      const float* xr = x + (size_t)(m0 + row) * XROW;
      const float* gr = gate + (size_t)((m0 + row) >> 5) * DF;
      frag_u f;
#pragma unroll
      for (int j = 0; j < 8; j++) {
        int gk = gk0 + j;
        f.us[j] = (gk < DF) ? f2bf(xr[gk] * gr[gk]) : (u16)0;
      }
      *(bf16x8_t*)(As + row * 128 + swz) = f.f;
      bf16x8_t vb = *(const bf16x8_t*)(Bt + (size_t)(n0w + row) * 256 + kt * 64 + c * 8);
      *(bf16x8_t*)(Bs + row * 128 + swz) = vb;
    }
    __syncthreads();
    bf16x8_t Af[2][4], Bf[2][4];
#pragma unroll
    for (int mi = 0; mi < 4; mi++) {
      int row = wr * 64 + mi * 16 + qi;
      int swz = (row & 7) << 4;
      const unsigned char* ap = As + row * 128;
      Af[0][mi] = *(const bf16x8_t*)(ap + ((g * 16) ^ swz));
      Af[1][mi] = *(const bf16x8_t*)(ap + ((64 + g * 16) ^ swz));
    }
#pragma unroll
    for (int ni = 0; ni < 4; ni++) {
      int row = wc * 64 + ni * 16 + qi;
      int swz = (row & 7) << 4;
      const unsigned char* bp = Bs + row * 128;
      Bf[0][ni] = *(const bf16x8_t*)(bp + ((g * 16) ^ swz));
      Bf[1][ni] = *(const bf16x8_t*)(bp + ((64 + g * 16) ^ swz));
    }
#pragma unroll
    for (int ks = 0; ks < 2; ks++)
#pragma unroll
      for (int mi = 0; mi < 4; mi++)
#pragma unroll
        for (int ni = 0; ni < 4; ni++)
          acc[mi][ni] = __builtin_amdgcn_mfma_f32_16x16x32_bf16(Af[ks][mi], Bf[ks][ni], acc[mi][ni], 0, 0, 0);
  }
#pragma unroll
  for (int mi = 0; mi < 4; mi++) {
#pragma unroll
    for (int ni = 0; ni < 4; ni++) {
#pragma unroll
      for (int r = 0; r < 4; r++) {
        int row = m0 + wr * 64 + mi * 16 + 4 * g + r;
        int col = n0w + wc * 64 + ni * 16 + qi;
        C[(size_t)row * 256 + col] = acc[mi][ni][r] + bias[col] + pe[(row & (T0 - 1)) * DM + col];
      }
    }
  }
}

// ---------------- fus GEMM: fused = pooled @ fus_W + fus_b ----------------
__global__ __launch_bounds__(256) void k_fus(const u16* __restrict__ A, const u16* __restrict__ Bt,
                                             const float* __restrict__ bias, float* __restrict__ C) {
  __shared__ __align__(16) unsigned char sm[16384];
  unsigned char* As = sm;
  unsigned char* Bs = sm + 8192;
  int n0 = blockIdx.x * 64, m0 = blockIdx.y * 64;
  int tid = threadIdx.x, lane = tid & 63, wid = tid >> 6;
  int qi = lane & 15, g = lane >> 4;
  f32x4_t acc[4];
#pragma unroll
  for (int i = 0; i < 4; i++) acc[i] = (f32x4_t){0.f, 0.f, 0.f, 0.f};
  for (int kt = 0; kt < 12; kt++) {
    if (kt) __syncthreads();
#pragma unroll
    for (int i = 0; i < 2; i++) {
      int cid = tid + i * 256;
      int row = cid >> 3, c = cid & 7;
      int swz = (c * 16) ^ ((row & 7) << 4);
      *(bf16x8_t*)(As + row * 128 + swz) = *(const bf16x8_t*)(A + (size_t)(m0 + row) * 768 + kt * 64 + c * 8);
      *(bf16x8_t*)(Bs + row * 128 + swz) = *(const bf16x8_t*)(Bt + (size_t)(n0 + row) * 768 + kt * 64 + c * 8);
    }
    __syncthreads();
    int arow = wid * 16 + qi;
    int asw = (arow & 7) << 4;
    bf16x8_t Af0 = *(const bf16x8_t*)(As + arow * 128 + ((g * 16) ^ asw));
    bf16x8_t Af1 = *(const bf16x8_t*)(As + arow * 128 + ((64 + g * 16) ^ asw));
#pragma unroll
    for (int ni = 0; ni < 4; ni++) {
      int brow = ni * 16 + qi;
      int bsw = (brow & 7) << 4;
      bf16x8_t B0 = *(const bf16x8_t*)(Bs + brow * 128 + ((g * 16) ^ bsw));
      bf16x8_t B1 = *(const bf16x8_t*)(Bs + brow * 128 + ((64 + g * 16) ^ bsw));
      acc[ni] = __builtin_amdgcn_mfma_f32_16x16x32_bf16(Af0, B0, acc[ni], 0, 0, 0);
      acc[ni] = __builtin_amdgcn_mfma_f32_16x16x32_bf16(Af1, B1, acc[ni], 0, 0, 0);
    }
  }
#pragma unroll
  for (int ni = 0; ni < 4; ni++)
#pragma unroll
    for (int r = 0; r < 4; r++) {
      int row = m0 + wid * 16 + 4 * g + r;
      int col = n0 + ni * 16 + qi;
      C[(size_t)row * 256 + col] = acc[ni][r] + bias[col];
    }
}

// ---------------- LayerNorm: wave per row, 4 rows/block ----------------
template <bool RES, bool ABF>
__global__ __launch_bounds__(256) void k_ln(const void* __restrict__ a, const float* __restrict__ b,
                                            const float* __restrict__ g, const float* __restrict__ be,
                                            u16* __restrict__ out) {
  int row = blockIdx.x * 4 + (threadIdx.x >> 6);
  int lane = threadIdx.x & 63;
  size_t base = (size_t)row * DM + lane * 4;
  float v[4];
  if (ABF) {
    ushort4 u = *(const ushort4*)((const u16*)a + base);
    v[0] = bf2f(u.x); v[1] = bf2f(u.y); v[2] = bf2f(u.z); v[3] = bf2f(u.w);
  } else {
    f32x4_t t = *(const f32x4_t*)((const float*)a + base);
    v[0] = t[0]; v[1] = t[1]; v[2] = t[2]; v[3] = t[3];
  }
  if (RES) {
    f32x4_t t = *(const f32x4_t*)(b + base);
    v[0] += t[0]; v[1] += t[1]; v[2] += t[2]; v[3] += t[3];
  }
  float s = v[0] + v[1] + v[2] + v[3];
#pragma unroll
  for (int off = 1; off < 64; off <<= 1) s += __shfl_xor(s, off);
  float mean = s * (1.0f / DM);
  float d0 = v[0] - mean, d1 = v[1] - mean, d2 = v[2] - mean, d3 = v[3] - mean;
  float ss = d0 * d0 + d1 * d1 + d2 * d2 + d3 * d3;
#pragma unroll
  for (int off = 1; off < 64; off <<= 1) ss += __shfl_xor(ss, off);
  float inv = rsqrtf(ss * (1.0f / DM) + 1e-5f);
  f32x4_t gg = *(const f32x4_t*)(g + lane * 4);
  f32x4_t bb = *(const f32x4_t*)(be + lane * 4);
  ushort4 o4;
  o4.x = f2bf(d0 * inv * gg[0] + bb[0]);
  o4.y = f2bf(d1 * inv * gg[1] + bb[1]);
  o4.z = f2bf(d2 * inv * gg[2] + bb[2]);
  o4.w = f2bf(d3 * inv * gg[3] + bb[3]);
  *(ushort4*)(out + base) = o4;
}

// ---------------- mean-pool over time groups (bf16 out), 4 elems/thread ----------------
__global__ void k_poolmean(const float* __restrict__ h, u16* __restrict__ out, int Tout, int P) {
  int vi = blockIdx.x * 256 + threadIdx.x;
  int dv = vi & 63;
  int rowi = vi >> 6;
  int to = rowi % Tout;
  int n = rowi / Tout;
  int Tin = Tout * P;
  float s0 = 0.f, s1 = 0.f, s2 = 0.f, s3 = 0.f;
  for (int p = 0; p < P; p++) {
    f32x4_t t = *(const f32x4_t*)(h + ((size_t)(n * Tin + to * P + p)) * DM + dv * 4);
    s0 += t[0]; s1 += t[1]; s2 += t[2]; s3 += t[3];
  }
  float inv = 1.0f / (float)P;
  ushort4 o4;
  o4.x = f2bf(s0 * inv); o4.y = f2bf(s1 * inv); o4.z = f2bf(s2 * inv); o4.w = f2bf(s3 * inv);
  *(ushort4*)(out + (size_t)rowi * DM + dv * 4) = o4;
}

// ---------------- time attention via MFMA, sigma-permuted PV (no P-LDS) ----------------
template <int T>
__global__ __launch_bounds__(256) void k_tattn(const u16* __restrict__ q, const u16* __restrict__ k,
                                               const u16* __restrict__ v, float* __restrict__ o) {
  constexpr int TR = (T < 16) ? 16 : T;
  constexpr int QKB = TR * 128;
  constexpr int HS = 2 * QKB + 64 * 80;
  __shared__ __align__(16) unsigned char smem[4 * HS];
  int n = blockIdx.x;
  int tid = threadIdx.x, lane = tid & 63, h = tid >> 6;
  int qi = lane & 15, g = lane >> 4;
  unsigned char* Qs = smem + h * HS;
  unsigned char* Ks = Qs + QKB;
  unsigned char* Vt = Ks + QKB;

  const u16* qh = q + (size_t)n * T * 256 + h * 64;
  const u16* kh = k + (size_t)n * T * 256 + h * 64;
  const u16* vh = v + (size_t)n * T * 256 + h * 64;
  const bf16x8_t zero8 = {0, 0, 0, 0, 0, 0, 0, 0};

  for (int idx = lane; idx < TR * 8; idx += 64) {
    int row = idx >> 3, c = idx & 7;
    bf16x8_t vq = zero8, vk = zero8;
    if (row < T) {
      vq = *(const bf16x8_t*)(qh + (size_t)row * 256 + c * 8);
      vk = *(const bf16x8_t*)(kh + (size_t)row * 256 + c * 8);
    }
    int off = row * 128 + ((c * 16) ^ ((row & 7) << 4));
    *(bf16x8_t*)(Qs + off) = vq;
    *(bf16x8_t*)(Ks + off) = vk;
  }
  // V staged transposed with sigma-permuted key positions: slot s=8g+e <-> key 16*(e>>2)+4g+(e&3)
  {
    int kp = lane & 15, dg = lane >> 4;
    int d0 = dg * 16;
    int kk = 2 * kp;
    int cb = ((((kk >> 2) & 3) << 3) | (((kk >> 4) & 1) << 2) | (kk & 3)) * 2;
    frag_u a0, a1, b0, b1;
    a0.f = a1.f = b0.f = b1.f = zero8;
    if (kk < T) {
      a0.f = *(const bf16x8_t*)(vh + (size_t)kk * 256 + d0);
      a1.f = *(const bf16x8_t*)(vh + (size_t)kk * 256 + d0 + 8);
    }
    if (kk + 1 < T) {
      b0.f = *(const bf16x8_t*)(vh + (size_t)(kk + 1) * 256 + d0);
      b1.f = *(const bf16x8_t*)(vh + (size_t)(kk + 1) * 256 + d0 + 8);
    }
#pragma unroll
    for (int i = 0; i < 8; i++)
      *(unsigned int*)(Vt + (d0 + i) * 80 + cb) = (unsigned int)a0.us[i] | ((unsigned int)b0.us[i] << 16);
#pragma unroll
    for (int i = 0; i < 8; i++)
      *(unsigned int*)(Vt + (d0 + 8 + i) * 80 + cb) = (unsigned int)a1.us[i] | ((unsigned int)b1.us[i] << 16);
  }
  __syncthreads();

  constexpr int NQT = (T == 32) ? 2 : 1;
  constexpr int NSUB = (T == 32) ? 2 : 1;
  const float scale = 0.125f;  // 1/sqrt(256/4)

  bf16x8_t Qb[NQT][2];
#pragma unroll
  for (int qt = 0; qt < NQT; qt++) {
    int row = qt * 16 + qi;
    int sw = (row & 7) << 4;
#pragma unroll
    for (int kst = 0; kst < 2; kst++)
      Qb[qt][kst] = *(const bf16x8_t*)(Qs + row * 128 + ((kst * 64 + g * 16) ^ sw));
  }
  f32x4_t sacc[NQT][NSUB];
#pragma unroll
  for (int qt = 0; qt < NQT; qt++)
#pragma unroll
    for (int sub = 0; sub < NSUB; sub++) sacc[qt][sub] = (f32x4_t){0.f, 0.f, 0.f, 0.f};
#pragma unroll
  for (int sub = 0; sub < NSUB; sub++) {
    int row = sub * 16 + qi;
    int sw = (row & 7) << 4;
    bf16x8_t Ka[2];
#pragma unroll
    for (int kst = 0; kst < 2; kst++)
      Ka[kst] = *(const bf16x8_t*)(Ks + row * 128 + ((kst * 64 + g * 16) ^ sw));
#pragma unroll
    for (int qt = 0; qt < NQT; qt++)
#pragma unroll
      for (int kst = 0; kst < 2; kst++)
        sacc[qt][sub] = __builtin_amdgcn_mfma_f32_16x16x32_bf16(Ka[kst], Qb[qt][kst], sacc[qt][sub], 0, 0, 0);
  }
  // softmax per query column; P packed in-register (sigma layout: Pa slot e = p[e>>2][e&3])
  frag_u Pf[NQT];
#pragma unroll
  for (int qt = 0; qt < NQT; qt++) {
    float sv[NSUB][4];
    float mx = -3.0e38f;
#pragma unroll
    for (int sub = 0; sub < NSUB; sub++)
#pragma unroll
      for (int r = 0; r < 4; r++) {
        int key = sub * 16 + 4 * g + r;
        float s = sacc[qt][sub][r] * scale;
        if (key >= T) s = -3.0e38f;
        sv[sub][r] = s;
        mx = fmaxf(mx, s);
      }
    mx = fmaxf(mx, __shfl_xor(mx, 16));
    mx = fmaxf(mx, __shfl_xor(mx, 32));
    float p[NSUB][4];
    float l = 0.f;
#pragma unroll
    for (int sub = 0; sub < NSUB; sub++)
#pragma unroll
      for (int r = 0; r < 4; r++) {
        float e = __expf(sv[sub][r] - mx);
        p[sub][r] = e;
        l += e;
      }
    l += __shfl_xor(l, 16);
    l += __shfl_xor(l, 32);
    float linv = 1.0f / l;
    Pf[qt].u32[0] = cvtpk(p[0][0] * linv, p[0][1] * linv);
    Pf[qt].u32[1] = cvtpk(p[0][2] * linv, p[0][3] * linv);
    if (NSUB == 2) {
      Pf[qt].u32[2] = cvtpk(p[NSUB - 1][0] * linv, p[NSUB - 1][1] * linv);
      Pf[qt].u32[3] = cvtpk(p[NSUB - 1][2] * linv, p[NSUB - 1][3] * linv);
    } else {
      Pf[qt].u32[2] = 0u;
      Pf[qt].u32[3] = 0u;
    }
  }
  // PV
  f32x4_t oacc[NQT][4];
#pragma unroll
  for (int qt = 0; qt < NQT; qt++)
#pragma unroll
    for (int ni = 0; ni < 4; ni++) oacc[qt][ni] = (f32x4_t){0.f, 0.f, 0.f, 0.f};
#pragma unroll
  for (int ni = 0; ni < 4; ni++) {
    bf16x8_t Vb = *(const bf16x8_t*)(Vt + (ni * 16 + qi) * 80 + g * 16);
#pragma unroll
    for (int qt = 0; qt < NQT; qt++)
      oacc[qt][ni] = __builtin_amdgcn_mfma_f32_16x16x32_bf16(Pf[qt].f, Vb, oacc[qt][ni], 0, 0, 0);
  }
#pragma unroll
  for (int qt = 0; qt < NQT; qt++)
#pragma unroll
    for (int ni = 0; ni < 4; ni++)
#pragma unroll
      for (int r = 0; r < 4; r++) {
        int qq = qt * 16 + 4 * g + r;
        if (qq < T) o[((size_t)(n * T + qq)) * 256 + h * 64 + ni * 16 + qi] = oacc[qt][ni][r];
      }
}

// ---------------- stock attention, all 3 scales in one dispatch; sigma-PV, defer-max ----------------
__global__ __launch_bounds__(256) void k_sattn(const u16* __restrict__ q, const u16* __restrict__ k,
                                               const u16* __restrict__ v, float* __restrict__ o) {
  __shared__ __align__(16) unsigned char smem[32768];
  unsigned char* Ks = smem;
  unsigned char* Vt = smem + 16384;

  int bid = blockIdx.x;
  int T, rowbase;
  if (bid < 1024) { T = 32; rowbase = 0; }
  else if (bid < 1536) { T = 16; rowbase = B1R; bid -= 1024; }
  else { T = 8; rowbase = B2R; bid -= 1536; }
  const int NTH = T * 2;
  int xcd = bid & 7, slot = bid >> 3;
  int th = xcd * (NTH >> 3) + (slot >> 4);
  int qb = slot & 15;
  int t = th >> 1, h = th & 1;

  int tid = threadIdx.x;
  int lane = tid & 63;
  int wid = tid >> 6;
  int qi = lane & 15;
  int g = lane >> 4;
  const float invtemp = 0.08838834764831845f;  // 1/sqrt(128)

  const size_t rs = (size_t)T * 256;
  const size_t hb = (size_t)rowbase * 256 + (size_t)t * 256 + h * 128;
  const u16* qp = q + hb;
  const u16* kp = k + hb;
  const u16* vp = v + hb;
  float* op = o + hb;

  int q0 = qb * 64 + wid * 16;

  bf16x8_t Qf[4];
  {
    const u16* src = qp + (size_t)(q0 + qi) * rs + g * 8;
#pragma unroll
    for (int kst = 0; kst < 4; kst++) Qf[kst] = *(const bf16x8_t*)(src + kst * 32);
  }

  f32x4_t Oacc[8];
#pragma unroll
  for (int i = 0; i < 8; i++) Oacc[i] = (f32x4_t){0.f, 0.f, 0.f, 0.f};
  float mrun = -3.0e38f, lrun = 0.f;

  // sigma position for V staging (constant per thread)
  int kpair = tid & 31, dg = tid >> 5;
  int d0s = dg * 16;
  int kk = 2 * kpair;
  int cb = (((kk >> 5) << 5) | (((kk >> 2) & 3) << 3) | (((kk >> 4) & 1) << 2) | (kk & 3)) * 2;

  for (int kb = 0; kb < NS; kb += 64) {
    __syncthreads();
    // stage K tile (swizzled rows)
#pragma unroll
    for (int i = 0; i < 4; i++) {
      int cid = tid + i * 256;
      int row = cid >> 4, ch = cid & 15;
      bf16x8_t kv = *(const bf16x8_t*)(kp + (size_t)(kb + row) * rs + ch * 8);
      *(bf16x8_t*)(Ks + row * 256 + ((ch * 16) ^ ((row & 7) << 4))) = kv;
    }
    // stage V transposed, sigma-permuted key columns
    {
      const u16* s0 = vp + (size_t)(kb + kk) * rs + d0s;
      const u16* s1 = s0 + rs;
      frag_u a0, a1, b0, b1;
      a0.f = *(const bf16x8_t*)s0;
      a1.f = *(const bf16x8_t*)(s0 + 8);
      b0.f = *(const bf16x8_t*)s1;
      b1.f = *(const bf16x8_t*)(s1 + 8);
#pragma unroll
      for (int i = 0; i < 8; i++) {
        int d = d0s + i;
        *(unsigned int*)(Vt + d * 128 + (cb ^ ((d & 7) << 4))) =
            (unsigned int)a0.us[i] | ((unsigned int)b0.us[i] << 16);
      }
#pragma unroll
      for (int i = 0; i < 8; i++) {
        int d = d0s + 8 + i;
        *(unsigned int*)(Vt + d * 128 + (cb ^ ((d & 7) << 4))) =
            (unsigned int)a1.us[i] | ((unsigned int)b1.us[i] << 16);
      }
    }
    __syncthreads();

    // QK^T (swapped): lane holds S[query=qi][key=16sub+4g+r]
    f32x4_t sacc[4];
#pragma unroll
    for (int i = 0; i < 4; i++) sacc[i] = (f32x4_t){0.f, 0.f, 0.f, 0.f};
#pragma unroll
    for (int sub = 0; sub < 4; sub++) {
      int row = sub * 16 + qi;
      int swz = (row & 7) << 4;
      const unsigned char* kr = Ks + row * 256;
#pragma unroll
      for (int kst = 0; kst < 4; kst++) {
        bf16x8_t Af = *(const bf16x8_t*)(kr + ((g * 16 + kst * 64) ^ swz));
        sacc[sub] = __builtin_amdgcn_mfma_f32_16x16x32_bf16(Af, Qf[kst], sacc[sub], 0, 0, 0);
      }
    }

    float sv[4][4];
    float pmax = -3.0e38f;
#pragma unroll
    for (int sub = 0; sub < 4; sub++)
#pragma unroll
      for (int r = 0; r < 4; r++) {
        sv[sub][r] = sacc[sub][r] * invtemp;
        pmax = fmaxf(pmax, sv[sub][r]);
      }
    pmax = fmaxf(pmax, __shfl_xor(pmax, 16));
    pmax = fmaxf(pmax, __shfl_xor(pmax, 32));
    // defer-max: rescale only when max grew past threshold (T13)
    if (__any(pmax - mrun > 8.0f)) {
      float mnew = fmaxf(mrun, pmax);
      float fac = __expf(mrun - mnew);
      lrun *= fac;
      float fr[4];
#pragma unroll
      for (int r = 0; r < 4; r++) fr[r] = __shfl(fac, (g << 2) | r);
#pragma unroll
      for (int dsub = 0; dsub < 8; dsub++)
#pragma unroll
        for (int r = 0; r < 4; r++) Oacc[dsub][r] *= fr[r];
      mrun = mnew;
    }
    float p[4][4];
    float ls = 0.f;
#pragma unroll
    for (int sub = 0; sub < 4; sub++)
#pragma unroll
      for (int r = 0; r < 4; r++) {
        float e = __expf(sv[sub][r] - mrun);
        p[sub][r] = e;
        ls += e;
      }
    ls += __shfl_xor(ls, 16);
    ls += __shfl_xor(ls, 32);
    lrun += ls;

    // P A-fragments, lane-local via sigma: Pa[kst] slot e = p[2kst + (e>>2)][e&3]
    frag_u pf0, pf1;
    pf0.u32[0] = cvtpk(p[0][0], p[0][1]);
    pf0.u32[1] = cvtpk(p[0][2], p[0][3]);
    pf0.u32[2] = cvtpk(p[1][0], p[1][1]);
    pf0.u32[3] = cvtpk(p[1][2], p[1][3]);
    pf1.u32[0] = cvtpk(p[2][0], p[2][1]);
    pf1.u32[1] = cvtpk(p[2][2], p[2][3]);
    pf1.u32[2] = cvtpk(p[3][0], p[3][1]);
    pf1.u32[3] = cvtpk(p[3][2], p[3][3]);

#pragma unroll
    for (int kst = 0; kst < 2; kst++) {
      bf16x8_t Pa = kst ? pf1.f : pf0.f;
#pragma unroll
      for (int dsub = 0; dsub < 8; dsub++) {
        int row = dsub * 16 + qi;
        bf16x8_t Vb = *(const bf16x8_t*)(Vt + row * 128 + ((g * 16 + kst * 64) ^ ((row & 7) << 4)));
        Oacc[dsub] = __builtin_amdgcn_mfma_f32_16x16x32_bf16(Pa, Vb, Oacc[dsub], 0, 0, 0);
      }
    }
  }

  float rin[4];
#pragma unroll
  for (int r = 0; r < 4; r++) rin[r] = 1.0f / __shfl(lrun, (g << 2) | r);
#pragma unroll
  for (int dsub = 0; dsub < 8; dsub++)
#pragma unroll
    for (int r = 0; r < 4; r++) {
      size_t row = (size_t)(q0 + 4 * g + r);
      op[row * rs + dsub * 16 + qi] = Oacc[dsub][r] * rin[r];
    }
}

// ---------------- temporal pooling (hh fp32, z bf16) -> pooled bf16 [n][768] ----------------
__global__ __launch_bounds__(256) void k_tpool(const float* __restrict__ hh, const u16* __restrict__ z,
                                               u16* __restrict__ pooled, int T, int off) {
  int n = blockIdx.x, d = threadIdx.x;
  __shared__ float red[256];
  __shared__ float lam[T0];
  __shared__ float lame[T0];
  float last = hh[((size_t)(n * T + T - 1)) * DM + d];
  for (int t = 0; t < T; t++) {
    red[d] = hh[((size_t)(n * T + t)) * DM + d] * last;
    __syncthreads();
    for (int s = 128; s > 0; s >>= 1) { if (d < s) red[d] += red[d + s]; __syncthreads(); }
    if (d == 0) lam[t] = red[0];
    __syncthreads();
  }
  float mx = -1e30f;
  for (int t = 0; t < T; t++) mx = fmaxf(mx, lam[t]);
  if (d < T) lame[d] = expf(lam[d] - mx);
  __syncthreads();
  float sum = 0.f;
  for (int t = 0; t < T; t++) sum += lame[t];
  float acc = 0.f;
  for (int t = 0; t < T; t++) acc += lame[t] * bf2f(z[((size_t)(n * T + t)) * DM + d]);
  pooled[(size_t)n * 768 + off + d] = f2bf(acc / sum);
}

// ---------------- final ----------------
__global__ __launch_bounds__(256) void k_final(const float* __restrict__ f, const float* __restrict__ g,
                                               const float* __restrict__ b, const float* __restrict__ dw,
                                               const float* __restrict__ db, float* __restrict__ out) {
  int n = blockIdx.x, d = threadIdx.x;
  float v = f[(size_t)n * DM + d];
  __shared__ float red[256];
  red[d] = v;
  __syncthreads();
  for (int s = 128; s > 0; s >>= 1) { if (d < s) red[d] += red[d + s]; __syncthreads(); }
  float mean = red[0] * (1.0f / DM);
  __syncthreads();
  float dv = v - mean;
  red[d] = dv * dv;
  __syncthreads();
  for (int s = 128; s > 0; s >>= 1) { if (d < s) red[d] += red[d + s]; __syncthreads(); }
  float var = red[0] * (1.0f / DM);
  __syncthreads();
  float y = dv * rsqrtf(var + 1e-5f) * g[d] + b[d];
  y = fmaxf(y, 0.f);
  red[d] = y * dw[d];
  __syncthreads();
  for (int s = 128; s > 0; s >>= 1) { if (d < s) red[d] += red[d + s]; __syncthreads(); }
  if (d == 0) out[n] = red[0] + db[0];
}

extern "C" void kernel_launch(void* const* d_in, const int* in_sizes, int n_in,
                              void* d_out, int out_size, void* d_ws, size_t ws_size,
                              hipStream_t stream) {
  const float* x = (const float*)d_in[0];
  const float* gate_W = (const float*)d_in[1];
  const float* gate_b = (const float*)d_in[2];
  const float* feat_W = (const float*)d_in[3];
  const float* feat_b = (const float*)d_in[4];
  const float* ds_mid_W = (const float*)d_in[5];
  const float* ds_mid_b = (const float*)d_in[6];
  const float* ds_small_W = (const float*)d_in[7];
  const float* ds_small_b = (const float*)d_in[8];
  const float* tn1g = (const float*)d_in[9];
  const float* tn1b = (const float*)d_in[10];
  const float* tWq = (const float*)d_in[11];
  const float* tWk = (const float*)d_in[12];
  const float* tWv = (const float*)d_in[13];
  const float* tn2g = (const float*)d_in[14];
  const float* tn2b = (const float*)d_in[15];
  const float* tW1 = (const float*)d_in[16];
  const float* tb1 = (const float*)d_in[17];
  const float* tW2 = (const float*)d_in[18];
  const float* tb2 = (const float*)d_in[19];
  const float* sn1g = (const float*)d_in[20];
  const float* sn1b = (const float*)d_in[21];
  const float* sWq = (const float*)d_in[22];
  const float* sWk = (const float*)d_in[23];
  const float* sWv = (const float*)d_in[24];
  const float* sn2g = (const float*)d_in[25];
  const float* sn2b = (const float*)d_in[26];
  const float* sW1 = (const float*)d_in[27];
  const float* sb1 = (const float*)d_in[28];
  const float* sW2 = (const float*)d_in[29];
  const float* sb2 = (const float*)d_in[30];
  const float* temp_W = (const float*)d_in[31];
  const float* fus_W = (const float*)d_in[32];
  const float* fus_b = (const float*)d_in[33];
  const float* fus_g = (const float*)d_in[34];
  const float* fus_bb = (const float*)d_in[35];
  const float* dec_W = (const float*)d_in[36];
  const float* dec_b = (const float*)d_in[37];

  float* ws = (float*)d_ws;
  size_t o = 0;
  float* pe = ws + o; o += 8192;
  float* g = ws + o; o += 161792;
  u16* wt = (u16*)(ws + o); o += 458752;        // 14 x 256x256 bf16
  float* hcat = ws + o; o += (size_t)MTOT * 256;     // fp32 slab: h -> bO -> hh -> fused
  u16* bXNu = (u16*)(ws + o); o += (size_t)MTOT * 128;
  u16* bQu = (u16*)(ws + o); o += (size_t)MTOT * 128;
  u16* bKu = (u16*)(ws + o); o += (size_t)MTOT * 128;
  u16* bVu = (u16*)(ws + o); o += (size_t)MTOT * 128;
  float* bO = hcat;
  float* hh = hcat;
  float* fused = hcat;
  u16* pooledu = bXNu;   // alias: xn2 dead before tpool
  u16* wFus = bKu;       // alias: written by wtrans after bKu dead

  u16* wFeat = wt;
  u16* wDSm = wt + 1 * 65536;
  u16* wDSs = wt + 2 * 65536;
  u16* wTQ = wt + 3 * 65536;
  u16* wTK = wt + 4 * 65536;
  u16* wTV = wt + 5 * 65536;
  u16* wT1 = wt + 6 * 65536;
  u16* wT2 = wt + 7 * 65536;
  u16* wSQ = wt + 8 * 65536;
  u16* wSK = wt + 9 * 65536;
  u16* wSV = wt + 10 * 65536;
  u16* wS1 = wt + 11 * 65536;
  u16* wS2 = wt + 12 * 65536;
  u16* wTW = wt + 13 * 65536;

  k_pe<<<T0, DM, 0, stream>>>(pe);
  k_gate<<<NS, 256, 0, stream>>>(x, gate_W, gate_b, g);
  WPrep wp;
  wp.s[0] = feat_W; wp.s[1] = ds_mid_W; wp.s[2] = ds_small_W;
  wp.s[3] = tWq; wp.s[4] = tWk; wp.s[5] = tWv; wp.s[6] = tW1; wp.s[7] = tW2;
  wp.s[8] = sWq; wp.s[9] = sWk; wp.s[10] = sWv; wp.s[11] = sW1; wp.s[12] = sW2;
  wp.s[13] = temp_W;
  k_wprep<<<224, 256, 0, stream>>>(wp, wt);

  // h0 (rows 0..32767)
  k_fgemm<<<dim3(2, 256), 256, 0, stream>>>(x, g, wFeat, feat_b, pe, hcat);
  // h1 (rows 32768..49151), h2 (rows 49152..57343)
  k_poolmean<<<4096, 256, 0, stream>>>(hcat, bQu, 16, 2);
  k_bgemm<true, false, false, false><<<dim3(2, 128, 1), 256, 0, stream>>>(
      bQu, wDSm, wDSm, wDSm, ds_mid_b, nullptr, hcat + (size_t)B1R * 256, nullptr, nullptr);
  k_poolmean<<<2048, 256, 0, stream>>>(hcat, bQu, 8, 4);
  k_bgemm<true, false, false, false><<<dim3(2, 64, 1), 256, 0, stream>>>(
      bQu, wDSs, wDSs, wDSs, ds_small_b, nullptr, hcat + (size_t)B2R * 256, nullptr, nullptr);

  dim3 g1(2, MTOT / 128, 1), g3(2, MTOT / 128, 3);
  // ---- time attention block (all scales merged) ----
  k_ln<false, false><<<MTOT / 4, 256, 0, stream>>>(hcat, nullptr, tn1g, tn1b, bXNu);
  k_bgemm<false, false, false, true><<<g3, 256, 0, stream>>>(
      bXNu, wTQ, wTK, wTV, nullptr, nullptr, bQu, bKu, bVu);
  k_tattn<32><<<NS, 256, 0, stream>>>(bQu, bKu, bVu, bO);
  k_tattn<16><<<NS, 256, 0, stream>>>(bQu + (size_t)B1R * 256, bKu + (size_t)B1R * 256,
                                      bVu + (size_t)B1R * 256, bO + (size_t)B1R * 256);
  k_tattn<8><<<NS, 256, 0, stream>>>(bQu + (size_t)B2R * 256, bKu + (size_t)B2R * 256,
                                     bVu + (size_t)B2R * 256, bO + (size_t)B2R * 256);
  k_ln<true, true><<<MTOT / 4, 256, 0, stream>>>(bXNu, bO, tn2g, tn2b, bQu);  // xt
  k_bgemm<true, true, false, true><<<g1, 256, 0, stream>>>(
      bQu, wT1, wT1, wT1, tb1, nullptr, bKu, nullptr, nullptr);
  k_bgemm<true, false, true, true><<<g1, 256, 0, stream>>>(
      bKu, wT2, wT2, wT2, tb2, bQu, bVu, nullptr, nullptr);  // z -> bVu
  // ---- stock attention block ----
  k_ln<false, true><<<MTOT / 4, 256, 0, stream>>>(bVu, nullptr, sn1g, sn1b, bXNu);  // xn2
  k_bgemm<false, false, false, true><<<g3, 256, 0, stream>>>(
      bXNu, wSQ, wSK, wSV, nullptr, nullptr, bQu, bKu, bVu);
  k_sattn<<<1792, 256, 0, stream>>>(bQu, bKu, bVu, bO);
  k_ln<true, true><<<MTOT / 4, 256, 0, stream>>>(bXNu, bO, sn2g, sn2b, bQu);  // xt2
  k_bgemm<true, true, false, true><<<g1, 256, 0, stream>>>(
      bQu, wS1, wS1, wS1, sb1, nullptr, bKu, nullptr, nullptr);
  k_bgemm<true, false, true, true><<<g1, 256, 0, stream>>>(
      bKu, wS2, wS2, wS2, sb2, bQu, bVu, nullptr, nullptr);  // z2 -> bVu
  k_bgemm<false, false, false, false><<<g1, 256, 0, stream>>>(
      bVu, wTW, wTW, wTW, nullptr, nullptr, hh, nullptr, nullptr);
  k_tpool<<<NS, 256, 0, stream>>>(hh, bVu, pooledu, 32, 0);
  k_tpool<<<NS, 256, 0, stream>>>(hh + (size_t)B1R * 256, bVu + (size_t)B1R * 256, pooledu, 16, 256);
  k_tpool<<<NS, 256, 0, stream>>>(hh + (size_t)B2R * 256, bVu + (size_t)B2R * 256, pooledu, 8, 512);

  k_wtrans<<<dim3(12, 4), 256, 0, stream>>>(fus_W, wFus);
  k_fus<<<dim3(4, 16), 256, 0, stream>>>(pooledu, wFus, fus_b, fused);
  k_final<<<NS, 256, 0, stream>>>(fused, fus_g, fus_bb, dec_W, dec_b, (float*)d_out);
}

// Round 6
// 497.731 us; speedup vs baseline: 9.1431x; 1.1949x over previous
//
#include <hip/hip_runtime.h>
#include <math.h>

#define NS 1024
#define T0 32
#define DF 158
#define DG 63
#define DM 256
#define XROW (DF + DG)  // 221
// merged-scale row bases: h0 rows [0,32768), h1 [32768,49152), h2 [49152,57344)
#define MTOT 57344
#define B1R 32768
#define B2R 49152

typedef unsigned short u16;
typedef __attribute__((ext_vector_type(8))) short bf16x8_t;
typedef __attribute__((ext_vector_type(4))) float f32x4_t;

union frag_u {
  bf16x8_t f;
  unsigned short us[8];
  unsigned int u32[4];
};

__device__ inline unsigned short f2bf(float x) {
  unsigned int u = __float_as_uint(x);
  unsigned int r = u + 0x7fffu + ((u >> 16) & 1u);
  return (unsigned short)(r >> 16);
}
__device__ inline float bf2f(u16 u) {
  return __uint_as_float(((unsigned int)u) << 16);
}
// v_cvt_pk_bf16_f32: D.lo16 = bf16(a), D.hi16 = bf16(b)
__device__ inline unsigned int cvtpk(float a, float b) {
  unsigned int r;
  asm("v_cvt_pk_bf16_f32 %0, %1, %2" : "=v"(r) : "v"(a), "v"(b));
  return r;
}
// async global->LDS, 16B per lane; LDS dest must be linear in lane order (G15/m97)
__device__ inline void gl16(const u16* gp, unsigned char* lp) {
  __builtin_amdgcn_global_load_lds((const __attribute__((address_space(1))) unsigned int*)gp,
                                   (__attribute__((address_space(3))) unsigned int*)lp, 16, 0, 0);
}

// ---------------- positional encoding table (32 x 256) ----------------
__global__ void k_pe(float* __restrict__ pe) {
  int t = blockIdx.x, d = threadIdx.x;
  int i2 = d & ~1;
  float div = expf((float)i2 * (-logf(10000.0f) / (float)DM));
  float ang = (float)t * div;
  pe[t * DM + d] = (d & 1) ? cosf(ang) : sinf(ang);
}

// ---------------- gate ----------------
__global__ void k_gate(const float* __restrict__ x, const float* __restrict__ gW,
                       const float* __restrict__ gb, float* __restrict__ g) {
  int n = blockIdx.x, tid = threadIdx.x;
  __shared__ float gin[DG];
  __shared__ float red[256];
  if (tid < DG) gin[tid] = x[(size_t)n * T0 * XROW + 31 * XROW + DF + tid];
  __syncthreads();
  float myv = 0.f;
  if (tid < DF) {
    float acc = gb[tid];
    for (int j = 0; j < DG; j++) acc = fmaf(gin[j], gW[j * DF + tid], acc);
    myv = acc * (1.0f / 5.0f);
  }
  red[tid] = (tid < DF) ? myv : -1e30f;
  __syncthreads();
  for (int s = 128; s > 0; s >>= 1) { if (tid < s) red[tid] = fmaxf(red[tid], red[tid + s]); __syncthreads(); }
  float mx = red[0];
  __syncthreads();
  float e = (tid < DF) ? expf(myv - mx) : 0.f;
  red[tid] = e;
  __syncthreads();
  for (int s = 128; s > 0; s >>= 1) { if (tid < s) red[tid] += red[tid + s]; __syncthreads(); }
  float sum = red[0];
  if (tid < DF) g[(size_t)n * DF + tid] = (float)DF * e / sum;
}

// ---------------- weight prep: W[K][256] fp32 -> Wt[256][256] bf16 (transposed, scaled, zero-pad K) ----------------
struct WPrep { const float* s[14]; float sc[14]; };
__global__ __launch_bounds__(256) void k_wprep(WPrep w, u16* __restrict__ dst) {
  int mat = blockIdx.x >> 4, nb = blockIdx.x & 15;
  int tid = threadIdx.x;
  int n = nb * 16 + (tid >> 4);
  int kc = (tid & 15) * 16;
  const float* src = w.s[mat];
  float sc = w.sc[mat];
  int K = (mat == 0) ? DF : 256;
  frag_u f0, f1;
#pragma unroll
  for (int j = 0; j < 8; j++) {
    int k0 = kc + j, k1 = kc + 8 + j;
    f0.us[j] = (k0 < K) ? f2bf(src[(size_t)k0 * 256 + n] * sc) : (u16)0;
    f1.us[j] = (k1 < K) ? f2bf(src[(size_t)k1 * 256 + n] * sc) : (u16)0;
  }
  u16* d = dst + (size_t)mat * 65536 + (size_t)n * 256 + kc;
  *(bf16x8_t*)d = f0.f;
  *(bf16x8_t*)(d + 8) = f1.f;
}

// ---------------- fus_W transpose: [768][256] fp32 -> [256][768] bf16 ----------------
__global__ __launch_bounds__(256) void k_wtrans(const float* __restrict__ W, u16* __restrict__ Wt) {
  __shared__ u16 Ts[64][65];
  int k0 = blockIdx.x * 64, n0 = blockIdx.y * 64;
  int tid = threadIdx.x;
#pragma unroll
  for (int i = 0; i < 16; i++) {
    int e = tid + i * 256;
    int r = e >> 6, c = e & 63;
    Ts[r][c] = f2bf(W[(size_t)(k0 + r) * 256 + n0 + c]);
  }
  __syncthreads();
#pragma unroll
  for (int i = 0; i < 16; i++) {
    int e = tid + i * 256;
    int r = e >> 6, c = e & 63;
    Wt[(size_t)(n0 + r) * 768 + k0 + c] = Ts[c][r];
  }
}

// ---------------- bf16 MFMA GEMM: C = act(A@Bt^T + bias + res); global_load_lds staging ----------------
template <bool BIAS, bool RELU, bool RES, bool OUTBF>
__global__ __launch_bounds__(256) void k_bgemm(
    const u16* __restrict__ A,
    const u16* __restrict__ B0, const u16* __restrict__ B1, const u16* __restrict__ B2,
    const float* __restrict__ bias, const u16* __restrict__ res,
    void* __restrict__ C0, void* __restrict__ C1, void* __restrict__ C2) {
  __shared__ __align__(16) unsigned char sm[32768];
  unsigned char* As = sm;
  unsigned char* Bs = sm + 16384;
  const u16* Bt = blockIdx.z == 0 ? B0 : (blockIdx.z == 1 ? B1 : B2);
  void* Cv = blockIdx.z == 0 ? C0 : (blockIdx.z == 1 ? C1 : C2);
  int m0 = blockIdx.y * 128, n0w = blockIdx.x * 128;
  int tid = threadIdx.x, lane = tid & 63, wid = tid >> 6;
  int qi = lane & 15, g = lane >> 4;
  int wr = wid >> 1, wc = wid & 1;
  f32x4_t acc[4][4];
#pragma unroll
  for (int i = 0; i < 4; i++)
#pragma unroll
    for (int j = 0; j < 4; j++) acc[i][j] = (f32x4_t){0.f, 0.f, 0.f, 0.f};
  for (int kt = 0; kt < 4; kt++) {
    if (kt) __syncthreads();
    // stage via global_load_lds: LDS linear at cid*16, global source pre-swizzled (c^(row&7))
#pragma unroll
    for (int i = 0; i < 4; i++) {
      int cid = tid + i * 256;
      int row = cid >> 3, c = cid & 7;
      int cs = c ^ (row & 7);
      gl16(A + (size_t)(m0 + row) * 256 + kt * 64 + cs * 8, As + cid * 16);
      gl16(Bt + (size_t)(n0w + row) * 256 + kt * 64 + cs * 8, Bs + cid * 16);
    }
    __syncthreads();
    bf16x8_t Af[2][4], Bf[2][4];
#pragma unroll
    for (int mi = 0; mi < 4; mi++) {
      int row = wr * 64 + mi * 16 + qi;
      int swz = (row & 7) << 4;
      const unsigned char* ap = As + row * 128;
      Af[0][mi] = *(const bf16x8_t*)(ap + ((g * 16) ^ swz));
      Af[1][mi] = *(const bf16x8_t*)(ap + ((64 + g * 16) ^ swz));
    }
#pragma unroll
    for (int ni = 0; ni < 4; ni++) {
      int row = wc * 64 + ni * 16 + qi;
      int swz = (row & 7) << 4;
      const unsigned char* bp = Bs + row * 128;
      Bf[0][ni] = *(const bf16x8_t*)(bp + ((g * 16) ^ swz));
      Bf[1][ni] = *(const bf16x8_t*)(bp + ((64 + g * 16) ^ swz));
    }
#pragma unroll
    for (int ks = 0; ks < 2; ks++)
#pragma unroll
      for (int mi = 0; mi < 4; mi++)
#pragma unroll
        for (int ni = 0; ni < 4; ni++)
          acc[mi][ni] = __builtin_amdgcn_mfma_f32_16x16x32_bf16(Af[ks][mi], Bf[ks][ni], acc[mi][ni], 0, 0, 0);
  }
#pragma unroll
  for (int mi = 0; mi < 4; mi++) {
#pragma unroll
    for (int ni = 0; ni < 4; ni++) {
#pragma unroll
      for (int r = 0; r < 4; r++) {
        int row = m0 + wr * 64 + mi * 16 + 4 * g + r;
        int col = n0w + wc * 64 + ni * 16 + qi;
        float vv = acc[mi][ni][r];
        if (BIAS) vv += bias[col];
        if (RES) vv += bf2f(res[(size_t)row * 256 + col]);
        if (RELU) vv = fmaxf(vv, 0.f);
        if (OUTBF) ((u16*)Cv)[(size_t)row * 256 + col] = f2bf(vv);
        else ((float*)Cv)[(size_t)row * 256 + col] = vv;
      }
    }
  }
}

// ---------------- feat GEMM: h = (x*gate)@feat_W + bias + pe, fp32 out ----------------
__global__ __launch_bounds__(256) void k_fgemm(
    const float* __restrict__ x, const float* __restrict__ gate,
    const u16* __restrict__ Bt, const float* __restrict__ bias,
    const float* __restrict__ pe, float* __restrict__ C) {
  __shared__ __align__(16) unsigned char sm[32768];
  unsigned char* As = sm;
  unsigned char* Bs = sm + 16384;
  int m0 = blockIdx.y * 128, n0w = blockIdx.x * 128;
  int tid = threadIdx.x, lane = tid & 63, wid = tid >> 6;
  int qi = lane & 15, g = lane >> 4;
  int wr = wid >> 1, wc = wid & 1;
  f32x4_t acc[4][4];
#pragma unroll
  for (int i = 0; i < 4; i++)
#pragma unroll
    for (int j = 0; j < 4; j++) acc[i][j] = (f32x4_t){0.f, 0.f, 0.f, 0.f};
  for (int kt = 0; kt < 3; kt++) {
    if (kt) __syncthreads();
#pragma unroll
    for (int i = 0; i < 4; i++) {
      int cid = tid + i * 256;
      int row = cid >> 3, c = cid & 7;
      int swz = (c * 16) ^ ((row & 7) << 4);
      int gk0 = kt * 64 + c * 8;
      const float* xr = x + (size_t)(m0 + row) * XROW;
      const float* gr = gate + (size_t)((m0 + row) >> 5) * DF;
      frag_u f;
#pragma unroll
      for (int j = 0; j < 8; j++) {
        int gk = gk0 + j;
        f.us[j] = (gk < DF) ? f2bf(xr[gk] * gr[gk]) : (u16)0;
      }
      *(bf16x8_t*)(As + row * 128 + swz) = f.f;
      bf16x8_t vb = *(const bf16x8_t*)(Bt + (size_t)(n0w + row) * 256 + kt * 64 + c * 8);
      *(bf16x8_t*)(Bs + row * 128 + swz) = vb;
    }
    __syncthreads();
    bf16x8_t Af[2][4], Bf[2][4];
#pragma unroll
    for (int mi = 0; mi < 4; mi++) {
      int row = wr * 64 + mi * 16 + qi;
      int swz = (row & 7) << 4;
      const unsigned char* ap = As + row * 128;
      Af[0][mi] = *(const bf16x8_t*)(ap + ((g * 16) ^ swz));
      Af[1][mi] = *(const bf16x8_t*)(ap + ((64 + g * 16) ^ swz));
    }
#pragma unroll
    for (int ni = 0; ni < 4; ni++) {
      int row = wc * 64 + ni * 16 + qi;
      int swz = (row & 7) << 4;
      const unsigned char* bp = Bs + row * 128;
      Bf[0][ni] = *(const bf16x8_t*)(bp + ((g * 16) ^ swz));
      Bf[1][ni] = *(const bf16x8_t*)(bp + ((64 + g * 16) ^ swz));
    }
#pragma unroll
    for (int ks = 0; ks < 2; ks++)
#pragma unroll
      for (int mi = 0; mi < 4; mi++)
#pragma unroll
        for (int ni = 0; ni < 4; ni++)
          acc[mi][ni] = __builtin_amdgcn_mfma_f32_16x16x32_bf16(Af[ks][mi], Bf[ks][ni], acc[mi][ni], 0, 0, 0);
  }
#pragma unroll
  for (int mi = 0; mi < 4; mi++) {
#pragma unroll
    for (int ni = 0; ni < 4; ni++) {
#pragma unroll
      for (int r = 0; r < 4; r++) {
        int row = m0 + wr * 64 + mi * 16 + 4 * g + r;
        int col = n0w + wc * 64 + ni * 16 + qi;
        C[(size_t)row * 256 + col] = acc[mi][ni][r] + bias[col] + pe[(row & (T0 - 1)) * DM + col];
      }
    }
  }
}

// ---------------- fus GEMM: fused = pooled @ fus_W + fus_b ----------------
__global__ __launch_bounds__(256) void k_fus(const u16* __restrict__ A, const u16* __restrict__ Bt,
                                             const float* __restrict__ bias, float* __restrict__ C) {
  __shared__ __align__(16) unsigned char sm[16384];
  unsigned char* As = sm;
  unsigned char* Bs = sm + 8192;
  int n0 = blockIdx.x * 64, m0 = blockIdx.y * 64;
  int tid = threadIdx.x, lane = tid & 63, wid = tid >> 6;
  int qi = lane & 15, g = lane >> 4;
  f32x4_t acc[4];
#pragma unroll
  for (int i = 0; i < 4; i++) acc[i] = (f32x4_t){0.f, 0.f, 0.f, 0.f};
  for (int kt = 0; kt < 12; kt++) {
    if (kt) __syncthreads();
#pragma unroll
    for (int i = 0; i < 2; i++) {
      int cid = tid + i * 256;
      int row = cid >> 3, c = cid & 7;
      int swz = (c * 16) ^ ((row & 7) << 4);
      *(bf16x8_t*)(As + row * 128 + swz) = *(const bf16x8_t*)(A + (size_t)(m0 + row) * 768 + kt * 64 + c * 8);
      *(bf16x8_t*)(Bs + row * 128 + swz) = *(const bf16x8_t*)(Bt + (size_t)(n0 + row) * 768 + kt * 64 + c * 8);
    }
    __syncthreads();
    int arow = wid * 16 + qi;
    int asw = (arow & 7) << 4;
    bf16x8_t Af0 = *(const bf16x8_t*)(As + arow * 128 + ((g * 16) ^ asw));
    bf16x8_t Af1 = *(const bf16x8_t*)(As + arow * 128 + ((64 + g * 16) ^ asw));
#pragma unroll
    for (int ni = 0; ni < 4; ni++) {
      int brow = ni * 16 + qi;
      int bsw = (brow & 7) << 4;
      bf16x8_t B0 = *(const bf16x8_t*)(Bs + brow * 128 + ((g * 16) ^ bsw));
      bf16x8_t B1 = *(const bf16x8_t*)(Bs + brow * 128 + ((64 + g * 16) ^ bsw));
      acc[ni] = __builtin_amdgcn_mfma_f32_16x16x32_bf16(Af0, B0, acc[ni], 0, 0, 0);
      acc[ni] = __builtin_amdgcn_mfma_f32_16x16x32_bf16(Af1, B1, acc[ni], 0, 0, 0);
    }
  }
#pragma unroll
  for (int ni = 0; ni < 4; ni++)
#pragma unroll
    for (int r = 0; r < 4; r++) {
      int row = m0 + wid * 16 + 4 * g + r;
      int col = n0 + ni * 16 + qi;
      C[(size_t)row * 256 + col] = acc[ni][r] + bias[col];
    }
}

// ---------------- LayerNorm: wave per row, 4 rows/block ----------------
template <bool RES, bool ABF>
__global__ __launch_bounds__(256) void k_ln(const void* __restrict__ a, const float* __restrict__ b,
                                            const float* __restrict__ g, const float* __restrict__ be,
                                            u16* __restrict__ out) {
  int row = blockIdx.x * 4 + (threadIdx.x >> 6);
  int lane = threadIdx.x & 63;
  size_t base = (size_t)row * DM + lane * 4;
  float v[4];
  if (ABF) {
    ushort4 u = *(const ushort4*)((const u16*)a + base);
    v[0] = bf2f(u.x); v[1] = bf2f(u.y); v[2] = bf2f(u.z); v[3] = bf2f(u.w);
  } else {
    f32x4_t t = *(const f32x4_t*)((const float*)a + base);
    v[0] = t[0]; v[1] = t[1]; v[2] = t[2]; v[3] = t[3];
  }
  if (RES) {
    f32x4_t t = *(const f32x4_t*)(b + base);
    v[0] += t[0]; v[1] += t[1]; v[2] += t[2]; v[3] += t[3];
  }
  float s = v[0] + v[1] + v[2] + v[3];
#pragma unroll
  for (int off = 1; off < 64; off <<= 1) s += __shfl_xor(s, off);
  float mean = s * (1.0f / DM);
  float d0 = v[0] - mean, d1 = v[1] - mean, d2 = v[2] - mean, d3 = v[3] - mean;
  float ss = d0 * d0 + d1 * d1 + d2 * d2 + d3 * d3;
#pragma unroll
  for (int off = 1; off < 64; off <<= 1) ss += __shfl_xor(ss, off);
  float inv = rsqrtf(ss * (1.0f / DM) + 1e-5f);
  f32x4_t gg = *(const f32x4_t*)(g + lane * 4);
  f32x4_t bb = *(const f32x4_t*)(be + lane * 4);
  ushort4 o4;
  o4.x = f2bf(d0 * inv * gg[0] + bb[0]);
  o4.y = f2bf(d1 * inv * gg[1] + bb[1]);
  o4.z = f2bf(d2 * inv * gg[2] + bb[2]);
  o4.w = f2bf(d3 * inv * gg[3] + bb[3]);
  *(ushort4*)(out + base) = o4;
}

// ---------------- mean-pool over time groups (bf16 out), 4 elems/thread ----------------
__global__ void k_poolmean(const float* __restrict__ h, u16* __restrict__ out, int Tout, int P) {
  int vi = blockIdx.x * 256 + threadIdx.x;
  int dv = vi & 63;
  int rowi = vi >> 6;
  int to = rowi % Tout;
  int n = rowi / Tout;
  int Tin = Tout * P;
  float s0 = 0.f, s1 = 0.f, s2 = 0.f, s3 = 0.f;
  for (int p = 0; p < P; p++) {
    f32x4_t t = *(const f32x4_t*)(h + ((size_t)(n * Tin + to * P + p)) * DM + dv * 4);
    s0 += t[0]; s1 += t[1]; s2 += t[2]; s3 += t[3];
  }
  float inv = 1.0f / (float)P;
  ushort4 o4;
  o4.x = f2bf(s0 * inv); o4.y = f2bf(s1 * inv); o4.z = f2bf(s2 * inv); o4.w = f2bf(s3 * inv);
  *(ushort4*)(out + (size_t)rowi * DM + dv * 4) = o4;
}

// ---------------- time attention via MFMA, sigma-permuted PV (no P-LDS); Q pre-scaled by 0.125*log2e ----------------
template <int T>
__global__ __launch_bounds__(256) void k_tattn(const u16* __restrict__ q, const u16* __restrict__ k,
                                               const u16* __restrict__ v, float* __restrict__ o) {
  constexpr int TR = (T < 16) ? 16 : T;
  constexpr int QKB = TR * 128;
  constexpr int HS = 2 * QKB + 64 * 80;
  __shared__ __align__(16) unsigned char smem[4 * HS];
  int n = blockIdx.x;
  int tid = threadIdx.x, lane = tid & 63, h = tid >> 6;
  int qi = lane & 15, g = lane >> 4;
  unsigned char* Qs = smem + h * HS;
  unsigned char* Ks = Qs + QKB;
  unsigned char* Vt = Ks + QKB;

  const u16* qh = q + (size_t)n * T * 256 + h * 64;
  const u16* kh = k + (size_t)n * T * 256 + h * 64;
  const u16* vh = v + (size_t)n * T * 256 + h * 64;
  const bf16x8_t zero8 = {0, 0, 0, 0, 0, 0, 0, 0};

  for (int idx = lane; idx < TR * 8; idx += 64) {
    int row = idx >> 3, c = idx & 7;
    bf16x8_t vq = zero8, vk = zero8;
    if (row < T) {
      vq = *(const bf16x8_t*)(qh + (size_t)row * 256 + c * 8);
      vk = *(const bf16x8_t*)(kh + (size_t)row * 256 + c * 8);
    }
    int off = row * 128 + ((c * 16) ^ ((row & 7) << 4));
    *(bf16x8_t*)(Qs + off) = vq;
    *(bf16x8_t*)(Ks + off) = vk;
  }
  // V staged transposed with sigma-permuted key positions
  {
    int kp = lane & 15, dg = lane >> 4;
    int d0 = dg * 16;
    int kk = 2 * kp;
    int cb = ((((kk >> 2) & 3) << 3) | (((kk >> 4) & 1) << 2) | (kk & 3)) * 2;
    frag_u a0, a1, b0, b1;
    a0.f = a1.f = b0.f = b1.f = zero8;
    if (kk < T) {
      a0.f = *(const bf16x8_t*)(vh + (size_t)kk * 256 + d0);
      a1.f = *(const bf16x8_t*)(vh + (size_t)kk * 256 + d0 + 8);
    }
    if (kk + 1 < T) {
      b0.f = *(const bf16x8_t*)(vh + (size_t)(kk + 1) * 256 + d0);
      b1.f = *(const bf16x8_t*)(vh + (size_t)(kk + 1) * 256 + d0 + 8);
    }
#pragma unroll
    for (int i = 0; i < 8; i++)
      *(unsigned int*)(Vt + (d0 + i) * 80 + cb) = (unsigned int)a0.us[i] | ((unsigned int)b0.us[i] << 16);
#pragma unroll
    for (int i = 0; i < 8; i++)
      *(unsigned int*)(Vt + (d0 + 8 + i) * 80 + cb) = (unsigned int)a1.us[i] | ((unsigned int)b1.us[i] << 16);
  }
  __syncthreads();

  constexpr int NQT = (T == 32) ? 2 : 1;
  constexpr int NSUB = (T == 32) ? 2 : 1;

  bf16x8_t Qb[NQT][2];
#pragma unroll
  for (int qt = 0; qt < NQT; qt++) {
    int row = qt * 16 + qi;
    int sw = (row & 7) << 4;
#pragma unroll
    for (int kst = 0; kst < 2; kst++)
      Qb[qt][kst] = *(const bf16x8_t*)(Qs + row * 128 + ((kst * 64 + g * 16) ^ sw));
  }
  f32x4_t sacc[NQT][NSUB];
#pragma unroll
  for (int qt = 0; qt < NQT; qt++)
#pragma unroll
    for (int sub = 0; sub < NSUB; sub++) sacc[qt][sub] = (f32x4_t){0.f, 0.f, 0.f, 0.f};
#pragma unroll
  for (int sub = 0; sub < NSUB; sub++) {
    int row = sub * 16 + qi;
    int sw = (row & 7) << 4;
    bf16x8_t Ka[2];
#pragma unroll
    for (int kst = 0; kst < 2; kst++)
      Ka[kst] = *(const bf16x8_t*)(Ks + row * 128 + ((kst * 64 + g * 16) ^ sw));
#pragma unroll
    for (int qt = 0; qt < NQT; qt++)
#pragma unroll
      for (int kst = 0; kst < 2; kst++)
        sacc[qt][sub] = __builtin_amdgcn_mfma_f32_16x16x32_bf16(Ka[kst], Qb[qt][kst], sacc[qt][sub], 0, 0, 0);
  }
  // softmax (exp2-space; Q pre-scaled); P packed in-register (sigma layout)
  frag_u Pf[NQT];
#pragma unroll
  for (int qt = 0; qt < NQT; qt++) {
    float sv[NSUB][4];
    float mx = -3.0e38f;
#pragma unroll
    for (int sub = 0; sub < NSUB; sub++)
#pragma unroll
      for (int r = 0; r < 4; r++) {
        int key = sub * 16 + 4 * g + r;
        float s = sacc[qt][sub][r];
        if (key >= T) s = -3.0e38f;
        sv[sub][r] = s;
        mx = fmaxf(mx, s);
      }
    mx = fmaxf(mx, __shfl_xor(mx, 16));
    mx = fmaxf(mx, __shfl_xor(mx, 32));
    float p[NSUB][4];
    float l = 0.f;
#pragma unroll
    for (int sub = 0; sub < NSUB; sub++)
#pragma unroll
      for (int r = 0; r < 4; r++) {
        float e = exp2f(sv[sub][r] - mx);
        p[sub][r] = e;
        l += e;
      }
    l += __shfl_xor(l, 16);
    l += __shfl_xor(l, 32);
    float linv = 1.0f / l;
    Pf[qt].u32[0] = cvtpk(p[0][0] * linv, p[0][1] * linv);
    Pf[qt].u32[1] = cvtpk(p[0][2] * linv, p[0][3] * linv);
    if (NSUB == 2) {
      Pf[qt].u32[2] = cvtpk(p[NSUB - 1][0] * linv, p[NSUB - 1][1] * linv);
      Pf[qt].u32[3] = cvtpk(p[NSUB - 1][2] * linv, p[NSUB - 1][3] * linv);
    } else {
      Pf[qt].u32[2] = 0u;
      Pf[qt].u32[3] = 0u;
    }
  }
  // PV
  f32x4_t oacc[NQT][4];
#pragma unroll
  for (int qt = 0; qt < NQT; qt++)
#pragma unroll
    for (int ni = 0; ni < 4; ni++) oacc[qt][ni] = (f32x4_t){0.f, 0.f, 0.f, 0.f};
#pragma unroll
  for (int ni = 0; ni < 4; ni++) {
    bf16x8_t Vb = *(const bf16x8_t*)(Vt + (ni * 16 + qi) * 80 + g * 16);
#pragma unroll
    for (int qt = 0; qt < NQT; qt++)
      oacc[qt][ni] = __builtin_amdgcn_mfma_f32_16x16x32_bf16(Pf[qt].f, Vb, oacc[qt][ni], 0, 0, 0);
  }
#pragma unroll
  for (int qt = 0; qt < NQT; qt++)
#pragma unroll
    for (int ni = 0; ni < 4; ni++)
#pragma unroll
      for (int r = 0; r < 4; r++) {
        int qq = qt * 16 + 4 * g + r;
        if (qq < T) o[((size_t)(n * T + qq)) * 256 + h * 64 + ni * 16 + qi] = oacc[qt][ni][r];
      }
}

// ---------------- stock attention: 32 queries/wave (128/block), sigma-PV, defer-max, exp2-space ----------------
__global__ __launch_bounds__(256) void k_sattn(const u16* __restrict__ q, const u16* __restrict__ k,
                                               const u16* __restrict__ v, float* __restrict__ o) {
  __shared__ __align__(16) unsigned char smem[32768];
  unsigned char* Ks = smem;
  unsigned char* Vt = smem + 16384;

  int bid = blockIdx.x;
  int T, rowbase;
  if (bid < 512) { T = 32; rowbase = 0; }
  else if (bid < 768) { T = 16; rowbase = B1R; bid -= 512; }
  else { T = 8; rowbase = B2R; bid -= 768; }
  const int NTH = T * 2;
  int xcd = bid & 7, slot = bid >> 3;
  int th = xcd * (NTH >> 3) + (slot >> 3);
  int qb = slot & 7;
  int t = th >> 1, h = th & 1;

  int tid = threadIdx.x;
  int lane = tid & 63;
  int wid = tid >> 6;
  int qi = lane & 15;
  int g = lane >> 4;

  const size_t rs = (size_t)T * 256;
  const size_t hb = (size_t)rowbase * 256 + (size_t)t * 256 + h * 128;
  const u16* qp = q + hb;
  const u16* kp = k + hb;
  const u16* vp = v + hb;
  float* op = o + hb;

  int q0 = qb * 128 + wid * 32;

  bf16x8_t QfA[4], QfB[4];
  {
    const u16* sA = qp + (size_t)(q0 + qi) * rs + g * 8;
    const u16* sB = sA + 16 * rs;
#pragma unroll
    for (int kst = 0; kst < 4; kst++) {
      QfA[kst] = *(const bf16x8_t*)(sA + kst * 32);
      QfB[kst] = *(const bf16x8_t*)(sB + kst * 32);
    }
  }

  f32x4_t OA[8], OB[8];
#pragma unroll
  for (int i = 0; i < 8; i++) {
    OA[i] = (f32x4_t){0.f, 0.f, 0.f, 0.f};
    OB[i] = (f32x4_t){0.f, 0.f, 0.f, 0.f};
  }
  float mA = -3.0e38f, lA = 0.f, mB = -3.0e38f, lB = 0.f;

  // sigma position for V staging (constant per thread)
  int kpair = tid & 31, dg = tid >> 5;
  int d0s = dg * 16;
  int kk = 2 * kpair;
  int cb = (((kk >> 5) << 5) | (((kk >> 2) & 3) << 3) | (((kk >> 4) & 1) << 2) | (kk & 3)) * 2;

  for (int kb = 0; kb < NS; kb += 64) {
    __syncthreads();
    // stage K tile (swizzled rows)
#pragma unroll
    for (int i = 0; i < 4; i++) {
      int cid = tid + i * 256;
      int row = cid >> 4, ch = cid & 15;
      bf16x8_t kv = *(const bf16x8_t*)(kp + (size_t)(kb + row) * rs + ch * 8);
      *(bf16x8_t*)(Ks + row * 256 + ((ch * 16) ^ ((row & 7) << 4))) = kv;
    }
    // stage V transposed, sigma-permuted key columns
    {
      const u16* s0 = vp + (size_t)(kb + kk) * rs + d0s;
      const u16* s1 = s0 + rs;
      frag_u a0, a1, b0, b1;
      a0.f = *(const bf16x8_t*)s0;
      a1.f = *(const bf16x8_t*)(s0 + 8);
      b0.f = *(const bf16x8_t*)s1;
      b1.f = *(const bf16x8_t*)(s1 + 8);
#pragma unroll
      for (int i = 0; i < 8; i++) {
        int d = d0s + i;
        *(unsigned int*)(Vt + d * 128 + (cb ^ ((d & 7) << 4))) =
            (unsigned int)a0.us[i] | ((unsigned int)b0.us[i] << 16);
      }
#pragma unroll
      for (int i = 0; i < 8; i++) {
        int d = d0s + 8 + i;
        *(unsigned int*)(Vt + d * 128 + (cb ^ ((d & 7) << 4))) =
            (unsigned int)a1.us[i] | ((unsigned int)b1.us[i] << 16);
      }
    }
    __syncthreads();

    // QK^T (swapped) for both query groups; K A-frags read once
    f32x4_t saA[4], saB[4];
#pragma unroll
    for (int i = 0; i < 4; i++) {
      saA[i] = (f32x4_t){0.f, 0.f, 0.f, 0.f};
      saB[i] = (f32x4_t){0.f, 0.f, 0.f, 0.f};
    }
#pragma unroll
    for (int sub = 0; sub < 4; sub++) {
      int row = sub * 16 + qi;
      int swz = (row & 7) << 4;
      const unsigned char* kr = Ks + row * 256;
#pragma unroll
      for (int kst = 0; kst < 4; kst++) {
        bf16x8_t Af = *(const bf16x8_t*)(kr + ((g * 16 + kst * 64) ^ swz));
        saA[sub] = __builtin_amdgcn_mfma_f32_16x16x32_bf16(Af, QfA[kst], saA[sub], 0, 0, 0);
        saB[sub] = __builtin_amdgcn_mfma_f32_16x16x32_bf16(Af, QfB[kst], saB[sub], 0, 0, 0);
      }
    }

    float pmA = -3.0e38f, pmB = -3.0e38f;
#pragma unroll
    for (int sub = 0; sub < 4; sub++)
#pragma unroll
      for (int r = 0; r < 4; r++) {
        pmA = fmaxf(pmA, saA[sub][r]);
        pmB = fmaxf(pmB, saB[sub][r]);
      }
    pmA = fmaxf(pmA, __shfl_xor(pmA, 16));
    pmA = fmaxf(pmA, __shfl_xor(pmA, 32));
    pmB = fmaxf(pmB, __shfl_xor(pmB, 16));
    pmB = fmaxf(pmB, __shfl_xor(pmB, 32));
    // defer-max (T13): rescale only when max grew past threshold (11.5 in log2 ~ e^8)
    if (__any(fmaxf(pmA - mA, pmB - mB) > 11.5f)) {
      float mnA = fmaxf(mA, pmA), mnB = fmaxf(mB, pmB);
      float fA = exp2f(mA - mnA), fB = exp2f(mB - mnB);
      lA *= fA;
      lB *= fB;
      float frA[4], frB[4];
#pragma unroll
      for (int r = 0; r < 4; r++) {
        frA[r] = __shfl(fA, (g << 2) | r);
        frB[r] = __shfl(fB, (g << 2) | r);
      }
#pragma unroll
      for (int dsub = 0; dsub < 8; dsub++)
#pragma unroll
        for (int r = 0; r < 4; r++) {
          OA[dsub][r] *= frA[r];
          OB[dsub][r] *= frB[r];
        }
      mA = mnA;
      mB = mnB;
    }
    float pA[4][4], pB[4][4];
    float lsA = 0.f, lsB = 0.f;
#pragma unroll
    for (int sub = 0; sub < 4; sub++)
#pragma unroll
      for (int r = 0; r < 4; r++) {
        float eA = exp2f(saA[sub][r] - mA);
        float eB = exp2f(saB[sub][r] - mB);
        pA[sub][r] = eA;
        pB[sub][r] = eB;
        lsA += eA;
        lsB += eB;
      }
    lsA += __shfl_xor(lsA, 16);
    lsA += __shfl_xor(lsA, 32);
    lsB += __shfl_xor(lsB, 16);
    lsB += __shfl_xor(lsB, 32);
    lA += lsA;
    lB += lsB;

    // P A-fragments lane-local via sigma: Pa[kst] slot e = p[2kst + (e>>2)][e&3]
    frag_u fA0, fA1, fB0, fB1;
    fA0.u32[0] = cvtpk(pA[0][0], pA[0][1]);
    fA0.u32[1] = cvtpk(pA[0][2], pA[0][3]);
    fA0.u32[2] = cvtpk(pA[1][0], pA[1][1]);
    fA0.u32[3] = cvtpk(pA[1][2], pA[1][3]);
    fA1.u32[0] = cvtpk(pA[2][0], pA[2][1]);
    fA1.u32[1] = cvtpk(pA[2][2], pA[2][3]);
    fA1.u32[2] = cvtpk(pA[3][0], pA[3][1]);
    fA1.u32[3] = cvtpk(pA[3][2], pA[3][3]);
    fB0.u32[0] = cvtpk(pB[0][0], pB[0][1]);
    fB0.u32[1] = cvtpk(pB[0][2], pB[0][3]);
    fB0.u32[2] = cvtpk(pB[1][0], pB[1][1]);
    fB0.u32[3] = cvtpk(pB[1][2], pB[1][3]);
    fB1.u32[0] = cvtpk(pB[2][0], pB[2][1]);
    fB1.u32[1] = cvtpk(pB[2][2], pB[2][3]);
    fB1.u32[2] = cvtpk(pB[3][0], pB[3][1]);
    fB1.u32[3] = cvtpk(pB[3][2], pB[3][3]);

#pragma unroll
    for (int kst = 0; kst < 2; kst++) {
      bf16x8_t PaA = kst ? fA1.f : fA0.f;
      bf16x8_t PaB = kst ? fB1.f : fB0.f;
#pragma unroll
      for (int dsub = 0; dsub < 8; dsub++) {
        int row = dsub * 16 + qi;
        bf16x8_t Vb = *(const bf16x8_t*)(Vt + row * 128 + ((g * 16 + kst * 64) ^ ((row & 7) << 4)));
        OA[dsub] = __builtin_amdgcn_mfma_f32_16x16x32_bf16(PaA, Vb, OA[dsub], 0, 0, 0);
        OB[dsub] = __builtin_amdgcn_mfma_f32_16x16x32_bf16(PaB, Vb, OB[dsub], 0, 0, 0);
      }
    }
  }

  float rinA[4], rinB[4];
#pragma unroll
  for (int r = 0; r < 4; r++) {
    rinA[r] = 1.0f / __shfl(lA, (g << 2) | r);
    rinB[r] = 1.0f / __shfl(lB, (g << 2) | r);
  }
#pragma unroll
  for (int dsub = 0; dsub < 8; dsub++)
#pragma unroll
    for (int r = 0; r < 4; r++) {
      size_t rowA = (size_t)(q0 + 4 * g + r);
      op[rowA * rs + dsub * 16 + qi] = OA[dsub][r] * rinA[r];
      op[(rowA + 16) * rs + dsub * 16 + qi] = OB[dsub][r] * rinB[r];
    }
}

// ---------------- temporal pooling, wave-parallel lambda dots ----------------
__global__ __launch_bounds__(256) void k_tpool(const float* __restrict__ hh, const u16* __restrict__ z,
                                               u16* __restrict__ pooled, int T, int off) {
  int n = blockIdx.x;
  int tid = threadIdx.x, lane = tid & 63, w = tid >> 6;
  __shared__ float lam[T0];
  __shared__ float lame[T0];
  __shared__ float lsum;
  const float* hn = hh + (size_t)n * T * DM;
  f32x4_t last = *(const f32x4_t*)(hn + (size_t)(T - 1) * DM + lane * 4);
  for (int t = w; t < T; t += 4) {
    f32x4_t hv = *(const f32x4_t*)(hn + (size_t)t * DM + lane * 4);
    float s = hv[0] * last[0] + hv[1] * last[1] + hv[2] * last[2] + hv[3] * last[3];
#pragma unroll
    for (int o2 = 1; o2 < 64; o2 <<= 1) s += __shfl_xor(s, o2);
    if (lane == 0) lam[t] = s;
  }
  __syncthreads();
  if (tid < 64) {
    float vv = (lane < T) ? lam[lane] : -3.0e38f;
    float mx = vv;
#pragma unroll
    for (int o2 = 1; o2 < 64; o2 <<= 1) mx = fmaxf(mx, __shfl_xor(mx, o2));
    float e = (lane < T) ? expf(vv - mx) : 0.f;
    float su = e;
#pragma unroll
    for (int o2 = 1; o2 < 64; o2 <<= 1) su += __shfl_xor(su, o2);
    if (lane < T) lame[lane] = e;
    if (lane == 0) lsum = su;
  }
  __syncthreads();
  float acc = 0.f;
  const u16* zn = z + (size_t)n * T * DM + tid;
  for (int t = 0; t < T; t++) acc += lame[t] * bf2f(zn[(size_t)t * DM]);
  pooled[(size_t)n * 768 + off + tid] = f2bf(acc / lsum);
}

// ---------------- final ----------------
__global__ __launch_bounds__(256) void k_final(const float* __restrict__ f, const float* __restrict__ g,
                                               const float* __restrict__ b, const float* __restrict__ dw,
                                               const float* __restrict__ db, float* __restrict__ out) {
  int n = blockIdx.x, d = threadIdx.x;
  float v = f[(size_t)n * DM + d];
  __shared__ float red[256];
  red[d] = v;
  __syncthreads();
  for (int s = 128; s > 0; s >>= 1) { if (d < s) red[d] += red[d + s]; __syncthreads(); }
  float mean = red[0] * (1.0f / DM);
  __syncthreads();
  float dv = v - mean;
  red[d] = dv * dv;
  __syncthreads();
  for (int s = 128; s > 0; s >>= 1) { if (d < s) red[d] += red[d + s]; __syncthreads(); }
  float var = red[0] * (1.0f / DM);
  __syncthreads();
  float y = dv * rsqrtf(var + 1e-5f) * g[d] + b[d];
  y = fmaxf(y, 0.f);
  red[d] = y * dw[d];
  __syncthreads();
  for (int s = 128; s > 0; s >>= 1) { if (d < s) red[d] += red[d + s]; __syncthreads(); }
  if (d == 0) out[n] = red[0] + db[0];
}

extern "C" void kernel_launch(void* const* d_in, const int* in_sizes, int n_in,
                              void* d_out, int out_size, void* d_ws, size_t ws_size,
                              hipStream_t stream) {
  const float* x = (const float*)d_in[0];
  const float* gate_W = (const float*)d_in[1];
  const float* gate_b = (const float*)d_in[2];
  const float* feat_W = (const float*)d_in[3];
  const float* feat_b = (const float*)d_in[4];
  const float* ds_mid_W = (const float*)d_in[5];
  const float* ds_mid_b = (const float*)d_in[6];
  const float* ds_small_W = (const float*)d_in[7];
  const float* ds_small_b = (const float*)d_in[8];
  const float* tn1g = (const float*)d_in[9];
  const float* tn1b = (const float*)d_in[10];
  const float* tWq = (const float*)d_in[11];
  const float* tWk = (const float*)d_in[12];
  const float* tWv = (const float*)d_in[13];
  const float* tn2g = (const float*)d_in[14];
  const float* tn2b = (const float*)d_in[15];
  const float* tW1 = (const float*)d_in[16];
  const float* tb1 = (const float*)d_in[17];
  const float* tW2 = (const float*)d_in[18];
  const float* tb2 = (const float*)d_in[19];
  const float* sn1g = (const float*)d_in[20];
  const float* sn1b = (const float*)d_in[21];
  const float* sWq = (const float*)d_in[22];
  const float* sWk = (const float*)d_in[23];
  const float* sWv = (const float*)d_in[24];
  const float* sn2g = (const float*)d_in[25];
  const float* sn2b = (const float*)d_in[26];
  const float* sW1 = (const float*)d_in[27];
  const float* sb1 = (const float*)d_in[28];
  const float* sW2 = (const float*)d_in[29];
  const float* sb2 = (const float*)d_in[30];
  const float* temp_W = (const float*)d_in[31];
  const float* fus_W = (const float*)d_in[32];
  const float* fus_b = (const float*)d_in[33];
  const float* fus_g = (const float*)d_in[34];
  const float* fus_bb = (const float*)d_in[35];
  const float* dec_W = (const float*)d_in[36];
  const float* dec_b = (const float*)d_in[37];

  float* ws = (float*)d_ws;
  size_t o = 0;
  float* pe = ws + o; o += 8192;
  float* g = ws + o; o += 161792;
  u16* wt = (u16*)(ws + o); o += 458752;        // 14 x 256x256 bf16
  float* hcat = ws + o; o += (size_t)MTOT * 256;     // fp32 slab: h -> bO -> hh -> fused
  u16* bXNu = (u16*)(ws + o); o += (size_t)MTOT * 128;
  u16* bQu = (u16*)(ws + o); o += (size_t)MTOT * 128;
  u16* bKu = (u16*)(ws + o); o += (size_t)MTOT * 128;
  u16* bVu = (u16*)(ws + o); o += (size_t)MTOT * 128;
  float* bO = hcat;
  float* hh = hcat;
  float* fused = hcat;
  u16* pooledu = bXNu;   // alias: xn2 dead before tpool
  u16* wFus = bKu;       // alias: written by wtrans after bKu dead

  u16* wFeat = wt;
  u16* wDSm = wt + 1 * 65536;
  u16* wDSs = wt + 2 * 65536;
  u16* wTQ = wt + 3 * 65536;
  u16* wTK = wt + 4 * 65536;
  u16* wTV = wt + 5 * 65536;
  u16* wT1 = wt + 6 * 65536;
  u16* wT2 = wt + 7 * 65536;
  u16* wSQ = wt + 8 * 65536;
  u16* wSK = wt + 9 * 65536;
  u16* wSV = wt + 10 * 65536;
  u16* wS1 = wt + 11 * 65536;
  u16* wS2 = wt + 12 * 65536;
  u16* wTW = wt + 13 * 65536;

  k_pe<<<T0, DM, 0, stream>>>(pe);
  k_gate<<<NS, 256, 0, stream>>>(x, gate_W, gate_b, g);
  WPrep wp;
  wp.s[0] = feat_W; wp.s[1] = ds_mid_W; wp.s[2] = ds_small_W;
  wp.s[3] = tWq; wp.s[4] = tWk; wp.s[5] = tWv; wp.s[6] = tW1; wp.s[7] = tW2;
  wp.s[8] = sWq; wp.s[9] = sWk; wp.s[10] = sWv; wp.s[11] = sW1; wp.s[12] = sW2;
  wp.s[13] = temp_W;
  for (int i = 0; i < 14; i++) wp.sc[i] = 1.0f;
  wp.sc[3] = 0.125f * 1.4426950408889634f;                 // tWq: 1/sqrt(64) * log2(e)
  wp.sc[8] = 0.08838834764831845f * 1.4426950408889634f;   // sWq: 1/sqrt(128) * log2(e)
  k_wprep<<<224, 256, 0, stream>>>(wp, wt);

  // h0 (rows 0..32767)
  k_fgemm<<<dim3(2, 256), 256, 0, stream>>>(x, g, wFeat, feat_b, pe, hcat);
  // h1 (rows 32768..49151), h2 (rows 49152..57343)
  k_poolmean<<<4096, 256, 0, stream>>>(hcat, bQu, 16, 2);
  k_bgemm<true, false, false, false><<<dim3(2, 128, 1), 256, 0, stream>>>(
      bQu, wDSm, wDSm, wDSm, ds_mid_b, nullptr, hcat + (size_t)B1R * 256, nullptr, nullptr);
  k_poolmean<<<2048, 256, 0, stream>>>(hcat, bQu, 8, 4);
  k_bgemm<true, false, false, false><<<dim3(2, 64, 1), 256, 0, stream>>>(
      bQu, wDSs, wDSs, wDSs, ds_small_b, nullptr, hcat + (size_t)B2R * 256, nullptr, nullptr);

  dim3 g1(2, MTOT / 128, 1), g3(2, MTOT / 128, 3);
  // ---- time attention block (all scales merged) ----
  k_ln<false, false><<<MTOT / 4, 256, 0, stream>>>(hcat, nullptr, tn1g, tn1b, bXNu);
  k_bgemm<false, false, false, true><<<g3, 256, 0, stream>>>(
      bXNu, wTQ, wTK, wTV, nullptr, nullptr, bQu, bKu, bVu);
  k_tattn<32><<<NS, 256, 0, stream>>>(bQu, bKu, bVu, bO);
  k_tattn<16><<<NS, 256, 0, stream>>>(bQu + (size_t)B1R * 256, bKu + (size_t)B1R * 256,
                                      bVu + (size_t)B1R * 256, bO + (size_t)B1R * 256);
  k_tattn<8><<<NS, 256, 0, stream>>>(bQu + (size_t)B2R * 256, bKu + (size_t)B2R * 256,
                                     bVu + (size_t)B2R * 256, bO + (size_t)B2R * 256);
  k_ln<true, true><<<MTOT / 4, 256, 0, stream>>>(bXNu, bO, tn2g, tn2b, bQu);  // xt
  k_bgemm<true, true, false, true><<<g1, 256, 0, stream>>>(
      bQu, wT1, wT1, wT1, tb1, nullptr, bKu, nullptr, nullptr);
  k_bgemm<true, false, true, true><<<g1, 256, 0, stream>>>(
      bKu, wT2, wT2, wT2, tb2, bQu, bVu, nullptr, nullptr);  // z -> bVu
  // ---- stock attention block ----
  k_ln<false, true><<<MTOT / 4, 256, 0, stream>>>(bVu, nullptr, sn1g, sn1b, bXNu);  // xn2
  k_bgemm<false, false, false, true><<<g3, 256, 0, stream>>>(
      bXNu, wSQ, wSK, wSV, nullptr, nullptr, bQu, bKu, bVu);
  k_sattn<<<896, 256, 0, stream>>>(bQu, bKu, bVu, bO);
  k_ln<true, true><<<MTOT / 4, 256, 0, stream>>>(bXNu, bO, sn2g, sn2b, bQu);  // xt2
  k_bgemm<true, true, false, true><<<g1, 256, 0, stream>>>(
      bQu, wS1, wS1, wS1, sb1, nullptr, bKu, nullptr, nullptr);
  k_bgemm<true, false, true, true><<<g1, 256, 0, stream>>>(
      bKu, wS2, wS2, wS2, sb2, bQu, bVu, nullptr, nullptr);  // z2 -> bVu
  k_bgemm<false, false, false, false><<<g1, 256, 0, stream>>>(
      bVu, wTW, wTW, wTW, nullptr, nullptr, hh, nullptr, nullptr);
  k_tpool<<<NS, 256, 0, stream>>>(hh, bVu, pooledu, 32, 0);
  k_tpool<<<NS, 256, 0, stream>>>(hh + (size_t)B1R * 256, bVu + (size_t)B1R * 256, pooledu, 16, 256);
  k_tpool<<<NS, 256, 0, stream>>>(hh + (size_t)B2R * 256, bVu + (size_t)B2R * 256, pooledu, 8, 512);

  k_wtrans<<<dim3(12, 4), 256, 0, stream>>>(fus_W, wFus);
  k_fus<<<dim3(4, 16), 256, 0, stream>>>(pooledu, wFus, fus_b, fused);
  k_final<<<NS, 256, 0, stream>>>(fused, fus_g, fus_bb, dec_W, dec_b, (float*)d_out);
}